// Round 6
// baseline (2103.446 us; speedup 1.0000x reference)
//
#include <hip/hip_runtime.h>
#include <math.h>

#define BB 256
#define LL 200
#define DD 512
#define VS 20000
#define VS_PAD 20224   // 316 * 64
#define STEPS 15

typedef __attribute__((ext_vector_type(8))) short bf16x8;
typedef __attribute__((ext_vector_type(4))) float f32x4;

// monotone mapping float -> uint32 preserving order
__device__ __forceinline__ unsigned int mono_key(float f) {
    unsigned int u = __float_as_uint(f);
    return (u & 0x80000000u) ? ~u : (u | 0x80000000u);
}

// bf16 round-to-nearest-even split helpers (bit ops, header-independent)
__device__ __forceinline__ unsigned short f2bf_rn(float x) {
    unsigned int u = __float_as_uint(x);
    unsigned int r = (u + 0x7FFFu + ((u >> 16) & 1u)) >> 16;
    return (unsigned short)r;
}
__device__ __forceinline__ float bf2f(unsigned short b) {
    return __uint_as_float((unsigned int)b << 16);
}

// split 8 consecutive floats into bf16 hi + lo residual, store 16B each
__device__ __forceinline__ void split_store8(float4 v0, float4 v1,
    unsigned short* __restrict__ hi, unsigned short* __restrict__ lo)
{
    ushort4 h0, h1, l0, l1;
    h0.x = f2bf_rn(v0.x); l0.x = f2bf_rn(v0.x - bf2f(h0.x));
    h0.y = f2bf_rn(v0.y); l0.y = f2bf_rn(v0.y - bf2f(h0.y));
    h0.z = f2bf_rn(v0.z); l0.z = f2bf_rn(v0.z - bf2f(h0.z));
    h0.w = f2bf_rn(v0.w); l0.w = f2bf_rn(v0.w - bf2f(h0.w));
    h1.x = f2bf_rn(v1.x); l1.x = f2bf_rn(v1.x - bf2f(h1.x));
    h1.y = f2bf_rn(v1.y); l1.y = f2bf_rn(v1.y - bf2f(h1.y));
    h1.z = f2bf_rn(v1.z); l1.z = f2bf_rn(v1.z - bf2f(h1.z));
    h1.w = f2bf_rn(v1.w); l1.w = f2bf_rn(v1.w - bf2f(h1.w));
    *(ushort4*)hi = h0; *(ushort4*)(hi + 4) = h1;
    *(ushort4*)lo = l0; *(ushort4*)(lo + 4) = l1;
}

// same split but into register fragments (for inline gather in the gates GEMM)
__device__ __forceinline__ void split_frag(float4 v0, float4 v1, bf16x8& hi, bf16x8& lo)
{
    float vv[8] = {v0.x, v0.y, v0.z, v0.w, v1.x, v1.y, v1.z, v1.w};
    #pragma unroll
    for (int j = 0; j < 8; j++) {
        unsigned short hb = f2bf_rn(vv[j]);
        hi[j] = (short)hb;
        lo[j] = (short)f2bf_rn(vv[j] - bf2f(hb));
    }
}

__global__ __launch_bounds__(256) void init_keys_kernel(unsigned long long* keys) {
    // low 32 bits = ~token ; decode token = ~(uint32)key. SOS token = 1.
    keys[threadIdx.x] = (unsigned long long)(unsigned int)(~1u);
}

// -------------------- fragment-order packing convention (16x16x32 bf16 MFMA):
// elem idx = panel*(NCH*512) + chunk*512 + lane*8 + j  where
// panel = row/16, chunk = k/32, lane = ((k%32)/8)*16 + row%16, j = k%8.
// A-side buffers are per-512-K halves: panel stride 8192 (16 chunks).

// one-time split of p_w [VS][512] -> hi/lo fragment order (K=512, panel stride 8192)
__global__ __launch_bounds__(256) void split_pw_kernel(
    const float* __restrict__ p_w, unsigned short* __restrict__ p_hi,
    unsigned short* __restrict__ p_lo)
{
    size_t q = (size_t)blockIdx.x * 256 + threadIdx.x;   // chunk id, VS_PAD*64 total
    int P   = (int)(q >> 10);
    int rem = (int)(q & 1023);
    int c   = rem >> 6;
    int l   = rem & 63;
    int row = P * 16 + (l & 15);
    int ks  = c * 32 + (l >> 4) * 8;
    float4 v0 = {0.f, 0.f, 0.f, 0.f}, v1 = {0.f, 0.f, 0.f, 0.f};
    if (row < VS) {
        const float* src = p_w + (size_t)row * DD + ks;
        v0 = *(const float4*)src;
        v1 = *(const float4*)(src + 4);
    }
    split_store8(v0, v1, p_hi + q * 8, p_lo + q * 8);
}

// one-time split of concat weights [R][1024] = [s0 | s1] (each [R][512]) -> hi/lo
// fragment order with panel stride 16384 (32 chunks). R must be multiple of 16.
// PERM=1 (gates W): packed panel P holds orig rows (P&3)*512 + (P>>2)*16 + col
// (gate-interleaved so one wave's 4 fragment columns = the 4 gates of one feature).
template <int PERM>
__global__ __launch_bounds__(256) void split_wcat_kernel(
    const float* __restrict__ s0, const float* __restrict__ s1,
    unsigned short* __restrict__ wh, unsigned short* __restrict__ wl)
{
    size_t q = (size_t)blockIdx.x * 256 + threadIdx.x;   // R*128 groups
    int P   = (int)(q >> 11);
    int rem = (int)(q & 2047);
    int c   = rem >> 6;
    int l   = rem & 63;
    int row;
    if (PERM) row = (P & 3) * 512 + (P >> 2) * 16 + (l & 15);
    else      row = P * 16 + (l & 15);
    int k   = c * 32 + (l >> 4) * 8;
    const float* src = (k < 512) ? (s0 + (size_t)row * DD + k)
                                 : (s1 + (size_t)row * DD + (k - 512));
    float4 v0 = *(const float4*)src;
    float4 v1 = *(const float4*)(src + 4);
    split_store8(v0, v1, wh + q * 8, wl + q * 8);
}

// -------------------- fused: token gather + gates GEMM + LSTM pointwise + h pack.
// 2-wave blocks; wave w owns m-tile (blockIdx.y*2+w)*16 — identical per-wave
// instruction stream to the proven R5 kernel, now spread over all 256 CUs.
// 16(m) x 64(n = 16 feats x 4 gates) tile, K=32 chunks.
// Epilogue = fp64 LSTM pointwise (4 cells/lane), writes c, h and packed h_out.
// grid (32 nt, 8) x 128 threads = 256 blocks, 512 waves.
__global__ __launch_bounds__(128) void gates_lstm_kernel(
    const float* __restrict__ sum_emb, const unsigned long long* __restrict__ keys,
    const unsigned short* __restrict__ hin_hi, const unsigned short* __restrict__ hin_lo,
    const unsigned short* __restrict__ w1h, const unsigned short* __restrict__ w1l,
    const float* __restrict__ bi, const float* __restrict__ bh,
    float* __restrict__ c, float* __restrict__ h,
    unsigned short* __restrict__ hout_hi, unsigned short* __restrict__ hout_lo)
{
    const int tid  = threadIdx.x;
    const int lane = tid & 63;
    const int wav  = tid >> 6;
    const int col = lane & 15;
    const int kg  = lane >> 4;
    const int m0  = (blockIdx.y * 2 + wav) * 16;
    const int nt  = blockIdx.x;               // features nt*16 .. nt*16+15

    unsigned int tok = ~(unsigned int)(keys[m0 + col] & 0xFFFFFFFFull);

    const size_t ahoff = (size_t)(m0 >> 4) * 8192 + (size_t)lane * 8;
    const size_t boff  = (size_t)(nt * 4) * 16384 + (size_t)lane * 8;

    f32x4 acc[4];
    #pragma unroll
    for (int g = 0; g < 4; g++) acc[g] = (f32x4){0.f, 0.f, 0.f, 0.f};

    bf16x8 fa_h[2], fa_l[2], fb_h[2][4], fb_l[2][4];

#define GL_LOAD(C, BUF)                                                            \
    {                                                                              \
        if ((C) < 16) {                                                            \
            const float* s_ = sum_emb + (size_t)tok * DD + (C) * 32 + kg * 8;      \
            float4 v0 = *(const float4*)s_;                                        \
            float4 v1 = *(const float4*)(s_ + 4);                                  \
            split_frag(v0, v1, fa_h[BUF], fa_l[BUF]);                              \
        } else {                                                                   \
            fa_h[BUF] = *(const bf16x8*)(hin_hi + ahoff + ((C) - 16) * 512);       \
            fa_l[BUF] = *(const bf16x8*)(hin_lo + ahoff + ((C) - 16) * 512);       \
        }                                                                          \
        _Pragma("unroll")                                                          \
        for (int g = 0; g < 4; g++) {                                              \
            fb_h[BUF][g] = *(const bf16x8*)(w1h + boff + (size_t)g * 16384 + (C) * 512); \
            fb_l[BUF][g] = *(const bf16x8*)(w1l + boff + (size_t)g * 16384 + (C) * 512); \
        }                                                                          \
    }

    GL_LOAD(0, 0);
    #pragma unroll
    for (int cc = 0; cc < 32; cc++) {
        const int cur = cc & 1, nxt = cur ^ 1;
        if (cc < 31) GL_LOAD(cc + 1, nxt);
        #pragma unroll
        for (int g = 0; g < 4; g++) {
            acc[g] = __builtin_amdgcn_mfma_f32_16x16x32_bf16(fa_h[cur], fb_h[cur][g], acc[g], 0, 0, 0);
            acc[g] = __builtin_amdgcn_mfma_f32_16x16x32_bf16(fa_h[cur], fb_l[cur][g], acc[g], 0, 0, 0);
            acc[g] = __builtin_amdgcn_mfma_f32_16x16x32_bf16(fa_l[cur], fb_h[cur][g], acc[g], 0, 0, 0);
        }
    }
#undef GL_LOAD

    const int feat = nt * 16 + col;
    float bias[4];
    #pragma unroll
    for (int g = 0; g < 4; g++)
        bias[g] = bi[g * 512 + feat] + bh[g * 512 + feat];

    // LSTM pointwise (fp64, identical math), 4 cells/lane
    #pragma unroll
    for (int r = 0; r < 4; r++) {
        const int b = m0 + kg * 4 + r;
        float vi = acc[0][r] + bias[0];
        float vf = acc[1][r] + bias[1];
        float vg = acc[2][r] + bias[2];
        float vo = acc[3][r] + bias[3];
        double ig = 1.0 / (1.0 + exp(-(double)vi));
        double fg = 1.0 / (1.0 + exp(-(double)vf));
        double gv = tanh((double)vg);
        double og = 1.0 / (1.0 + exp(-(double)vo));
        size_t cidx = (size_t)b * DD + feat;
        double cn = fg * (double)c[cidx] + ig * gv;
        double hn = og * tanh(cn);
        c[cidx] = (float)cn;
        float hf = (float)hn;
        h[cidx] = hf;
        size_t hidx = (size_t)(b >> 4) * 8192 + (size_t)(feat >> 5) * 512
                    + (size_t)(((feat >> 3) & 3) * 16 + (b & 15)) * 8 + (feat & 7);
        unsigned short hb2 = f2bf_rn(hf);
        hout_hi[hidx] = hb2;
        hout_lo[hidx] = f2bf_rn(hf - bf2f(hb2));
    }
}

// -------------------- pre GEMM: tanh([t|h] @ [t_w|h_w]^T + t_b + h_b) -> packed A.
// 4-wave blocks, 16(m) x 32(n) tile, 4-way K-split (wave w = chunks 8w..8w+7).
// Partials reduced via LDS; tanh epilogue spread over 256 threads (2 cells each).
// grid (16 n-tiles, 16 m-tiles) = 1024 waves.
__global__ __launch_bounds__(256) void pre_kernel(
    const unsigned short* __restrict__ t_hi, const unsigned short* __restrict__ t_lo,
    const unsigned short* __restrict__ h_hi, const unsigned short* __restrict__ h_lo,
    const unsigned short* __restrict__ w2h, const unsigned short* __restrict__ w2l,
    const float* __restrict__ tb, const float* __restrict__ hbv,
    unsigned short* __restrict__ o_hi, unsigned short* __restrict__ o_lo)
{
    const int tid  = threadIdx.x;
    const int lane = tid & 63;
    const int wav  = tid >> 6;        // K-split: absolute chunks wav*8 .. wav*8+7
    const int col  = lane & 15;
    const int kg   = lane >> 4;
    const int m0   = blockIdx.y * 16;
    const int n0   = blockIdx.x * 32;

    const unsigned short* ah = (wav < 2) ? t_hi : h_hi;
    const unsigned short* al = (wav < 2) ? t_lo : h_lo;
    const size_t aoff = (size_t)(m0 >> 4) * 8192 + (size_t)lane * 8
                      + (size_t)((wav & 1) * 8) * 512;
    const size_t boff = (size_t)(n0 >> 4) * 16384 + (size_t)lane * 8
                      + (size_t)(wav * 8) * 512;

    f32x4 acc[2];
    acc[0] = (f32x4){0.f, 0.f, 0.f, 0.f};
    acc[1] = (f32x4){0.f, 0.f, 0.f, 0.f};

    bf16x8 fa_h[2], fa_l[2], fb_h[2][2], fb_l[2][2];
    fa_h[0] = *(const bf16x8*)(ah + aoff);
    fa_l[0] = *(const bf16x8*)(al + aoff);
    #pragma unroll
    for (int g = 0; g < 2; g++) {
        fb_h[0][g] = *(const bf16x8*)(w2h + boff + (size_t)g * 16384);
        fb_l[0][g] = *(const bf16x8*)(w2l + boff + (size_t)g * 16384);
    }
    #pragma unroll
    for (int cc = 0; cc < 8; cc++) {
        const int cur = cc & 1, nxt = cur ^ 1;
        if (cc < 7) {
            const int off = (cc + 1) * 512;
            fa_h[nxt] = *(const bf16x8*)(ah + aoff + off);
            fa_l[nxt] = *(const bf16x8*)(al + aoff + off);
            #pragma unroll
            for (int g = 0; g < 2; g++) {
                fb_h[nxt][g] = *(const bf16x8*)(w2h + boff + (size_t)g * 16384 + off);
                fb_l[nxt][g] = *(const bf16x8*)(w2l + boff + (size_t)g * 16384 + off);
            }
        }
        #pragma unroll
        for (int g = 0; g < 2; g++) {
            acc[g] = __builtin_amdgcn_mfma_f32_16x16x32_bf16(fa_h[cur], fb_h[cur][g], acc[g], 0, 0, 0);
            acc[g] = __builtin_amdgcn_mfma_f32_16x16x32_bf16(fa_h[cur], fb_l[cur][g], acc[g], 0, 0, 0);
            acc[g] = __builtin_amdgcn_mfma_f32_16x16x32_bf16(fa_l[cur], fb_h[cur][g], acc[g], 0, 0, 0);
        }
    }

    __shared__ float psum[4][16][32];
    #pragma unroll
    for (int g = 0; g < 2; g++)
        #pragma unroll
        for (int r = 0; r < 4; r++)
            psum[wav][kg * 4 + r][g * 16 + col] = acc[g][r];
    __syncthreads();

    #pragma unroll
    for (int e = 0; e < 2; e++) {
        const int idx  = tid * 2 + e;
        const int row  = idx >> 5, coln = idx & 31;
        const int b    = m0 + row;
        const int n    = n0 + coln;
        float accs = (psum[0][row][coln] + psum[1][row][coln])
                   + (psum[2][row][coln] + psum[3][row][coln]);
        float val = accs + (tb[n] + hbv[n]);
        float v2 = (float)tanh((double)val);
        int P = b >> 4, colb = b & 15;
        int cc2 = n >> 5, kgg = (n >> 3) & 3, jj = n & 7;
        size_t oidx = (size_t)P * 8192 + (size_t)cc2 * 512
                    + (size_t)(kgg * 16 + colb) * 8 + jj;
        unsigned short hb = f2bf_rn(v2);
        o_hi[oidx] = hb;
        o_lo[oidx] = f2bf_rn(v2 - bf2f(hb));
    }
}

// -------------------- logits GEMM (bf16x3 MFMA) + bias + store + argmax.
// 32(m) x 64(n) tile per wave, WPB waves per block sharing B panels.
// B prefetch 2-ahead (ring-3 buffers, L3 latency), A 1-ahead (L2-hot).
// MFMA order identical to the proven kernel -> bit-identical output.
template <int NCH, int EPI, int WPB>
__global__ __launch_bounds__(64 * WPB, 2) void mfma_gemm(
    const unsigned short* __restrict__ a0h, const unsigned short* __restrict__ a0l,
    const unsigned short* __restrict__ a1h, const unsigned short* __restrict__ a1l,
    const unsigned short* __restrict__ bmh, const unsigned short* __restrict__ bml,
    const float* __restrict__ bias0, const float* __restrict__ bias1,
    float* __restrict__ outp,
    unsigned short* __restrict__ o_hi, unsigned short* __restrict__ o_lo,
    unsigned long long* __restrict__ keys, int s)
{
    const int tid  = threadIdx.x;
    const int lane = tid & 63;
    const int wav  = tid >> 6;
    const int col = lane & 15;        // fragment row (A) / column (B)
    const int kg  = lane >> 4;        // k-group 0..3
    const int m0 = (blockIdx.y * WPB + wav) * 32;
    const int n0 = blockIdx.x * 64;

    const size_t aoff = (size_t)(m0 >> 4) * 8192 + (size_t)lane * 8;
    const size_t boff = (size_t)(n0 >> 4) * (NCH * 512) + (size_t)lane * 8;

    f32x4 acc[2][4];
    #pragma unroll
    for (int f = 0; f < 2; f++)
        #pragma unroll
        for (int g = 0; g < 4; g++)
            acc[f][g] = (f32x4){0.f, 0.f, 0.f, 0.f};

    bf16x8 fah[2][2], fal[2][2];      // A: 1-ahead double buffer
    bf16x8 fbh[3][4], fbl[3][4];      // B: 2-ahead ring-3

#define LOAD_A(C, BUF)                                                             \
    {                                                                              \
        const unsigned short* ah_ = ((NCH == 16) || ((C) < 16)) ? a0h : a1h;       \
        const unsigned short* al_ = ((NCH == 16) || ((C) < 16)) ? a0l : a1l;       \
        const int cc_ = (C) & 15;                                                  \
        _Pragma("unroll")                                                          \
        for (int f = 0; f < 2; f++) {                                              \
            fah[BUF][f] = *(const bf16x8*)(ah_ + aoff + (size_t)f * 8192 + cc_ * 512); \
            fal[BUF][f] = *(const bf16x8*)(al_ + aoff + (size_t)f * 8192 + cc_ * 512); \
        }                                                                          \
    }
#define LOAD_B(C, BUF)                                                             \
    {                                                                              \
        _Pragma("unroll")                                                          \
        for (int g = 0; g < 4; g++) {                                              \
            fbh[BUF][g] = *(const bf16x8*)(bmh + boff + (size_t)g * (NCH * 512) + (C) * 512); \
            fbl[BUF][g] = *(const bf16x8*)(bml + boff + (size_t)g * (NCH * 512) + (C) * 512); \
        }                                                                          \
    }

    LOAD_B(0, 0);
    LOAD_B(1, 1);
    LOAD_A(0, 0);
    #pragma unroll
    for (int c = 0; c < NCH; c++) {
        const int bcur = c % 3;
        const int acur = c & 1;
        if (c + 2 < NCH) LOAD_B(c + 2, (c + 2) % 3);
        if (c + 1 < NCH) LOAD_A(c + 1, (c + 1) & 1);
        #pragma unroll
        for (int f = 0; f < 2; f++)
            #pragma unroll
            for (int g = 0; g < 4; g++) {
                acc[f][g] = __builtin_amdgcn_mfma_f32_16x16x32_bf16(fah[acur][f], fbh[bcur][g], acc[f][g], 0, 0, 0);
                acc[f][g] = __builtin_amdgcn_mfma_f32_16x16x32_bf16(fah[acur][f], fbl[bcur][g], acc[f][g], 0, 0, 0);
                acc[f][g] = __builtin_amdgcn_mfma_f32_16x16x32_bf16(fal[acur][f], fbh[bcur][g], acc[f][g], 0, 0, 0);
            }
    }
#undef LOAD_A
#undef LOAD_B

    // bias per n-col of this lane (col fixed per lane)
    float bias[4];
    #pragma unroll
    for (int g = 0; g < 4; g++) {
        int v = n0 + g * 16 + col;
        bias[g] = (v < VS) ? bias0[v] : 0.f;
    }

    // epilogue (C/D: col = lane&15, row = kg*4 + reg)
    #pragma unroll
    for (int f = 0; f < 2; f++) {
        #pragma unroll
        for (int r = 0; r < 4; r++) {
            const int b = m0 + f * 16 + kg * 4 + r;
            float* orow = outp + ((size_t)b * STEPS + s) * VS;
            unsigned long long kmax = 0ull;
            #pragma unroll
            for (int g = 0; g < 4; g++) {
                int v = n0 + g * 16 + col;
                float val = acc[f][g][r] + bias[g];
                if (v < VS) {
                    orow[v] = val;
                    unsigned long long key =
                        ((unsigned long long)mono_key(val) << 32) |
                        (unsigned long long)(unsigned int)(~v);
                    if (key > kmax) kmax = key;
                }
            }
            #pragma unroll
            for (int mk = 1; mk < 16; mk <<= 1) {
                unsigned long long o = __shfl_xor(kmax, mk, 64);
                if (o > kmax) kmax = o;
            }
            if (col == 0) {
                // load-filter: stale reads are only ever lower -> conservative
                if (kmax > *(volatile unsigned long long*)&keys[b])
                    atomicMax(&keys[b], kmax);
            }
        }
    }
}

// -------------------- attention: scores -> softmax -> weighted sum. One block per
// batch row, 512 threads (8 waves); waves stride l by 8 in both passes with explicit
// 1-ahead load prefetch. Epilogue packs t into hi/lo fragment order, resets keys[b].
__global__ __launch_bounds__(512) void attn_kernel(
    const int* __restrict__ method_code, const float* __restrict__ code_emb,
    const float* __restrict__ h, unsigned short* __restrict__ t_hi,
    unsigned short* __restrict__ t_lo, unsigned long long* __restrict__ keys)
{
    const int b = blockIdx.x;
    const int tid = threadIdx.x;
    const int lane = tid & 63, wave = tid >> 6;

    __shared__ float sc[LL];        // scores, then attn weights
    __shared__ int   rows[LL];
    __shared__ float fred[256];
    __shared__ double dred[256];
    __shared__ float ts[DD];
    __shared__ float part[8][DD];

    if (tid < LL) rows[tid] = method_code[b * LL + tid];
    if (tid == 0) keys[b] = 0ull;   // safe: gates GEMM already consumed last step's keys
    // h fragment in registers: 8 consecutive per lane (same for all 8 waves)
    const float* hb = h + (size_t)b * DD;
    float4 h0 = *(const float4*)(hb + lane * 8);
    float4 h1 = *(const float4*)(hb + lane * 8 + 4);
    __syncthreads();

    // pass 1: scores[l] = h . e_l (8 waves stride l; 25 iters each; 1-ahead prefetch)
    {
        const float* e = code_emb + (size_t)rows[wave] * DD + lane * 8;
        float4 e0 = *(const float4*)e;
        float4 e1 = *(const float4*)(e + 4);
        for (int l = wave; l < LL; l += 8) {
            float4 n0v = e0, n1v = e1;
            if (l + 8 < LL) {
                const float* en = code_emb + (size_t)rows[l + 8] * DD + lane * 8;
                n0v = *(const float4*)en;
                n1v = *(const float4*)(en + 4);
            }
            float p = h0.x * e0.x + h0.y * e0.y + h0.z * e0.z + h0.w * e0.w
                    + h1.x * e1.x + h1.y * e1.y + h1.z * e1.z + h1.w * e1.w;
            #pragma unroll
            for (int m = 1; m < 64; m <<= 1) p += __shfl_xor(p, m, 64);
            if (lane == 0) sc[l] = p;
            e0 = n0v; e1 = n1v;
        }
    }
    __syncthreads();

    // softmax over 200 (max-subtract, fp64 exp & sum); reduction on first 256 threads
    if (tid < 256) fred[tid] = (tid < LL) ? sc[tid] : -INFINITY;
    __syncthreads();
    for (int s2 = 128; s2 > 0; s2 >>= 1) {
        if (tid < s2) fred[tid] = fmaxf(fred[tid], fred[tid + s2]);
        __syncthreads();
    }
    float smax = fred[0];
    __syncthreads();
    double w = (tid < LL) ? exp((double)sc[tid] - (double)smax) : 0.0;
    if (tid < 256) dred[tid] = w;
    __syncthreads();
    for (int s2 = 128; s2 > 0; s2 >>= 1) {
        if (tid < s2) dred[tid] += dred[tid + s2];
        __syncthreads();
    }
    double ssum = dred[0];
    __syncthreads();
    if (tid < LL) sc[tid] = (float)(w / ssum);
    __syncthreads();

    // pass 2: 8-way wave-split over l with 1-ahead prefetch; lane owns 8 dims
    float pa[8] = {0.f, 0.f, 0.f, 0.f, 0.f, 0.f, 0.f, 0.f};
    {
        const float* e = code_emb + (size_t)rows[wave] * DD + lane * 8;
        float4 e0 = *(const float4*)e;
        float4 e1 = *(const float4*)(e + 4);
        for (int l = wave; l < LL; l += 8) {
            float4 n0v = e0, n1v = e1;
            if (l + 8 < LL) {
                const float* en = code_emb + (size_t)rows[l + 8] * DD + lane * 8;
                n0v = *(const float4*)en;
                n1v = *(const float4*)(en + 4);
            }
            float wl = sc[l];
            pa[0] = fmaf(wl, e0.x, pa[0]); pa[1] = fmaf(wl, e0.y, pa[1]);
            pa[2] = fmaf(wl, e0.z, pa[2]); pa[3] = fmaf(wl, e0.w, pa[3]);
            pa[4] = fmaf(wl, e1.x, pa[4]); pa[5] = fmaf(wl, e1.y, pa[5]);
            pa[6] = fmaf(wl, e1.z, pa[6]); pa[7] = fmaf(wl, e1.w, pa[7]);
            e0 = n0v; e1 = n1v;
        }
    }
    #pragma unroll
    for (int j = 0; j < 8; j++) part[wave][lane * 8 + j] = pa[j];
    __syncthreads();

    // combine partials: each thread owns 1 dim, fixed pairwise order
    {
        const int d = tid;   // 512 threads, 512 dims
        float v01 = part[0][d] + part[1][d];
        float v23 = part[2][d] + part[3][d];
        float v45 = part[4][d] + part[5][d];
        float v67 = part[6][d] + part[7][d];
        ts[d] = (v01 + v23) + (v45 + v67);
    }
    __syncthreads();

    // pack t row into fragment order: 64 lanes x 8 consecutive dims
    if (tid < 64) {
        const int cc = tid >> 2, kgg = tid & 3;
        const float* src = ts + cc * 32 + kgg * 8;   // = ts + tid*8 (contiguous)
        float4 v0 = *(const float4*)src;
        float4 v1 = *(const float4*)(src + 4);
        size_t base = (size_t)(b >> 4) * 8192 + (size_t)cc * 512
                    + (size_t)(kgg * 16 + (b & 15)) * 8;
        split_store8(v0, v1, t_hi + base, t_lo + base);
    }
}

extern "C" void kernel_launch(void* const* d_in, const int* in_sizes, int n_in,
                              void* d_out, int out_size, void* d_ws, size_t ws_size,
                              hipStream_t stream)
{
    const int*   method_code = (const int*)d_in[0];
    const float* code_emb    = (const float*)d_in[1];
    const float* sum_emb     = (const float*)d_in[2];
    const float* w_ih        = (const float*)d_in[3];
    const float* w_hh        = (const float*)d_in[4];
    const float* b_ih        = (const float*)d_in[5];
    const float* b_hh        = (const float*)d_in[6];
    const float* t_w         = (const float*)d_in[7];
    const float* t_b         = (const float*)d_in[8];
    const float* h_w         = (const float*)d_in[9];
    const float* h_b         = (const float*)d_in[10];
    const float* p_w         = (const float*)d_in[11];
    const float* p_b         = (const float*)d_in[12];
    float* out = (float*)d_out;

    float* h     = (float*)d_ws;                                   // 256*512 f32
    float* c     = h + BB * DD;                                    // 256*512 f32
    unsigned long long* keys = (unsigned long long*)(c + BB * DD); // 256
    unsigned short* a_hi   = (unsigned short*)(keys + BB);         // 256*512 (logits A)
    unsigned short* a_lo   = a_hi   + BB * DD;
    unsigned short* t_hi   = a_lo   + BB * DD;                     // t half of pre-A
    unsigned short* t_lo   = t_hi   + BB * DD;
    unsigned short* hp0_hi = t_lo   + BB * DD;                     // packed h, buffer 0
    unsigned short* hp0_lo = hp0_hi + BB * DD;
    unsigned short* hp1_hi = hp0_lo + BB * DD;                     // packed h, buffer 1
    unsigned short* hp1_lo = hp1_hi + BB * DD;
    unsigned short* w1_hi  = hp1_lo + BB * DD;                     // [w_ih|w_hh] perm 2048x1024
    unsigned short* w1_lo  = w1_hi  + (size_t)2048 * 1024;
    unsigned short* w2_hi  = w1_lo  + (size_t)2048 * 1024;         // [t_w|h_w] 512x1024
    unsigned short* w2_lo  = w2_hi  + (size_t)512 * 1024;
    unsigned short* p_hi   = w2_lo  + (size_t)512 * 1024;          // 20224*512
    unsigned short* p_lo   = p_hi   + (size_t)VS_PAD * DD;

    // zero h, c (contiguous) and hp0 pair (step-0 gates reads it)
    hipMemsetAsync(h, 0, (size_t)2 * BB * DD * sizeof(float), stream);
    hipMemsetAsync(hp0_hi, 0, (size_t)2 * BB * DD * sizeof(unsigned short), stream);
    init_keys_kernel<<<1, 256, 0, stream>>>(keys);
    split_pw_kernel<<<(VS_PAD * 64) / 256, 256, 0, stream>>>(p_w, p_hi, p_lo);
    split_wcat_kernel<1><<<1024, 256, 0, stream>>>(w_ih, w_hh, w1_hi, w1_lo);  // gate-interleaved
    split_wcat_kernel<0><<<256, 256, 0, stream>>>(t_w, h_w, w2_hi, w2_lo);     // R=512

    for (int s = 0; s < STEPS; s++) {
        const unsigned short* hin_hi  = (s & 1) ? hp1_hi : hp0_hi;
        const unsigned short* hin_lo  = (s & 1) ? hp1_lo : hp0_lo;
        unsigned short*       hout_hi = (s & 1) ? hp0_hi : hp1_hi;
        unsigned short*       hout_lo = (s & 1) ? hp0_lo : hp1_lo;

        // fused gather + gates GEMM + LSTM + h pack (M=256, N=2048, K=1024)
        gates_lstm_kernel<<<dim3(32, 8), 128, 0, stream>>>(
            sum_emb, keys, hin_hi, hin_lo, w1_hi, w1_lo, b_ih, b_hh,
            c, h, hout_hi, hout_lo);
        attn_kernel<<<256, 512, 0, stream>>>(method_code, code_emb, h, t_hi, t_lo, keys);
        // pre = tanh([t|h] @ [t_w|h_w]^T + t_b + h_b) -> packed logits-A (K split 4)
        pre_kernel<<<dim3(16, 16), 256, 0, stream>>>(
            t_hi, t_lo, hout_hi, hout_lo, w2_hi, w2_lo, t_b, h_b, a_hi, a_lo);
        // logits + greedy argmax (M=256, N=20224, K=512), 4 waves/block share B panels
        mfma_gemm<16, 2, 4><<<dim3(316, 2), 256, 0, stream>>>(
            a_hi, a_lo, nullptr, nullptr, p_hi, p_lo, p_b, nullptr,
            out, nullptr, nullptr, keys, s);
    }
}

// Round 7
// 2086.440 us; speedup vs baseline: 1.0082x; 1.0082x over previous
//
#include <hip/hip_runtime.h>
#include <math.h>

#define BB 256
#define LL 200
#define DD 512
#define VS 20000
#define VS_PAD 20224   // 316 * 64
#define STEPS 15

typedef __attribute__((ext_vector_type(8))) short bf16x8;
typedef __attribute__((ext_vector_type(4))) float f32x4;

// monotone mapping float -> uint32 preserving order
__device__ __forceinline__ unsigned int mono_key(float f) {
    unsigned int u = __float_as_uint(f);
    return (u & 0x80000000u) ? ~u : (u | 0x80000000u);
}

// bf16 round-to-nearest-even split helpers (bit ops, header-independent)
__device__ __forceinline__ unsigned short f2bf_rn(float x) {
    unsigned int u = __float_as_uint(x);
    unsigned int r = (u + 0x7FFFu + ((u >> 16) & 1u)) >> 16;
    return (unsigned short)r;
}
__device__ __forceinline__ float bf2f(unsigned short b) {
    return __uint_as_float((unsigned int)b << 16);
}

// split 8 consecutive floats into bf16 hi + lo residual, store 16B each
__device__ __forceinline__ void split_store8(float4 v0, float4 v1,
    unsigned short* __restrict__ hi, unsigned short* __restrict__ lo)
{
    ushort4 h0, h1, l0, l1;
    h0.x = f2bf_rn(v0.x); l0.x = f2bf_rn(v0.x - bf2f(h0.x));
    h0.y = f2bf_rn(v0.y); l0.y = f2bf_rn(v0.y - bf2f(h0.y));
    h0.z = f2bf_rn(v0.z); l0.z = f2bf_rn(v0.z - bf2f(h0.z));
    h0.w = f2bf_rn(v0.w); l0.w = f2bf_rn(v0.w - bf2f(h0.w));
    h1.x = f2bf_rn(v1.x); l1.x = f2bf_rn(v1.x - bf2f(h1.x));
    h1.y = f2bf_rn(v1.y); l1.y = f2bf_rn(v1.y - bf2f(h1.y));
    h1.z = f2bf_rn(v1.z); l1.z = f2bf_rn(v1.z - bf2f(h1.z));
    h1.w = f2bf_rn(v1.w); l1.w = f2bf_rn(v1.w - bf2f(h1.w));
    *(ushort4*)hi = h0; *(ushort4*)(hi + 4) = h1;
    *(ushort4*)lo = l0; *(ushort4*)(lo + 4) = l1;
}

// same split but into register fragments (for inline gather in the gates GEMM)
__device__ __forceinline__ void split_frag(float4 v0, float4 v1, bf16x8& hi, bf16x8& lo)
{
    float vv[8] = {v0.x, v0.y, v0.z, v0.w, v1.x, v1.y, v1.z, v1.w};
    #pragma unroll
    for (int j = 0; j < 8; j++) {
        unsigned short hb = f2bf_rn(vv[j]);
        hi[j] = (short)hb;
        lo[j] = (short)f2bf_rn(vv[j] - bf2f(hb));
    }
}

__global__ __launch_bounds__(256) void init_keys_kernel(unsigned long long* keys) {
    // low 32 bits = ~token ; decode token = ~(uint32)key. SOS token = 1.
    keys[threadIdx.x] = (unsigned long long)(unsigned int)(~1u);
}

// -------------------- fragment-order packing convention (16x16x32 bf16 MFMA):
// elem idx = panel*(NCH*512) + chunk*512 + lane*8 + j  where
// panel = row/16, chunk = k/32, lane = ((k%32)/8)*16 + row%16, j = k%8.
// A-side buffers are per-512-K halves: panel stride 8192 (16 chunks).

// one-time split of p_w [VS][512] -> hi/lo fragment order (K=512, panel stride 8192)
__global__ __launch_bounds__(256) void split_pw_kernel(
    const float* __restrict__ p_w, unsigned short* __restrict__ p_hi,
    unsigned short* __restrict__ p_lo)
{
    size_t q = (size_t)blockIdx.x * 256 + threadIdx.x;   // chunk id, VS_PAD*64 total
    int P   = (int)(q >> 10);
    int rem = (int)(q & 1023);
    int c   = rem >> 6;
    int l   = rem & 63;
    int row = P * 16 + (l & 15);
    int ks  = c * 32 + (l >> 4) * 8;
    float4 v0 = {0.f, 0.f, 0.f, 0.f}, v1 = {0.f, 0.f, 0.f, 0.f};
    if (row < VS) {
        const float* src = p_w + (size_t)row * DD + ks;
        v0 = *(const float4*)src;
        v1 = *(const float4*)(src + 4);
    }
    split_store8(v0, v1, p_hi + q * 8, p_lo + q * 8);
}

// one-time split of concat weights [R][1024] = [s0 | s1] (each [R][512]) -> hi/lo
// fragment order with panel stride 16384 (32 chunks). R must be multiple of 16.
// PERM=1 (gates W): packed panel P holds orig rows (P&3)*512 + (P>>2)*16 + col
// (gate-interleaved so one wave's 4 fragment columns = the 4 gates of one feature).
template <int PERM>
__global__ __launch_bounds__(256) void split_wcat_kernel(
    const float* __restrict__ s0, const float* __restrict__ s1,
    unsigned short* __restrict__ wh, unsigned short* __restrict__ wl)
{
    size_t q = (size_t)blockIdx.x * 256 + threadIdx.x;   // R*128 groups
    int P   = (int)(q >> 11);
    int rem = (int)(q & 2047);
    int c   = rem >> 6;
    int l   = rem & 63;
    int row;
    if (PERM) row = (P & 3) * 512 + (P >> 2) * 16 + (l & 15);
    else      row = P * 16 + (l & 15);
    int k   = c * 32 + (l >> 4) * 8;
    const float* src = (k < 512) ? (s0 + (size_t)row * DD + k)
                                 : (s1 + (size_t)row * DD + (k - 512));
    float4 v0 = *(const float4*)src;
    float4 v1 = *(const float4*)(src + 4);
    split_store8(v0, v1, wh + q * 8, wl + q * 8);
}

// -------------------- fused: token gather + gates GEMM + LSTM pointwise + h pack.
// 4-wave blocks; wave w owns one 16-row m-tile. XCD-aware swizzle: flat block id
// id = by*32+bx, XCD g = id%8 owns nt in [4g, 4g+4) -> per-XCD unique W1 slice
// = 1.05 MB (L2-resident) instead of ~4+ MB. Per-wave instruction stream identical
// to the proven R5 kernel. grid (32, 4) x 256 threads = 128 blocks, 512 waves.
__global__ __launch_bounds__(256) void gates_lstm_kernel(
    const float* __restrict__ sum_emb, const unsigned long long* __restrict__ keys,
    const unsigned short* __restrict__ hin_hi, const unsigned short* __restrict__ hin_lo,
    const unsigned short* __restrict__ w1h, const unsigned short* __restrict__ w1l,
    const float* __restrict__ bi, const float* __restrict__ bh,
    float* __restrict__ c, float* __restrict__ h,
    unsigned short* __restrict__ hout_hi, unsigned short* __restrict__ hout_lo)
{
    const int tid  = threadIdx.x;
    const int lane = tid & 63;
    const int wav  = tid >> 6;
    const int col = lane & 15;
    const int kg  = lane >> 4;
    // XCD swizzle (bijective over 128 blocks): g=id%8 -> nt group, k -> (nt, my)
    const int id  = blockIdx.y * 32 + blockIdx.x;
    const int g   = id & 7;
    const int k8  = id >> 3;              // 0..15
    const int nt  = (g << 2) + (k8 & 3);  // features nt*16 .. nt*16+15
    const int my  = k8 >> 2;              // 0..3
    const int m0  = (my * 4 + wav) * 16;

    unsigned int tok = ~(unsigned int)(keys[m0 + col] & 0xFFFFFFFFull);

    const size_t ahoff = (size_t)(m0 >> 4) * 8192 + (size_t)lane * 8;
    const size_t boff  = (size_t)(nt * 4) * 16384 + (size_t)lane * 8;

    f32x4 acc[4];
    #pragma unroll
    for (int gg = 0; gg < 4; gg++) acc[gg] = (f32x4){0.f, 0.f, 0.f, 0.f};

    bf16x8 fa_h[2], fa_l[2], fb_h[2][4], fb_l[2][4];

#define GL_LOAD(C, BUF)                                                            \
    {                                                                              \
        if ((C) < 16) {                                                            \
            const float* s_ = sum_emb + (size_t)tok * DD + (C) * 32 + kg * 8;      \
            float4 v0 = *(const float4*)s_;                                        \
            float4 v1 = *(const float4*)(s_ + 4);                                  \
            split_frag(v0, v1, fa_h[BUF], fa_l[BUF]);                              \
        } else {                                                                   \
            fa_h[BUF] = *(const bf16x8*)(hin_hi + ahoff + ((C) - 16) * 512);       \
            fa_l[BUF] = *(const bf16x8*)(hin_lo + ahoff + ((C) - 16) * 512);       \
        }                                                                          \
        _Pragma("unroll")                                                          \
        for (int gg = 0; gg < 4; gg++) {                                           \
            fb_h[BUF][gg] = *(const bf16x8*)(w1h + boff + (size_t)gg * 16384 + (C) * 512); \
            fb_l[BUF][gg] = *(const bf16x8*)(w1l + boff + (size_t)gg * 16384 + (C) * 512); \
        }                                                                          \
    }

    GL_LOAD(0, 0);
    #pragma unroll
    for (int cc = 0; cc < 32; cc++) {
        const int cur = cc & 1, nxt = cur ^ 1;
        if (cc < 31) GL_LOAD(cc + 1, nxt);
        #pragma unroll
        for (int gg = 0; gg < 4; gg++) {
            acc[gg] = __builtin_amdgcn_mfma_f32_16x16x32_bf16(fa_h[cur], fb_h[cur][gg], acc[gg], 0, 0, 0);
            acc[gg] = __builtin_amdgcn_mfma_f32_16x16x32_bf16(fa_h[cur], fb_l[cur][gg], acc[gg], 0, 0, 0);
            acc[gg] = __builtin_amdgcn_mfma_f32_16x16x32_bf16(fa_l[cur], fb_h[cur][gg], acc[gg], 0, 0, 0);
        }
    }
#undef GL_LOAD

    const int feat = nt * 16 + col;
    float bias[4];
    #pragma unroll
    for (int gg = 0; gg < 4; gg++)
        bias[gg] = bi[gg * 512 + feat] + bh[gg * 512 + feat];

    // LSTM pointwise (fp64, identical math), 4 cells/lane
    #pragma unroll
    for (int r = 0; r < 4; r++) {
        const int b = m0 + kg * 4 + r;
        float vi = acc[0][r] + bias[0];
        float vf = acc[1][r] + bias[1];
        float vg = acc[2][r] + bias[2];
        float vo = acc[3][r] + bias[3];
        double ig = 1.0 / (1.0 + exp(-(double)vi));
        double fg = 1.0 / (1.0 + exp(-(double)vf));
        double gv = tanh((double)vg);
        double og = 1.0 / (1.0 + exp(-(double)vo));
        size_t cidx = (size_t)b * DD + feat;
        double cn = fg * (double)c[cidx] + ig * gv;
        double hn = og * tanh(cn);
        c[cidx] = (float)cn;
        float hf = (float)hn;
        h[cidx] = hf;
        size_t hidx = (size_t)(b >> 4) * 8192 + (size_t)(feat >> 5) * 512
                    + (size_t)(((feat >> 3) & 3) * 16 + (b & 15)) * 8 + (feat & 7);
        unsigned short hb2 = f2bf_rn(hf);
        hout_hi[hidx] = hb2;
        hout_lo[hidx] = f2bf_rn(hf - bf2f(hb2));
    }
}

// -------------------- pre GEMM: tanh([t|h] @ [t_w|h_w]^T + t_b + h_b) -> packed A.
// 4-wave blocks, 16(m) x 32(n) tile, 4-way K-split (wave w = chunks 8w..8w+7).
// Partials reduced via LDS; tanh epilogue spread over 256 threads (2 cells each).
// grid (16 n-tiles, 16 m-tiles) = 1024 waves.
__global__ __launch_bounds__(256) void pre_kernel(
    const unsigned short* __restrict__ t_hi, const unsigned short* __restrict__ t_lo,
    const unsigned short* __restrict__ h_hi, const unsigned short* __restrict__ h_lo,
    const unsigned short* __restrict__ w2h, const unsigned short* __restrict__ w2l,
    const float* __restrict__ tb, const float* __restrict__ hbv,
    unsigned short* __restrict__ o_hi, unsigned short* __restrict__ o_lo)
{
    const int tid  = threadIdx.x;
    const int lane = tid & 63;
    const int wav  = tid >> 6;        // K-split: absolute chunks wav*8 .. wav*8+7
    const int col  = lane & 15;
    const int kg   = lane >> 4;
    const int m0   = blockIdx.y * 16;
    const int n0   = blockIdx.x * 32;

    const unsigned short* ah = (wav < 2) ? t_hi : h_hi;
    const unsigned short* al = (wav < 2) ? t_lo : h_lo;
    const size_t aoff = (size_t)(m0 >> 4) * 8192 + (size_t)lane * 8
                      + (size_t)((wav & 1) * 8) * 512;
    const size_t boff = (size_t)(n0 >> 4) * 16384 + (size_t)lane * 8
                      + (size_t)(wav * 8) * 512;

    f32x4 acc[2];
    acc[0] = (f32x4){0.f, 0.f, 0.f, 0.f};
    acc[1] = (f32x4){0.f, 0.f, 0.f, 0.f};

    bf16x8 fa_h[2], fa_l[2], fb_h[2][2], fb_l[2][2];
    fa_h[0] = *(const bf16x8*)(ah + aoff);
    fa_l[0] = *(const bf16x8*)(al + aoff);
    #pragma unroll
    for (int g = 0; g < 2; g++) {
        fb_h[0][g] = *(const bf16x8*)(w2h + boff + (size_t)g * 16384);
        fb_l[0][g] = *(const bf16x8*)(w2l + boff + (size_t)g * 16384);
    }
    #pragma unroll
    for (int cc = 0; cc < 8; cc++) {
        const int cur = cc & 1, nxt = cur ^ 1;
        if (cc < 7) {
            const int off = (cc + 1) * 512;
            fa_h[nxt] = *(const bf16x8*)(ah + aoff + off);
            fa_l[nxt] = *(const bf16x8*)(al + aoff + off);
            #pragma unroll
            for (int g = 0; g < 2; g++) {
                fb_h[nxt][g] = *(const bf16x8*)(w2h + boff + (size_t)g * 16384 + off);
                fb_l[nxt][g] = *(const bf16x8*)(w2l + boff + (size_t)g * 16384 + off);
            }
        }
        #pragma unroll
        for (int g = 0; g < 2; g++) {
            acc[g] = __builtin_amdgcn_mfma_f32_16x16x32_bf16(fa_h[cur], fb_h[cur][g], acc[g], 0, 0, 0);
            acc[g] = __builtin_amdgcn_mfma_f32_16x16x32_bf16(fa_h[cur], fb_l[cur][g], acc[g], 0, 0, 0);
            acc[g] = __builtin_amdgcn_mfma_f32_16x16x32_bf16(fa_l[cur], fb_h[cur][g], acc[g], 0, 0, 0);
        }
    }

    __shared__ float psum[4][16][32];
    #pragma unroll
    for (int g = 0; g < 2; g++)
        #pragma unroll
        for (int r = 0; r < 4; r++)
            psum[wav][kg * 4 + r][g * 16 + col] = acc[g][r];
    __syncthreads();

    #pragma unroll
    for (int e = 0; e < 2; e++) {
        const int idx  = tid * 2 + e;
        const int row  = idx >> 5, coln = idx & 31;
        const int b    = m0 + row;
        const int n    = n0 + coln;
        float accs = (psum[0][row][coln] + psum[1][row][coln])
                   + (psum[2][row][coln] + psum[3][row][coln]);
        float val = accs + (tb[n] + hbv[n]);
        float v2 = (float)tanh((double)val);
        int P = b >> 4, colb = b & 15;
        int cc2 = n >> 5, kgg = (n >> 3) & 3, jj = n & 7;
        size_t oidx = (size_t)P * 8192 + (size_t)cc2 * 512
                    + (size_t)(kgg * 16 + colb) * 8 + jj;
        unsigned short hb = f2bf_rn(v2);
        o_hi[oidx] = hb;
        o_lo[oidx] = f2bf_rn(v2 - bf2f(hb));
    }
}

// -------------------- logits GEMM (bf16x3 MFMA) + bias + store + argmax.
// 32(m) x 64(n) tile per wave, WPB waves per block sharing B panels.
// XCD-aware swizzle: the two m-halves (by=0/1) of the same n-column become
// ADJACENT blocks on the SAME XCD -> second block's B panels are L2-hot.
// Per-wave instruction stream identical to R5 -> bit-identical output.
template <int NCH, int EPI, int WPB>
__global__ __launch_bounds__(64 * WPB, 3) void mfma_gemm(
    const unsigned short* __restrict__ a0h, const unsigned short* __restrict__ a0l,
    const unsigned short* __restrict__ a1h, const unsigned short* __restrict__ a1l,
    const unsigned short* __restrict__ bmh, const unsigned short* __restrict__ bml,
    const float* __restrict__ bias0, const float* __restrict__ bias1,
    float* __restrict__ outp,
    unsigned short* __restrict__ o_hi, unsigned short* __restrict__ o_lo,
    unsigned long long* __restrict__ keys, int s)
{
    const int tid  = threadIdx.x;
    const int lane = tid & 63;
    const int wav  = tid >> 6;
    const int col = lane & 15;        // fragment row (A) / column (B)
    const int kg  = lane >> 4;        // k-group 0..3
    // XCD swizzle (bijective; requires total blocks % 8 == 0, gridDim.y == 2):
    // XCD g gets 2*gridDim.x/8 consecutive (bx,by) pairs ordered by bx then by.
    const int id  = blockIdx.y * gridDim.x + blockIdx.x;
    const int nb8 = (gridDim.x * gridDim.y) >> 3;    // blocks per XCD
    const int g   = id & 7;
    const int p   = g * nb8 + (id >> 3);
    const int bxx = p >> 1;
    const int byy = p & 1;
    const int m0 = (byy * WPB + wav) * 32;
    const int n0 = bxx * 64;

    const size_t aoff = (size_t)(m0 >> 4) * 8192 + (size_t)lane * 8;
    const size_t boff = (size_t)(n0 >> 4) * (NCH * 512) + (size_t)lane * 8;

    f32x4 acc[2][4];
    #pragma unroll
    for (int f = 0; f < 2; f++)
        #pragma unroll
        for (int gg = 0; gg < 4; gg++)
            acc[f][gg] = (f32x4){0.f, 0.f, 0.f, 0.f};

    bf16x8 fah[2][2], fal[2][2], fbh[2][4], fbl[2][4];

#define LOAD_CHUNK(C, BUF)                                                         \
    {                                                                              \
        const unsigned short* ah_ = ((NCH == 16) || ((C) < 16)) ? a0h : a1h;       \
        const unsigned short* al_ = ((NCH == 16) || ((C) < 16)) ? a0l : a1l;       \
        const int cc_ = (C) & 15;                                                  \
        _Pragma("unroll")                                                          \
        for (int f = 0; f < 2; f++) {                                              \
            fah[BUF][f] = *(const bf16x8*)(ah_ + aoff + (size_t)f * 8192 + cc_ * 512); \
            fal[BUF][f] = *(const bf16x8*)(al_ + aoff + (size_t)f * 8192 + cc_ * 512); \
        }                                                                          \
        _Pragma("unroll")                                                          \
        for (int gg = 0; gg < 4; gg++) {                                           \
            fbh[BUF][gg] = *(const bf16x8*)(bmh + boff + (size_t)gg * (NCH * 512) + (C) * 512); \
            fbl[BUF][gg] = *(const bf16x8*)(bml + boff + (size_t)gg * (NCH * 512) + (C) * 512); \
        }                                                                          \
    }

    LOAD_CHUNK(0, 0);
    #pragma unroll
    for (int c = 0; c < NCH; c++) {
        const int cur = c & 1, nxt = cur ^ 1;
        if (c < NCH - 1) LOAD_CHUNK(c + 1, nxt);
        #pragma unroll
        for (int f = 0; f < 2; f++)
            #pragma unroll
            for (int gg = 0; gg < 4; gg++) {
                acc[f][gg] = __builtin_amdgcn_mfma_f32_16x16x32_bf16(fah[cur][f], fbh[cur][gg], acc[f][gg], 0, 0, 0);
                acc[f][gg] = __builtin_amdgcn_mfma_f32_16x16x32_bf16(fah[cur][f], fbl[cur][gg], acc[f][gg], 0, 0, 0);
                acc[f][gg] = __builtin_amdgcn_mfma_f32_16x16x32_bf16(fal[cur][f], fbh[cur][gg], acc[f][gg], 0, 0, 0);
            }
    }
#undef LOAD_CHUNK

    // bias per n-col of this lane (col fixed per lane)
    float bias[4];
    #pragma unroll
    for (int gg = 0; gg < 4; gg++) {
        int v = n0 + gg * 16 + col;
        bias[gg] = (v < VS) ? bias0[v] : 0.f;
    }

    // epilogue (C/D: col = lane&15, row = kg*4 + reg)
    #pragma unroll
    for (int f = 0; f < 2; f++) {
        #pragma unroll
        for (int r = 0; r < 4; r++) {
            const int b = m0 + f * 16 + kg * 4 + r;
            float* orow = outp + ((size_t)b * STEPS + s) * VS;
            unsigned long long kmax = 0ull;
            #pragma unroll
            for (int gg = 0; gg < 4; gg++) {
                int v = n0 + gg * 16 + col;
                float val = acc[f][gg][r] + bias[gg];
                if (v < VS) {
                    orow[v] = val;
                    unsigned long long key =
                        ((unsigned long long)mono_key(val) << 32) |
                        (unsigned long long)(unsigned int)(~v);
                    if (key > kmax) kmax = key;
                }
            }
            #pragma unroll
            for (int mk = 1; mk < 16; mk <<= 1) {
                unsigned long long o = __shfl_xor(kmax, mk, 64);
                if (o > kmax) kmax = o;
            }
            if (col == 0) {
                // load-filter: stale reads are only ever lower -> conservative
                if (kmax > *(volatile unsigned long long*)&keys[b])
                    atomicMax(&keys[b], kmax);
            }
        }
    }
}

// -------------------- attention: scores -> softmax -> weighted sum. One block per
// batch row, 512 threads (8 waves); waves stride l by 8 in both passes.
// Epilogue packs t into hi/lo fragment order and resets keys[b].
__global__ __launch_bounds__(512) void attn_kernel(
    const int* __restrict__ method_code, const float* __restrict__ code_emb,
    const float* __restrict__ h, unsigned short* __restrict__ t_hi,
    unsigned short* __restrict__ t_lo, unsigned long long* __restrict__ keys)
{
    const int b = blockIdx.x;
    const int tid = threadIdx.x;
    const int lane = tid & 63, wave = tid >> 6;

    __shared__ float sc[LL];        // scores, then attn weights
    __shared__ int   rows[LL];
    __shared__ float fred[256];
    __shared__ double dred[256];
    __shared__ float ts[DD];
    __shared__ float part[8][DD];

    if (tid < LL) rows[tid] = method_code[b * LL + tid];
    if (tid == 0) keys[b] = 0ull;   // safe: gates GEMM already consumed last step's keys
    // h fragment in registers: 8 consecutive per lane (same for all 8 waves)
    const float* hb = h + (size_t)b * DD;
    float4 h0 = *(const float4*)(hb + lane * 8);
    float4 h1 = *(const float4*)(hb + lane * 8 + 4);
    __syncthreads();

    // pass 1: scores[l] = h . e_l   (8 waves stride over l)
    for (int l = wave; l < LL; l += 8) {
        const float* e = code_emb + (size_t)rows[l] * DD + lane * 8;
        float4 e0 = *(const float4*)e;
        float4 e1 = *(const float4*)(e + 4);
        float p = h0.x * e0.x + h0.y * e0.y + h0.z * e0.z + h0.w * e0.w
                + h1.x * e1.x + h1.y * e1.y + h1.z * e1.z + h1.w * e1.w;
        #pragma unroll
        for (int m = 1; m < 64; m <<= 1) p += __shfl_xor(p, m, 64);
        if (lane == 0) sc[l] = p;
    }
    __syncthreads();

    // softmax over 200 (max-subtract, fp64 exp & sum); reduction on first 256 threads
    if (tid < 256) fred[tid] = (tid < LL) ? sc[tid] : -INFINITY;
    __syncthreads();
    for (int s2 = 128; s2 > 0; s2 >>= 1) {
        if (tid < s2) fred[tid] = fmaxf(fred[tid], fred[tid + s2]);
        __syncthreads();
    }
    float smax = fred[0];
    __syncthreads();
    double w = (tid < LL) ? exp((double)sc[tid] - (double)smax) : 0.0;
    if (tid < 256) dred[tid] = w;
    __syncthreads();
    for (int s2 = 128; s2 > 0; s2 >>= 1) {
        if (tid < s2) dred[tid] += dred[tid + s2];
        __syncthreads();
    }
    double ssum = dred[0];
    __syncthreads();
    if (tid < LL) sc[tid] = (float)(w / ssum);
    __syncthreads();

    // pass 2: 8-way wave-split over l; lane owns 8 dims (same addressing as pass 1)
    float pa[8] = {0.f, 0.f, 0.f, 0.f, 0.f, 0.f, 0.f, 0.f};
    for (int l = wave; l < LL; l += 8) {
        float wl = sc[l];
        const float* e = code_emb + (size_t)rows[l] * DD + lane * 8;
        float4 e0 = *(const float4*)e;
        float4 e1 = *(const float4*)(e + 4);
        pa[0] = fmaf(wl, e0.x, pa[0]); pa[1] = fmaf(wl, e0.y, pa[1]);
        pa[2] = fmaf(wl, e0.z, pa[2]); pa[3] = fmaf(wl, e0.w, pa[3]);
        pa[4] = fmaf(wl, e1.x, pa[4]); pa[5] = fmaf(wl, e1.y, pa[5]);
        pa[6] = fmaf(wl, e1.z, pa[6]); pa[7] = fmaf(wl, e1.w, pa[7]);
    }
    #pragma unroll
    for (int j = 0; j < 8; j++) part[wave][lane * 8 + j] = pa[j];
    __syncthreads();

    // combine partials: each thread owns 1 dim, fixed pairwise order
    {
        const int d = tid;   // 512 threads, 512 dims
        float v01 = part[0][d] + part[1][d];
        float v23 = part[2][d] + part[3][d];
        float v45 = part[4][d] + part[5][d];
        float v67 = part[6][d] + part[7][d];
        ts[d] = (v01 + v23) + (v45 + v67);
    }
    __syncthreads();

    // pack t row into fragment order: 64 lanes x 8 consecutive dims
    if (tid < 64) {
        const int cc = tid >> 2, kgg = tid & 3;
        const float* src = ts + cc * 32 + kgg * 8;   // = ts + tid*8 (contiguous)
        float4 v0 = *(const float4*)src;
        float4 v1 = *(const float4*)(src + 4);
        size_t base = (size_t)(b >> 4) * 8192 + (size_t)cc * 512
                    + (size_t)(kgg * 16 + (b & 15)) * 8;
        split_store8(v0, v1, t_hi + base, t_lo + base);
    }
}

extern "C" void kernel_launch(void* const* d_in, const int* in_sizes, int n_in,
                              void* d_out, int out_size, void* d_ws, size_t ws_size,
                              hipStream_t stream)
{
    const int*   method_code = (const int*)d_in[0];
    const float* code_emb    = (const float*)d_in[1];
    const float* sum_emb     = (const float*)d_in[2];
    const float* w_ih        = (const float*)d_in[3];
    const float* w_hh        = (const float*)d_in[4];
    const float* b_ih        = (const float*)d_in[5];
    const float* b_hh        = (const float*)d_in[6];
    const float* t_w         = (const float*)d_in[7];
    const float* t_b         = (const float*)d_in[8];
    const float* h_w         = (const float*)d_in[9];
    const float* h_b         = (const float*)d_in[10];
    const float* p_w         = (const float*)d_in[11];
    const float* p_b         = (const float*)d_in[12];
    float* out = (float*)d_out;

    float* h     = (float*)d_ws;                                   // 256*512 f32
    float* c     = h + BB * DD;                                    // 256*512 f32
    unsigned long long* keys = (unsigned long long*)(c + BB * DD); // 256
    unsigned short* a_hi   = (unsigned short*)(keys + BB);         // 256*512 (logits A)
    unsigned short* a_lo   = a_hi   + BB * DD;
    unsigned short* t_hi   = a_lo   + BB * DD;                     // t half of pre-A
    unsigned short* t_lo   = t_hi   + BB * DD;
    unsigned short* hp0_hi = t_lo   + BB * DD;                     // packed h, buffer 0
    unsigned short* hp0_lo = hp0_hi + BB * DD;
    unsigned short* hp1_hi = hp0_lo + BB * DD;                     // packed h, buffer 1
    unsigned short* hp1_lo = hp1_hi + BB * DD;
    unsigned short* w1_hi  = hp1_lo + BB * DD;                     // [w_ih|w_hh] perm 2048x1024
    unsigned short* w1_lo  = w1_hi  + (size_t)2048 * 1024;
    unsigned short* w2_hi  = w1_lo  + (size_t)2048 * 1024;         // [t_w|h_w] 512x1024
    unsigned short* w2_lo  = w2_hi  + (size_t)512 * 1024;
    unsigned short* p_hi   = w2_lo  + (size_t)512 * 1024;          // 20224*512
    unsigned short* p_lo   = p_hi   + (size_t)VS_PAD * DD;

    // zero h, c (contiguous) and hp0 pair (step-0 gates reads it)
    hipMemsetAsync(h, 0, (size_t)2 * BB * DD * sizeof(float), stream);
    hipMemsetAsync(hp0_hi, 0, (size_t)2 * BB * DD * sizeof(unsigned short), stream);
    init_keys_kernel<<<1, 256, 0, stream>>>(keys);
    split_pw_kernel<<<(VS_PAD * 64) / 256, 256, 0, stream>>>(p_w, p_hi, p_lo);
    split_wcat_kernel<1><<<1024, 256, 0, stream>>>(w_ih, w_hh, w1_hi, w1_lo);  // gate-interleaved
    split_wcat_kernel<0><<<256, 256, 0, stream>>>(t_w, h_w, w2_hi, w2_lo);     // R=512

    for (int s = 0; s < STEPS; s++) {
        const unsigned short* hin_hi  = (s & 1) ? hp1_hi : hp0_hi;
        const unsigned short* hin_lo  = (s & 1) ? hp1_lo : hp0_lo;
        unsigned short*       hout_hi = (s & 1) ? hp0_hi : hp1_hi;
        unsigned short*       hout_lo = (s & 1) ? hp0_lo : hp1_lo;

        // fused gather + gates GEMM + LSTM + h pack (M=256, N=2048, K=1024)
        gates_lstm_kernel<<<dim3(32, 4), 256, 0, stream>>>(
            sum_emb, keys, hin_hi, hin_lo, w1_hi, w1_lo, b_ih, b_hh,
            c, h, hout_hi, hout_lo);
        attn_kernel<<<256, 512, 0, stream>>>(method_code, code_emb, h, t_hi, t_lo, keys);
        // pre = tanh([t|h] @ [t_w|h_w]^T + t_b + h_b) -> packed logits-A (K split 4)
        pre_kernel<<<dim3(16, 16), 256, 0, stream>>>(
            t_hi, t_lo, hout_hi, hout_lo, w2_hi, w2_lo, t_b, h_b, a_hi, a_lo);
        // logits + greedy argmax (M=256, N=20224, K=512), 4 waves/block share B panels
        mfma_gemm<16, 2, 4><<<dim3(316, 2), 256, 0, stream>>>(
            a_hi, a_lo, nullptr, nullptr, p_hi, p_lo, p_b, nullptr,
            out, nullptr, nullptr, keys, s);
    }
}

// Round 8
// 1948.901 us; speedup vs baseline: 1.0793x; 1.0706x over previous
//
#include <hip/hip_runtime.h>
#include <math.h>

#define BB 256
#define LL 200
#define DD 512
#define VS 20000
#define VS_PAD 20224   // 316 * 64
#define STEPS 15

typedef __attribute__((ext_vector_type(8))) short bf16x8;
typedef __attribute__((ext_vector_type(4))) float f32x4;

// monotone mapping float -> uint32 preserving order
__device__ __forceinline__ unsigned int mono_key(float f) {
    unsigned int u = __float_as_uint(f);
    return (u & 0x80000000u) ? ~u : (u | 0x80000000u);
}

// bf16 round-to-nearest-even split helpers (bit ops, header-independent)
__device__ __forceinline__ unsigned short f2bf_rn(float x) {
    unsigned int u = __float_as_uint(x);
    unsigned int r = (u + 0x7FFFu + ((u >> 16) & 1u)) >> 16;
    return (unsigned short)r;
}
__device__ __forceinline__ float bf2f(unsigned short b) {
    return __uint_as_float((unsigned int)b << 16);
}

// split 8 consecutive floats into bf16 hi + lo residual, store 16B each
__device__ __forceinline__ void split_store8(float4 v0, float4 v1,
    unsigned short* __restrict__ hi, unsigned short* __restrict__ lo)
{
    ushort4 h0, h1, l0, l1;
    h0.x = f2bf_rn(v0.x); l0.x = f2bf_rn(v0.x - bf2f(h0.x));
    h0.y = f2bf_rn(v0.y); l0.y = f2bf_rn(v0.y - bf2f(h0.y));
    h0.z = f2bf_rn(v0.z); l0.z = f2bf_rn(v0.z - bf2f(h0.z));
    h0.w = f2bf_rn(v0.w); l0.w = f2bf_rn(v0.w - bf2f(h0.w));
    h1.x = f2bf_rn(v1.x); l1.x = f2bf_rn(v1.x - bf2f(h1.x));
    h1.y = f2bf_rn(v1.y); l1.y = f2bf_rn(v1.y - bf2f(h1.y));
    h1.z = f2bf_rn(v1.z); l1.z = f2bf_rn(v1.z - bf2f(h1.z));
    h1.w = f2bf_rn(v1.w); l1.w = f2bf_rn(v1.w - bf2f(h1.w));
    *(ushort4*)hi = h0; *(ushort4*)(hi + 4) = h1;
    *(ushort4*)lo = l0; *(ushort4*)(lo + 4) = l1;
}

// same split but into register fragments (for inline gather in the gates GEMM)
__device__ __forceinline__ void split_frag(float4 v0, float4 v1, bf16x8& hi, bf16x8& lo)
{
    float vv[8] = {v0.x, v0.y, v0.z, v0.w, v1.x, v1.y, v1.z, v1.w};
    #pragma unroll
    for (int j = 0; j < 8; j++) {
        unsigned short hb = f2bf_rn(vv[j]);
        hi[j] = (short)hb;
        lo[j] = (short)f2bf_rn(vv[j] - bf2f(hb));
    }
}

__global__ __launch_bounds__(256) void init_keys_kernel(unsigned long long* keys) {
    // low 32 bits = ~token ; decode token = ~(uint32)key. SOS token = 1.
    keys[threadIdx.x] = (unsigned long long)(unsigned int)(~1u);
}

// -------------------- fragment-order packing convention (16x16x32 bf16 MFMA):
// elem idx = panel*(NCH*512) + chunk*512 + lane*8 + j  where
// panel = row/16, chunk = k/32, lane = ((k%32)/8)*16 + row%16, j = k%8.
// A-side buffers are per-512-K halves: panel stride 8192 (16 chunks).

// one-time split of p_w [VS][512] -> hi/lo fragment order (K=512, panel stride 8192)
__global__ __launch_bounds__(256) void split_pw_kernel(
    const float* __restrict__ p_w, unsigned short* __restrict__ p_hi,
    unsigned short* __restrict__ p_lo)
{
    size_t q = (size_t)blockIdx.x * 256 + threadIdx.x;   // chunk id, VS_PAD*64 total
    int P   = (int)(q >> 10);
    int rem = (int)(q & 1023);
    int c   = rem >> 6;
    int l   = rem & 63;
    int row = P * 16 + (l & 15);
    int ks  = c * 32 + (l >> 4) * 8;
    float4 v0 = {0.f, 0.f, 0.f, 0.f}, v1 = {0.f, 0.f, 0.f, 0.f};
    if (row < VS) {
        const float* src = p_w + (size_t)row * DD + ks;
        v0 = *(const float4*)src;
        v1 = *(const float4*)(src + 4);
    }
    split_store8(v0, v1, p_hi + q * 8, p_lo + q * 8);
}

// one-time split of concat weights [R][1024] = [s0 | s1] (each [R][512]) -> hi/lo
// fragment order with panel stride 16384 (32 chunks). R must be multiple of 16.
// PERM=1 (gates W): packed panel P holds orig rows (P&3)*512 + (P>>2)*16 + col
// (gate-interleaved so one wave's 4 fragment columns = the 4 gates of one feature).
template <int PERM>
__global__ __launch_bounds__(256) void split_wcat_kernel(
    const float* __restrict__ s0, const float* __restrict__ s1,
    unsigned short* __restrict__ wh, unsigned short* __restrict__ wl)
{
    size_t q = (size_t)blockIdx.x * 256 + threadIdx.x;   // R*128 groups
    int P   = (int)(q >> 11);
    int rem = (int)(q & 2047);
    int c   = rem >> 6;
    int l   = rem & 63;
    int row;
    if (PERM) row = (P & 3) * 512 + (P >> 2) * 16 + (l & 15);
    else      row = P * 16 + (l & 15);
    int k   = c * 32 + (l >> 4) * 8;
    const float* src = (k < 512) ? (s0 + (size_t)row * DD + k)
                                 : (s1 + (size_t)row * DD + (k - 512));
    float4 v0 = *(const float4*)src;
    float4 v1 = *(const float4*)(src + 4);
    split_store8(v0, v1, wh + q * 8, wl + q * 8);
}

// -------------------- fused: token gather + gates GEMM + LSTM pointwise + h pack.
// 4-wave blocks; wave w owns m-tile (blockIdx.y*4+w)*16 (proven R5 config).
// 16(m) x 64(n = 16 feats x 4 gates) tile, K=32 chunks.
// Epilogue = fp64 LSTM pointwise (4 cells/lane), writes c, h and packed h_out.
// grid (32 nt, 4) x 256 threads = 512 waves.
__global__ __launch_bounds__(256) void gates_lstm_kernel(
    const float* __restrict__ sum_emb, const unsigned long long* __restrict__ keys,
    const unsigned short* __restrict__ hin_hi, const unsigned short* __restrict__ hin_lo,
    const unsigned short* __restrict__ w1h, const unsigned short* __restrict__ w1l,
    const float* __restrict__ bi, const float* __restrict__ bh,
    float* __restrict__ c, float* __restrict__ h,
    unsigned short* __restrict__ hout_hi, unsigned short* __restrict__ hout_lo)
{
    const int tid  = threadIdx.x;
    const int lane = tid & 63;
    const int wav  = tid >> 6;
    const int col = lane & 15;
    const int kg  = lane >> 4;
    const int m0  = (blockIdx.y * 4 + wav) * 16;
    const int nt  = blockIdx.x;               // features nt*16 .. nt*16+15

    unsigned int tok = ~(unsigned int)(keys[m0 + col] & 0xFFFFFFFFull);

    const size_t ahoff = (size_t)(m0 >> 4) * 8192 + (size_t)lane * 8;
    const size_t boff  = (size_t)(nt * 4) * 16384 + (size_t)lane * 8;

    f32x4 acc[4];
    #pragma unroll
    for (int g = 0; g < 4; g++) acc[g] = (f32x4){0.f, 0.f, 0.f, 0.f};

    bf16x8 fa_h[2], fa_l[2], fb_h[2][4], fb_l[2][4];

#define GL_LOAD(C, BUF)                                                            \
    {                                                                              \
        if ((C) < 16) {                                                            \
            const float* s_ = sum_emb + (size_t)tok * DD + (C) * 32 + kg * 8;      \
            float4 v0 = *(const float4*)s_;                                        \
            float4 v1 = *(const float4*)(s_ + 4);                                  \
            split_frag(v0, v1, fa_h[BUF], fa_l[BUF]);                              \
        } else {                                                                   \
            fa_h[BUF] = *(const bf16x8*)(hin_hi + ahoff + ((C) - 16) * 512);       \
            fa_l[BUF] = *(const bf16x8*)(hin_lo + ahoff + ((C) - 16) * 512);       \
        }                                                                          \
        _Pragma("unroll")                                                          \
        for (int g = 0; g < 4; g++) {                                              \
            fb_h[BUF][g] = *(const bf16x8*)(w1h + boff + (size_t)g * 16384 + (C) * 512); \
            fb_l[BUF][g] = *(const bf16x8*)(w1l + boff + (size_t)g * 16384 + (C) * 512); \
        }                                                                          \
    }

    GL_LOAD(0, 0);
    #pragma unroll
    for (int cc = 0; cc < 32; cc++) {
        const int cur = cc & 1, nxt = cur ^ 1;
        if (cc < 31) GL_LOAD(cc + 1, nxt);
        #pragma unroll
        for (int g = 0; g < 4; g++) {
            acc[g] = __builtin_amdgcn_mfma_f32_16x16x32_bf16(fa_h[cur], fb_h[cur][g], acc[g], 0, 0, 0);
            acc[g] = __builtin_amdgcn_mfma_f32_16x16x32_bf16(fa_h[cur], fb_l[cur][g], acc[g], 0, 0, 0);
            acc[g] = __builtin_amdgcn_mfma_f32_16x16x32_bf16(fa_l[cur], fb_h[cur][g], acc[g], 0, 0, 0);
        }
    }
#undef GL_LOAD

    const int feat = nt * 16 + col;
    float bias[4];
    #pragma unroll
    for (int g = 0; g < 4; g++)
        bias[g] = bi[g * 512 + feat] + bh[g * 512 + feat];

    // LSTM pointwise (fp64, identical math), 4 cells/lane
    #pragma unroll
    for (int r = 0; r < 4; r++) {
        const int b = m0 + kg * 4 + r;
        float vi = acc[0][r] + bias[0];
        float vf = acc[1][r] + bias[1];
        float vg = acc[2][r] + bias[2];
        float vo = acc[3][r] + bias[3];
        double ig = 1.0 / (1.0 + exp(-(double)vi));
        double fg = 1.0 / (1.0 + exp(-(double)vf));
        double gv = tanh((double)vg);
        double og = 1.0 / (1.0 + exp(-(double)vo));
        size_t cidx = (size_t)b * DD + feat;
        double cn = fg * (double)c[cidx] + ig * gv;
        double hn = og * tanh(cn);
        c[cidx] = (float)cn;
        float hf = (float)hn;
        h[cidx] = hf;
        size_t hidx = (size_t)(b >> 4) * 8192 + (size_t)(feat >> 5) * 512
                    + (size_t)(((feat >> 3) & 3) * 16 + (b & 15)) * 8 + (feat & 7);
        unsigned short hb2 = f2bf_rn(hf);
        hout_hi[hidx] = hb2;
        hout_lo[hidx] = f2bf_rn(hf - bf2f(hb2));
    }
}

// -------------------- pre GEMM: tanh([t|h] @ [t_w|h_w]^T + t_b + h_b) -> packed A.
// 4-wave blocks, 16(m) x 32(n) tile, 4-way K-split (wave w = chunks 8w..8w+7).
// Partials reduced via LDS; tanh epilogue spread over 256 threads (2 cells each).
// grid (16 n-tiles, 16 m-tiles) = 1024 waves.
__global__ __launch_bounds__(256) void pre_kernel(
    const unsigned short* __restrict__ t_hi, const unsigned short* __restrict__ t_lo,
    const unsigned short* __restrict__ h_hi, const unsigned short* __restrict__ h_lo,
    const unsigned short* __restrict__ w2h, const unsigned short* __restrict__ w2l,
    const float* __restrict__ tb, const float* __restrict__ hbv,
    unsigned short* __restrict__ o_hi, unsigned short* __restrict__ o_lo)
{
    const int tid  = threadIdx.x;
    const int lane = tid & 63;
    const int wav  = tid >> 6;        // K-split: absolute chunks wav*8 .. wav*8+7
    const int col  = lane & 15;
    const int kg   = lane >> 4;
    const int m0   = blockIdx.y * 16;
    const int n0   = blockIdx.x * 32;

    const unsigned short* ah = (wav < 2) ? t_hi : h_hi;
    const unsigned short* al = (wav < 2) ? t_lo : h_lo;
    const size_t aoff = (size_t)(m0 >> 4) * 8192 + (size_t)lane * 8
                      + (size_t)((wav & 1) * 8) * 512;
    const size_t boff = (size_t)(n0 >> 4) * 16384 + (size_t)lane * 8
                      + (size_t)(wav * 8) * 512;

    f32x4 acc[2];
    acc[0] = (f32x4){0.f, 0.f, 0.f, 0.f};
    acc[1] = (f32x4){0.f, 0.f, 0.f, 0.f};

    bf16x8 fa_h[2], fa_l[2], fb_h[2][2], fb_l[2][2];
    fa_h[0] = *(const bf16x8*)(ah + aoff);
    fa_l[0] = *(const bf16x8*)(al + aoff);
    #pragma unroll
    for (int g = 0; g < 2; g++) {
        fb_h[0][g] = *(const bf16x8*)(w2h + boff + (size_t)g * 16384);
        fb_l[0][g] = *(const bf16x8*)(w2l + boff + (size_t)g * 16384);
    }
    #pragma unroll
    for (int cc = 0; cc < 8; cc++) {
        const int cur = cc & 1, nxt = cur ^ 1;
        if (cc < 7) {
            const int off = (cc + 1) * 512;
            fa_h[nxt] = *(const bf16x8*)(ah + aoff + off);
            fa_l[nxt] = *(const bf16x8*)(al + aoff + off);
            #pragma unroll
            for (int g = 0; g < 2; g++) {
                fb_h[nxt][g] = *(const bf16x8*)(w2h + boff + (size_t)g * 16384 + off);
                fb_l[nxt][g] = *(const bf16x8*)(w2l + boff + (size_t)g * 16384 + off);
            }
        }
        #pragma unroll
        for (int g = 0; g < 2; g++) {
            acc[g] = __builtin_amdgcn_mfma_f32_16x16x32_bf16(fa_h[cur], fb_h[cur][g], acc[g], 0, 0, 0);
            acc[g] = __builtin_amdgcn_mfma_f32_16x16x32_bf16(fa_h[cur], fb_l[cur][g], acc[g], 0, 0, 0);
            acc[g] = __builtin_amdgcn_mfma_f32_16x16x32_bf16(fa_l[cur], fb_h[cur][g], acc[g], 0, 0, 0);
        }
    }

    __shared__ float psum[4][16][32];
    #pragma unroll
    for (int g = 0; g < 2; g++)
        #pragma unroll
        for (int r = 0; r < 4; r++)
            psum[wav][kg * 4 + r][g * 16 + col] = acc[g][r];
    __syncthreads();

    #pragma unroll
    for (int e = 0; e < 2; e++) {
        const int idx  = tid * 2 + e;
        const int row  = idx >> 5, coln = idx & 31;
        const int b    = m0 + row;
        const int n    = n0 + coln;
        float accs = (psum[0][row][coln] + psum[1][row][coln])
                   + (psum[2][row][coln] + psum[3][row][coln]);
        float val = accs + (tb[n] + hbv[n]);
        float v2 = (float)tanh((double)val);
        int P = b >> 4, colb = b & 15;
        int cc2 = n >> 5, kgg = (n >> 3) & 3, jj = n & 7;
        size_t oidx = (size_t)P * 8192 + (size_t)cc2 * 512
                    + (size_t)(kgg * 16 + colb) * 8 + jj;
        unsigned short hb = f2bf_rn(v2);
        o_hi[oidx] = hb;
        o_lo[oidx] = f2bf_rn(v2 - bf2f(hb));
    }
}

// -------------------- logits GEMM (bf16x3 MFMA) + bias + store + argmax (R5 proven).
// 32(m) x 64(n) tile per wave, WPB waves per block sharing B panels.
template <int NCH, int EPI, int WPB>
__global__ __launch_bounds__(64 * WPB, 3) void mfma_gemm(
    const unsigned short* __restrict__ a0h, const unsigned short* __restrict__ a0l,
    const unsigned short* __restrict__ a1h, const unsigned short* __restrict__ a1l,
    const unsigned short* __restrict__ bmh, const unsigned short* __restrict__ bml,
    const float* __restrict__ bias0, const float* __restrict__ bias1,
    float* __restrict__ outp,
    unsigned short* __restrict__ o_hi, unsigned short* __restrict__ o_lo,
    unsigned long long* __restrict__ keys, int s)
{
    const int tid  = threadIdx.x;
    const int lane = tid & 63;
    const int wav  = tid >> 6;
    const int col = lane & 15;        // fragment row (A) / column (B)
    const int kg  = lane >> 4;        // k-group 0..3
    const int m0 = (blockIdx.y * WPB + wav) * 32;
    const int n0 = blockIdx.x * 64;

    const size_t aoff = (size_t)(m0 >> 4) * 8192 + (size_t)lane * 8;
    const size_t boff = (size_t)(n0 >> 4) * (NCH * 512) + (size_t)lane * 8;

    f32x4 acc[2][4];
    #pragma unroll
    for (int f = 0; f < 2; f++)
        #pragma unroll
        for (int g = 0; g < 4; g++)
            acc[f][g] = (f32x4){0.f, 0.f, 0.f, 0.f};

    bf16x8 fah[2][2], fal[2][2], fbh[2][4], fbl[2][4];

#define LOAD_CHUNK(C, BUF)                                                         \
    {                                                                              \
        const unsigned short* ah_ = ((NCH == 16) || ((C) < 16)) ? a0h : a1h;       \
        const unsigned short* al_ = ((NCH == 16) || ((C) < 16)) ? a0l : a1l;       \
        const int cc_ = (C) & 15;                                                  \
        _Pragma("unroll")                                                          \
        for (int f = 0; f < 2; f++) {                                              \
            fah[BUF][f] = *(const bf16x8*)(ah_ + aoff + (size_t)f * 8192 + cc_ * 512); \
            fal[BUF][f] = *(const bf16x8*)(al_ + aoff + (size_t)f * 8192 + cc_ * 512); \
        }                                                                          \
        _Pragma("unroll")                                                          \
        for (int g = 0; g < 4; g++) {                                              \
            fbh[BUF][g] = *(const bf16x8*)(bmh + boff + (size_t)g * (NCH * 512) + (C) * 512); \
            fbl[BUF][g] = *(const bf16x8*)(bml + boff + (size_t)g * (NCH * 512) + (C) * 512); \
        }                                                                          \
    }

    LOAD_CHUNK(0, 0);
    #pragma unroll
    for (int c = 0; c < NCH; c++) {
        const int cur = c & 1, nxt = cur ^ 1;
        if (c < NCH - 1) LOAD_CHUNK(c + 1, nxt);
        #pragma unroll
        for (int f = 0; f < 2; f++)
            #pragma unroll
            for (int g = 0; g < 4; g++) {
                acc[f][g] = __builtin_amdgcn_mfma_f32_16x16x32_bf16(fah[cur][f], fbh[cur][g], acc[f][g], 0, 0, 0);
                acc[f][g] = __builtin_amdgcn_mfma_f32_16x16x32_bf16(fah[cur][f], fbl[cur][g], acc[f][g], 0, 0, 0);
                acc[f][g] = __builtin_amdgcn_mfma_f32_16x16x32_bf16(fal[cur][f], fbh[cur][g], acc[f][g], 0, 0, 0);
            }
    }
#undef LOAD_CHUNK

    // bias per n-col of this lane (col fixed per lane)
    float bias[4];
    #pragma unroll
    for (int g = 0; g < 4; g++) {
        int v = n0 + g * 16 + col;
        bias[g] = (v < VS) ? bias0[v] : 0.f;
    }

    // epilogue (C/D: col = lane&15, row = kg*4 + reg)
    #pragma unroll
    for (int f = 0; f < 2; f++) {
        #pragma unroll
        for (int r = 0; r < 4; r++) {
            const int b = m0 + f * 16 + kg * 4 + r;
            float* orow = outp + ((size_t)b * STEPS + s) * VS;
            unsigned long long kmax = 0ull;
            #pragma unroll
            for (int g = 0; g < 4; g++) {
                int v = n0 + g * 16 + col;
                float val = acc[f][g][r] + bias[g];
                if (v < VS) {
                    orow[v] = val;
                    unsigned long long key =
                        ((unsigned long long)mono_key(val) << 32) |
                        (unsigned long long)(unsigned int)(~v);
                    if (key > kmax) kmax = key;
                }
            }
            #pragma unroll
            for (int mk = 1; mk < 16; mk <<= 1) {
                unsigned long long o = __shfl_xor(kmax, mk, 64);
                if (o > kmax) kmax = o;
            }
            if (col == 0) {
                // load-filter: stale reads are only ever lower -> conservative
                if (kmax > *(volatile unsigned long long*)&keys[b])
                    atomicMax(&keys[b], kmax);
            }
        }
    }
}

// -------------------- attention: SINGLE-PASS online softmax. One block per batch
// row, 512 threads (8 waves); wave w handles l = w, w+8, ... (25 each). For each l,
// the score p = h.e_l is wave-reduced (uniform across lanes), then e_l (still in
// registers) is immediately accumulated with weight exp(p - m_running), with online
// max rescaling. Cross-wave combine rescales by exp(m_w - M) and divides by the
// global sum. Halves code_emb gather traffic vs the 2-pass version and removes the
// serial softmax block-reduction. Epilogue packs t and resets keys[b].
__global__ __launch_bounds__(512) void attn_kernel(
    const int* __restrict__ method_code, const float* __restrict__ code_emb,
    const float* __restrict__ h, unsigned short* __restrict__ t_hi,
    unsigned short* __restrict__ t_lo, unsigned long long* __restrict__ keys)
{
    const int b = blockIdx.x;
    const int tid = threadIdx.x;
    const int lane = tid & 63, wave = tid >> 6;

    __shared__ int    rows[LL];
    __shared__ float  ts[DD];
    __shared__ float  part[8][DD];
    __shared__ float  wmax[8];
    __shared__ double wsum[8];

    if (tid < LL) rows[tid] = method_code[b * LL + tid];
    if (tid == 0) keys[b] = 0ull;   // safe: gates GEMM already consumed last step's keys
    // h fragment in registers: 8 consecutive dims per lane (same for all 8 waves)
    const float* hb = h + (size_t)b * DD;
    float4 h0 = *(const float4*)(hb + lane * 8);
    float4 h1 = *(const float4*)(hb + lane * 8 + 4);
    __syncthreads();

    // single pass: score + online-softmax accumulate (e_l reused from registers)
    float  m = -INFINITY;
    double s = 0.0;
    float pa[8] = {0.f, 0.f, 0.f, 0.f, 0.f, 0.f, 0.f, 0.f};
    for (int l = wave; l < LL; l += 8) {
        const float* e = code_emb + (size_t)rows[l] * DD + lane * 8;
        float4 e0 = *(const float4*)e;
        float4 e1 = *(const float4*)(e + 4);
        float p = h0.x * e0.x + h0.y * e0.y + h0.z * e0.z + h0.w * e0.w
                + h1.x * e1.x + h1.y * e1.y + h1.z * e1.z + h1.w * e1.w;
        #pragma unroll
        for (int mk = 1; mk < 64; mk <<= 1) p += __shfl_xor(p, mk, 64);
        // p is uniform across the wave; online max update (branch is wave-uniform)
        if (p > m) {
            float scale = (m == -INFINITY) ? 0.f : (float)exp((double)m - (double)p);
            s *= (double)scale;
            #pragma unroll
            for (int j = 0; j < 8; j++) pa[j] *= scale;
            m = p;
        }
        double wd = exp((double)p - (double)m);   // <= 1
        s += wd;
        float wf = (float)wd;
        pa[0] = fmaf(wf, e0.x, pa[0]); pa[1] = fmaf(wf, e0.y, pa[1]);
        pa[2] = fmaf(wf, e0.z, pa[2]); pa[3] = fmaf(wf, e0.w, pa[3]);
        pa[4] = fmaf(wf, e1.x, pa[4]); pa[5] = fmaf(wf, e1.y, pa[5]);
        pa[6] = fmaf(wf, e1.z, pa[6]); pa[7] = fmaf(wf, e1.w, pa[7]);
    }
    #pragma unroll
    for (int j = 0; j < 8; j++) part[wave][lane * 8 + j] = pa[j];
    if (lane == 0) { wmax[wave] = m; wsum[wave] = s; }
    __syncthreads();

    // cross-wave combine: each of 512 threads owns one dim (redundant M/S compute)
    {
        float M = wmax[0];
        #pragma unroll
        for (int w2 = 1; w2 < 8; w2++) M = fmaxf(M, wmax[w2]);
        float sc8[8];
        double S = 0.0;
        #pragma unroll
        for (int w2 = 0; w2 < 8; w2++) {
            sc8[w2] = (float)exp((double)wmax[w2] - (double)M);
            S += wsum[w2] * (double)sc8[w2];
        }
        const int d = tid;
        float v01 = part[0][d] * sc8[0] + part[1][d] * sc8[1];
        float v23 = part[2][d] * sc8[2] + part[3][d] * sc8[3];
        float v45 = part[4][d] * sc8[4] + part[5][d] * sc8[5];
        float v67 = part[6][d] * sc8[6] + part[7][d] * sc8[7];
        ts[d] = (float)((double)((v01 + v23) + (v45 + v67)) / S);
    }
    __syncthreads();

    // pack t row into fragment order: 64 lanes x 8 consecutive dims
    if (tid < 64) {
        const int cc = tid >> 2, kgg = tid & 3;
        const float* src = ts + cc * 32 + kgg * 8;   // = ts + tid*8 (contiguous)
        float4 v0 = *(const float4*)src;
        float4 v1 = *(const float4*)(src + 4);
        size_t base = (size_t)(b >> 4) * 8192 + (size_t)cc * 512
                    + (size_t)(kgg * 16 + (b & 15)) * 8;
        split_store8(v0, v1, t_hi + base, t_lo + base);
    }
}

extern "C" void kernel_launch(void* const* d_in, const int* in_sizes, int n_in,
                              void* d_out, int out_size, void* d_ws, size_t ws_size,
                              hipStream_t stream)
{
    const int*   method_code = (const int*)d_in[0];
    const float* code_emb    = (const float*)d_in[1];
    const float* sum_emb     = (const float*)d_in[2];
    const float* w_ih        = (const float*)d_in[3];
    const float* w_hh        = (const float*)d_in[4];
    const float* b_ih        = (const float*)d_in[5];
    const float* b_hh        = (const float*)d_in[6];
    const float* t_w         = (const float*)d_in[7];
    const float* t_b         = (const float*)d_in[8];
    const float* h_w         = (const float*)d_in[9];
    const float* h_b         = (const float*)d_in[10];
    const float* p_w         = (const float*)d_in[11];
    const float* p_b         = (const float*)d_in[12];
    float* out = (float*)d_out;

    float* h     = (float*)d_ws;                                   // 256*512 f32
    float* c     = h + BB * DD;                                    // 256*512 f32
    unsigned long long* keys = (unsigned long long*)(c + BB * DD); // 256
    unsigned short* a_hi   = (unsigned short*)(keys + BB);         // 256*512 (logits A)
    unsigned short* a_lo   = a_hi   + BB * DD;
    unsigned short* t_hi   = a_lo   + BB * DD;                     // t half of pre-A
    unsigned short* t_lo   = t_hi   + BB * DD;
    unsigned short* hp0_hi = t_lo   + BB * DD;                     // packed h, buffer 0
    unsigned short* hp0_lo = hp0_hi + BB * DD;
    unsigned short* hp1_hi = hp0_lo + BB * DD;                     // packed h, buffer 1
    unsigned short* hp1_lo = hp1_hi + BB * DD;
    unsigned short* w1_hi  = hp1_lo + BB * DD;                     // [w_ih|w_hh] perm 2048x1024
    unsigned short* w1_lo  = w1_hi  + (size_t)2048 * 1024;
    unsigned short* w2_hi  = w1_lo  + (size_t)2048 * 1024;         // [t_w|h_w] 512x1024
    unsigned short* w2_lo  = w2_hi  + (size_t)512 * 1024;
    unsigned short* p_hi   = w2_lo  + (size_t)512 * 1024;          // 20224*512
    unsigned short* p_lo   = p_hi   + (size_t)VS_PAD * DD;

    // zero h, c (contiguous) and hp0 pair (step-0 gates reads it)
    hipMemsetAsync(h, 0, (size_t)2 * BB * DD * sizeof(float), stream);
    hipMemsetAsync(hp0_hi, 0, (size_t)2 * BB * DD * sizeof(unsigned short), stream);
    init_keys_kernel<<<1, 256, 0, stream>>>(keys);
    split_pw_kernel<<<(VS_PAD * 64) / 256, 256, 0, stream>>>(p_w, p_hi, p_lo);
    split_wcat_kernel<1><<<1024, 256, 0, stream>>>(w_ih, w_hh, w1_hi, w1_lo);  // gate-interleaved
    split_wcat_kernel<0><<<256, 256, 0, stream>>>(t_w, h_w, w2_hi, w2_lo);     // R=512

    for (int s = 0; s < STEPS; s++) {
        const unsigned short* hin_hi  = (s & 1) ? hp1_hi : hp0_hi;
        const unsigned short* hin_lo  = (s & 1) ? hp1_lo : hp0_lo;
        unsigned short*       hout_hi = (s & 1) ? hp0_hi : hp1_hi;
        unsigned short*       hout_lo = (s & 1) ? hp0_lo : hp1_lo;

        // fused gather + gates GEMM + LSTM + h pack (M=256, N=2048, K=1024)
        gates_lstm_kernel<<<dim3(32, 4), 256, 0, stream>>>(
            sum_emb, keys, hin_hi, hin_lo, w1_hi, w1_lo, b_ih, b_hh,
            c, h, hout_hi, hout_lo);
        attn_kernel<<<256, 512, 0, stream>>>(method_code, code_emb, h, t_hi, t_lo, keys);
        // pre = tanh([t|h] @ [t_w|h_w]^T + t_b + h_b) -> packed logits-A (K split 4)
        pre_kernel<<<dim3(16, 16), 256, 0, stream>>>(
            t_hi, t_lo, hout_hi, hout_lo, w2_hi, w2_lo, t_b, h_b, a_hi, a_lo);
        // logits + greedy argmax (M=256, N=20224, K=512), 4 waves/block share B panels
        mfma_gemm<16, 2, 4><<<dim3(316, 2), 256, 0, stream>>>(
            a_hi, a_lo, nullptr, nullptr, p_hi, p_lo, p_b, nullptr,
            out, nullptr, nullptr, keys, s);
    }
}

// Round 9
// 1880.709 us; speedup vs baseline: 1.1184x; 1.0363x over previous
//
#include <hip/hip_runtime.h>
#include <math.h>

#define BB 256
#define LL 200
#define DD 512
#define VS 20000
#define VS_PAD 20224   // 316 * 64
#define STEPS 15

typedef __attribute__((ext_vector_type(8))) short bf16x8;
typedef __attribute__((ext_vector_type(4))) float f32x4;

// monotone mapping float -> uint32 preserving order
__device__ __forceinline__ unsigned int mono_key(float f) {
    unsigned int u = __float_as_uint(f);
    return (u & 0x80000000u) ? ~u : (u | 0x80000000u);
}

// bf16 round-to-nearest-even split helpers (bit ops, header-independent)
__device__ __forceinline__ unsigned short f2bf_rn(float x) {
    unsigned int u = __float_as_uint(x);
    unsigned int r = (u + 0x7FFFu + ((u >> 16) & 1u)) >> 16;
    return (unsigned short)r;
}
__device__ __forceinline__ float bf2f(unsigned short b) {
    return __uint_as_float((unsigned int)b << 16);
}

// split 8 consecutive floats into bf16 hi + lo residual, store 16B each
__device__ __forceinline__ void split_store8(float4 v0, float4 v1,
    unsigned short* __restrict__ hi, unsigned short* __restrict__ lo)
{
    ushort4 h0, h1, l0, l1;
    h0.x = f2bf_rn(v0.x); l0.x = f2bf_rn(v0.x - bf2f(h0.x));
    h0.y = f2bf_rn(v0.y); l0.y = f2bf_rn(v0.y - bf2f(h0.y));
    h0.z = f2bf_rn(v0.z); l0.z = f2bf_rn(v0.z - bf2f(h0.z));
    h0.w = f2bf_rn(v0.w); l0.w = f2bf_rn(v0.w - bf2f(h0.w));
    h1.x = f2bf_rn(v1.x); l1.x = f2bf_rn(v1.x - bf2f(h1.x));
    h1.y = f2bf_rn(v1.y); l1.y = f2bf_rn(v1.y - bf2f(h1.y));
    h1.z = f2bf_rn(v1.z); l1.z = f2bf_rn(v1.z - bf2f(h1.z));
    h1.w = f2bf_rn(v1.w); l1.w = f2bf_rn(v1.w - bf2f(h1.w));
    *(ushort4*)hi = h0; *(ushort4*)(hi + 4) = h1;
    *(ushort4*)lo = l0; *(ushort4*)(lo + 4) = l1;
}

// same split but into register fragments (for inline gather in the gates GEMM)
__device__ __forceinline__ void split_frag(float4 v0, float4 v1, bf16x8& hi, bf16x8& lo)
{
    float vv[8] = {v0.x, v0.y, v0.z, v0.w, v1.x, v1.y, v1.z, v1.w};
    #pragma unroll
    for (int j = 0; j < 8; j++) {
        unsigned short hb = f2bf_rn(vv[j]);
        hi[j] = (short)hb;
        lo[j] = (short)f2bf_rn(vv[j] - bf2f(hb));
    }
}

__global__ __launch_bounds__(256) void init_keys_kernel(unsigned long long* keys) {
    // low 32 bits = ~token ; decode token = ~(uint32)key. SOS token = 1.
    keys[threadIdx.x] = (unsigned long long)(unsigned int)(~1u);
}

// -------------------- fragment-order packing convention (16x16x32 bf16 MFMA):
// elem idx = panel*(NCH*512) + chunk*512 + lane*8 + j  where
// panel = row/16, chunk = k/32, lane = ((k%32)/8)*16 + row%16, j = k%8.
// A-side buffers are per-512-K halves: panel stride 8192 (16 chunks).

// one-time split of p_w [VS][512] -> hi/lo fragment order (K=512, panel stride 8192)
__global__ __launch_bounds__(256) void split_pw_kernel(
    const float* __restrict__ p_w, unsigned short* __restrict__ p_hi,
    unsigned short* __restrict__ p_lo)
{
    size_t q = (size_t)blockIdx.x * 256 + threadIdx.x;   // chunk id, VS_PAD*64 total
    int P   = (int)(q >> 10);
    int rem = (int)(q & 1023);
    int c   = rem >> 6;
    int l   = rem & 63;
    int row = P * 16 + (l & 15);
    int ks  = c * 32 + (l >> 4) * 8;
    float4 v0 = {0.f, 0.f, 0.f, 0.f}, v1 = {0.f, 0.f, 0.f, 0.f};
    if (row < VS) {
        const float* src = p_w + (size_t)row * DD + ks;
        v0 = *(const float4*)src;
        v1 = *(const float4*)(src + 4);
    }
    split_store8(v0, v1, p_hi + q * 8, p_lo + q * 8);
}

// one-time split of concat weights [R][1024] = [s0 | s1] (each [R][512]) -> hi/lo
// fragment order with panel stride 16384 (32 chunks). R must be multiple of 16.
// PERM=1 (gates W): packed panel P holds orig rows (P&3)*512 + (P>>2)*16 + col
// (gate-interleaved so one wave's 4 fragment columns = the 4 gates of one feature).
template <int PERM>
__global__ __launch_bounds__(256) void split_wcat_kernel(
    const float* __restrict__ s0, const float* __restrict__ s1,
    unsigned short* __restrict__ wh, unsigned short* __restrict__ wl)
{
    size_t q = (size_t)blockIdx.x * 256 + threadIdx.x;   // R*128 groups
    int P   = (int)(q >> 11);
    int rem = (int)(q & 2047);
    int c   = rem >> 6;
    int l   = rem & 63;
    int row;
    if (PERM) row = (P & 3) * 512 + (P >> 2) * 16 + (l & 15);
    else      row = P * 16 + (l & 15);
    int k   = c * 32 + (l >> 4) * 8;
    const float* src = (k < 512) ? (s0 + (size_t)row * DD + k)
                                 : (s1 + (size_t)row * DD + (k - 512));
    float4 v0 = *(const float4*)src;
    float4 v1 = *(const float4*)(src + 4);
    split_store8(v0, v1, wh + q * 8, wl + q * 8);
}

// -------------------- fused: token gather + gates GEMM + LSTM pointwise + h pack.
// 2-wave blocks; wave w owns m-tile (blockIdx.y*2+w)*16 — per-wave instruction
// stream identical to the proven R5/R8 kernel, but 256 blocks cover ALL 256 CUs
// (was 128 blocks = half the chip idle). 16(m) x 64(n = 16 feats x 4 gates) tile.
// Epilogue = fp64 LSTM pointwise (4 cells/lane), writes c, h and packed h_out.
// grid (32 nt, 8) x 128 threads = 256 blocks, 512 waves.
__global__ __launch_bounds__(128) void gates_lstm_kernel(
    const float* __restrict__ sum_emb, const unsigned long long* __restrict__ keys,
    const unsigned short* __restrict__ hin_hi, const unsigned short* __restrict__ hin_lo,
    const unsigned short* __restrict__ w1h, const unsigned short* __restrict__ w1l,
    const float* __restrict__ bi, const float* __restrict__ bh,
    float* __restrict__ c, float* __restrict__ h,
    unsigned short* __restrict__ hout_hi, unsigned short* __restrict__ hout_lo)
{
    const int tid  = threadIdx.x;
    const int lane = tid & 63;
    const int wav  = tid >> 6;
    const int col = lane & 15;
    const int kg  = lane >> 4;
    const int m0  = (blockIdx.y * 2 + wav) * 16;
    const int nt  = blockIdx.x;               // features nt*16 .. nt*16+15

    unsigned int tok = ~(unsigned int)(keys[m0 + col] & 0xFFFFFFFFull);

    const size_t ahoff = (size_t)(m0 >> 4) * 8192 + (size_t)lane * 8;
    const size_t boff  = (size_t)(nt * 4) * 16384 + (size_t)lane * 8;

    f32x4 acc[4];
    #pragma unroll
    for (int g = 0; g < 4; g++) acc[g] = (f32x4){0.f, 0.f, 0.f, 0.f};

    bf16x8 fa_h[2], fa_l[2], fb_h[2][4], fb_l[2][4];

#define GL_LOAD(C, BUF)                                                            \
    {                                                                              \
        if ((C) < 16) {                                                            \
            const float* s_ = sum_emb + (size_t)tok * DD + (C) * 32 + kg * 8;      \
            float4 v0 = *(const float4*)s_;                                        \
            float4 v1 = *(const float4*)(s_ + 4);                                  \
            split_frag(v0, v1, fa_h[BUF], fa_l[BUF]);                              \
        } else {                                                                   \
            fa_h[BUF] = *(const bf16x8*)(hin_hi + ahoff + ((C) - 16) * 512);       \
            fa_l[BUF] = *(const bf16x8*)(hin_lo + ahoff + ((C) - 16) * 512);       \
        }                                                                          \
        _Pragma("unroll")                                                          \
        for (int g = 0; g < 4; g++) {                                              \
            fb_h[BUF][g] = *(const bf16x8*)(w1h + boff + (size_t)g * 16384 + (C) * 512); \
            fb_l[BUF][g] = *(const bf16x8*)(w1l + boff + (size_t)g * 16384 + (C) * 512); \
        }                                                                          \
    }

    GL_LOAD(0, 0);
    #pragma unroll
    for (int cc = 0; cc < 32; cc++) {
        const int cur = cc & 1, nxt = cur ^ 1;
        if (cc < 31) GL_LOAD(cc + 1, nxt);
        #pragma unroll
        for (int g = 0; g < 4; g++) {
            acc[g] = __builtin_amdgcn_mfma_f32_16x16x32_bf16(fa_h[cur], fb_h[cur][g], acc[g], 0, 0, 0);
            acc[g] = __builtin_amdgcn_mfma_f32_16x16x32_bf16(fa_h[cur], fb_l[cur][g], acc[g], 0, 0, 0);
            acc[g] = __builtin_amdgcn_mfma_f32_16x16x32_bf16(fa_l[cur], fb_h[cur][g], acc[g], 0, 0, 0);
        }
    }
#undef GL_LOAD

    const int feat = nt * 16 + col;
    float bias[4];
    #pragma unroll
    for (int g = 0; g < 4; g++)
        bias[g] = bi[g * 512 + feat] + bh[g * 512 + feat];

    // LSTM pointwise (fp64, identical math), 4 cells/lane
    #pragma unroll
    for (int r = 0; r < 4; r++) {
        const int b = m0 + kg * 4 + r;
        float vi = acc[0][r] + bias[0];
        float vf = acc[1][r] + bias[1];
        float vg = acc[2][r] + bias[2];
        float vo = acc[3][r] + bias[3];
        double ig = 1.0 / (1.0 + exp(-(double)vi));
        double fg = 1.0 / (1.0 + exp(-(double)vf));
        double gv = tanh((double)vg);
        double og = 1.0 / (1.0 + exp(-(double)vo));
        size_t cidx = (size_t)b * DD + feat;
        double cn = fg * (double)c[cidx] + ig * gv;
        double hn = og * tanh(cn);
        c[cidx] = (float)cn;
        float hf = (float)hn;
        h[cidx] = hf;
        size_t hidx = (size_t)(b >> 4) * 8192 + (size_t)(feat >> 5) * 512
                    + (size_t)(((feat >> 3) & 3) * 16 + (b & 15)) * 8 + (feat & 7);
        unsigned short hb2 = f2bf_rn(hf);
        hout_hi[hidx] = hb2;
        hout_lo[hidx] = f2bf_rn(hf - bf2f(hb2));
    }
}

// -------------------- pre GEMM: tanh([t|h] @ [t_w|h_w]^T + t_b + h_b) -> packed A.
// 4-wave blocks, 16(m) x 32(n) tile, 4-way K-split (wave w = chunks 8w..8w+7).
// Partials reduced via LDS; tanh epilogue spread over 256 threads (2 cells each).
// grid (16 n-tiles, 16 m-tiles) = 1024 waves.
__global__ __launch_bounds__(256) void pre_kernel(
    const unsigned short* __restrict__ t_hi, const unsigned short* __restrict__ t_lo,
    const unsigned short* __restrict__ h_hi, const unsigned short* __restrict__ h_lo,
    const unsigned short* __restrict__ w2h, const unsigned short* __restrict__ w2l,
    const float* __restrict__ tb, const float* __restrict__ hbv,
    unsigned short* __restrict__ o_hi, unsigned short* __restrict__ o_lo)
{
    const int tid  = threadIdx.x;
    const int lane = tid & 63;
    const int wav  = tid >> 6;        // K-split: absolute chunks wav*8 .. wav*8+7
    const int col  = lane & 15;
    const int kg   = lane >> 4;
    const int m0   = blockIdx.y * 16;
    const int n0   = blockIdx.x * 32;

    const unsigned short* ah = (wav < 2) ? t_hi : h_hi;
    const unsigned short* al = (wav < 2) ? t_lo : h_lo;
    const size_t aoff = (size_t)(m0 >> 4) * 8192 + (size_t)lane * 8
                      + (size_t)((wav & 1) * 8) * 512;
    const size_t boff = (size_t)(n0 >> 4) * 16384 + (size_t)lane * 8
                      + (size_t)(wav * 8) * 512;

    f32x4 acc[2];
    acc[0] = (f32x4){0.f, 0.f, 0.f, 0.f};
    acc[1] = (f32x4){0.f, 0.f, 0.f, 0.f};

    bf16x8 fa_h[2], fa_l[2], fb_h[2][2], fb_l[2][2];
    fa_h[0] = *(const bf16x8*)(ah + aoff);
    fa_l[0] = *(const bf16x8*)(al + aoff);
    #pragma unroll
    for (int g = 0; g < 2; g++) {
        fb_h[0][g] = *(const bf16x8*)(w2h + boff + (size_t)g * 16384);
        fb_l[0][g] = *(const bf16x8*)(w2l + boff + (size_t)g * 16384);
    }
    #pragma unroll
    for (int cc = 0; cc < 8; cc++) {
        const int cur = cc & 1, nxt = cur ^ 1;
        if (cc < 7) {
            const int off = (cc + 1) * 512;
            fa_h[nxt] = *(const bf16x8*)(ah + aoff + off);
            fa_l[nxt] = *(const bf16x8*)(al + aoff + off);
            #pragma unroll
            for (int g = 0; g < 2; g++) {
                fb_h[nxt][g] = *(const bf16x8*)(w2h + boff + (size_t)g * 16384 + off);
                fb_l[nxt][g] = *(const bf16x8*)(w2l + boff + (size_t)g * 16384 + off);
            }
        }
        #pragma unroll
        for (int g = 0; g < 2; g++) {
            acc[g] = __builtin_amdgcn_mfma_f32_16x16x32_bf16(fa_h[cur], fb_h[cur][g], acc[g], 0, 0, 0);
            acc[g] = __builtin_amdgcn_mfma_f32_16x16x32_bf16(fa_h[cur], fb_l[cur][g], acc[g], 0, 0, 0);
            acc[g] = __builtin_amdgcn_mfma_f32_16x16x32_bf16(fa_l[cur], fb_h[cur][g], acc[g], 0, 0, 0);
        }
    }

    __shared__ float psum[4][16][32];
    #pragma unroll
    for (int g = 0; g < 2; g++)
        #pragma unroll
        for (int r = 0; r < 4; r++)
            psum[wav][kg * 4 + r][g * 16 + col] = acc[g][r];
    __syncthreads();

    #pragma unroll
    for (int e = 0; e < 2; e++) {
        const int idx  = tid * 2 + e;
        const int row  = idx >> 5, coln = idx & 31;
        const int b    = m0 + row;
        const int n    = n0 + coln;
        float accs = (psum[0][row][coln] + psum[1][row][coln])
                   + (psum[2][row][coln] + psum[3][row][coln]);
        float val = accs + (tb[n] + hbv[n]);
        float v2 = (float)tanh((double)val);
        int P = b >> 4, colb = b & 15;
        int cc2 = n >> 5, kgg = (n >> 3) & 3, jj = n & 7;
        size_t oidx = (size_t)P * 8192 + (size_t)cc2 * 512
                    + (size_t)(kgg * 16 + colb) * 8 + jj;
        unsigned short hb = f2bf_rn(v2);
        o_hi[oidx] = hb;
        o_lo[oidx] = f2bf_rn(v2 - bf2f(hb));
    }
}

// -------------------- logits GEMM (bf16x3 MFMA) + bias + store + argmax (R5 proven).
// 32(m) x 64(n) tile per wave, WPB waves per block sharing B panels.
template <int NCH, int EPI, int WPB>
__global__ __launch_bounds__(64 * WPB, 3) void mfma_gemm(
    const unsigned short* __restrict__ a0h, const unsigned short* __restrict__ a0l,
    const unsigned short* __restrict__ a1h, const unsigned short* __restrict__ a1l,
    const unsigned short* __restrict__ bmh, const unsigned short* __restrict__ bml,
    const float* __restrict__ bias0, const float* __restrict__ bias1,
    float* __restrict__ outp,
    unsigned short* __restrict__ o_hi, unsigned short* __restrict__ o_lo,
    unsigned long long* __restrict__ keys, int s)
{
    const int tid  = threadIdx.x;
    const int lane = tid & 63;
    const int wav  = tid >> 6;
    const int col = lane & 15;        // fragment row (A) / column (B)
    const int kg  = lane >> 4;        // k-group 0..3
    const int m0 = (blockIdx.y * WPB + wav) * 32;
    const int n0 = blockIdx.x * 64;

    const size_t aoff = (size_t)(m0 >> 4) * 8192 + (size_t)lane * 8;
    const size_t boff = (size_t)(n0 >> 4) * (NCH * 512) + (size_t)lane * 8;

    f32x4 acc[2][4];
    #pragma unroll
    for (int f = 0; f < 2; f++)
        #pragma unroll
        for (int g = 0; g < 4; g++)
            acc[f][g] = (f32x4){0.f, 0.f, 0.f, 0.f};

    bf16x8 fah[2][2], fal[2][2], fbh[2][4], fbl[2][4];

#define LOAD_CHUNK(C, BUF)                                                         \
    {                                                                              \
        const unsigned short* ah_ = ((NCH == 16) || ((C) < 16)) ? a0h : a1h;       \
        const unsigned short* al_ = ((NCH == 16) || ((C) < 16)) ? a0l : a1l;       \
        const int cc_ = (C) & 15;                                                  \
        _Pragma("unroll")                                                          \
        for (int f = 0; f < 2; f++) {                                              \
            fah[BUF][f] = *(const bf16x8*)(ah_ + aoff + (size_t)f * 8192 + cc_ * 512); \
            fal[BUF][f] = *(const bf16x8*)(al_ + aoff + (size_t)f * 8192 + cc_ * 512); \
        }                                                                          \
        _Pragma("unroll")                                                          \
        for (int g = 0; g < 4; g++) {                                              \
            fbh[BUF][g] = *(const bf16x8*)(bmh + boff + (size_t)g * (NCH * 512) + (C) * 512); \
            fbl[BUF][g] = *(const bf16x8*)(bml + boff + (size_t)g * (NCH * 512) + (C) * 512); \
        }                                                                          \
    }

    LOAD_CHUNK(0, 0);
    #pragma unroll
    for (int c = 0; c < NCH; c++) {
        const int cur = c & 1, nxt = cur ^ 1;
        if (c < NCH - 1) LOAD_CHUNK(c + 1, nxt);
        #pragma unroll
        for (int f = 0; f < 2; f++)
            #pragma unroll
            for (int g = 0; g < 4; g++) {
                acc[f][g] = __builtin_amdgcn_mfma_f32_16x16x32_bf16(fah[cur][f], fbh[cur][g], acc[f][g], 0, 0, 0);
                acc[f][g] = __builtin_amdgcn_mfma_f32_16x16x32_bf16(fah[cur][f], fbl[cur][g], acc[f][g], 0, 0, 0);
                acc[f][g] = __builtin_amdgcn_mfma_f32_16x16x32_bf16(fal[cur][f], fbh[cur][g], acc[f][g], 0, 0, 0);
            }
    }
#undef LOAD_CHUNK

    // bias per n-col of this lane (col fixed per lane)
    float bias[4];
    #pragma unroll
    for (int g = 0; g < 4; g++) {
        int v = n0 + g * 16 + col;
        bias[g] = (v < VS) ? bias0[v] : 0.f;
    }

    // epilogue (C/D: col = lane&15, row = kg*4 + reg)
    #pragma unroll
    for (int f = 0; f < 2; f++) {
        #pragma unroll
        for (int r = 0; r < 4; r++) {
            const int b = m0 + f * 16 + kg * 4 + r;
            float* orow = outp + ((size_t)b * STEPS + s) * VS;
            unsigned long long kmax = 0ull;
            #pragma unroll
            for (int g = 0; g < 4; g++) {
                int v = n0 + g * 16 + col;
                float val = acc[f][g][r] + bias[g];
                if (v < VS) {
                    orow[v] = val;
                    unsigned long long key =
                        ((unsigned long long)mono_key(val) << 32) |
                        (unsigned long long)(unsigned int)(~v);
                    if (key > kmax) kmax = key;
                }
            }
            #pragma unroll
            for (int mk = 1; mk < 16; mk <<= 1) {
                unsigned long long o = __shfl_xor(kmax, mk, 64);
                if (o > kmax) kmax = o;
            }
            if (col == 0) {
                // load-filter: stale reads are only ever lower -> conservative
                if (kmax > *(volatile unsigned long long*)&keys[b])
                    atomicMax(&keys[b], kmax);
            }
        }
    }
}

// -------------------- attention: SINGLE-PASS online softmax (R8 proven). One block
// per batch row, 512 threads (8 waves); wave w handles l = w, w+8, ... For each l,
// the score p = h.e_l is wave-reduced, then e_l (still in registers) is accumulated
// with weight exp(p - m_running), online max rescaling. Cross-wave combine at end.
__global__ __launch_bounds__(512) void attn_kernel(
    const int* __restrict__ method_code, const float* __restrict__ code_emb,
    const float* __restrict__ h, unsigned short* __restrict__ t_hi,
    unsigned short* __restrict__ t_lo, unsigned long long* __restrict__ keys)
{
    const int b = blockIdx.x;
    const int tid = threadIdx.x;
    const int lane = tid & 63, wave = tid >> 6;

    __shared__ int    rows[LL];
    __shared__ float  ts[DD];
    __shared__ float  part[8][DD];
    __shared__ float  wmax[8];
    __shared__ double wsum[8];

    if (tid < LL) rows[tid] = method_code[b * LL + tid];
    if (tid == 0) keys[b] = 0ull;   // safe: gates GEMM already consumed last step's keys
    // h fragment in registers: 8 consecutive dims per lane (same for all 8 waves)
    const float* hb = h + (size_t)b * DD;
    float4 h0 = *(const float4*)(hb + lane * 8);
    float4 h1 = *(const float4*)(hb + lane * 8 + 4);
    __syncthreads();

    // single pass: score + online-softmax accumulate (e_l reused from registers)
    float  m = -INFINITY;
    double s = 0.0;
    float pa[8] = {0.f, 0.f, 0.f, 0.f, 0.f, 0.f, 0.f, 0.f};
    for (int l = wave; l < LL; l += 8) {
        const float* e = code_emb + (size_t)rows[l] * DD + lane * 8;
        float4 e0 = *(const float4*)e;
        float4 e1 = *(const float4*)(e + 4);
        float p = h0.x * e0.x + h0.y * e0.y + h0.z * e0.z + h0.w * e0.w
                + h1.x * e1.x + h1.y * e1.y + h1.z * e1.z + h1.w * e1.w;
        #pragma unroll
        for (int mk = 1; mk < 64; mk <<= 1) p += __shfl_xor(p, mk, 64);
        // p is uniform across the wave; online max update (branch is wave-uniform)
        if (p > m) {
            float scale = (m == -INFINITY) ? 0.f : (float)exp((double)m - (double)p);
            s *= (double)scale;
            #pragma unroll
            for (int j = 0; j < 8; j++) pa[j] *= scale;
            m = p;
        }
        double wd = exp((double)p - (double)m);   // <= 1
        s += wd;
        float wf = (float)wd;
        pa[0] = fmaf(wf, e0.x, pa[0]); pa[1] = fmaf(wf, e0.y, pa[1]);
        pa[2] = fmaf(wf, e0.z, pa[2]); pa[3] = fmaf(wf, e0.w, pa[3]);
        pa[4] = fmaf(wf, e1.x, pa[4]); pa[5] = fmaf(wf, e1.y, pa[5]);
        pa[6] = fmaf(wf, e1.z, pa[6]); pa[7] = fmaf(wf, e1.w, pa[7]);
    }
    #pragma unroll
    for (int j = 0; j < 8; j++) part[wave][lane * 8 + j] = pa[j];
    if (lane == 0) { wmax[wave] = m; wsum[wave] = s; }
    __syncthreads();

    // cross-wave combine: each of 512 threads owns one dim (redundant M/S compute)
    {
        float M = wmax[0];
        #pragma unroll
        for (int w2 = 1; w2 < 8; w2++) M = fmaxf(M, wmax[w2]);
        float sc8[8];
        double S = 0.0;
        #pragma unroll
        for (int w2 = 0; w2 < 8; w2++) {
            sc8[w2] = (float)exp((double)wmax[w2] - (double)M);
            S += wsum[w2] * (double)sc8[w2];
        }
        const int d = tid;
        float v01 = part[0][d] * sc8[0] + part[1][d] * sc8[1];
        float v23 = part[2][d] * sc8[2] + part[3][d] * sc8[3];
        float v45 = part[4][d] * sc8[4] + part[5][d] * sc8[5];
        float v67 = part[6][d] * sc8[6] + part[7][d] * sc8[7];
        ts[d] = (float)((double)((v01 + v23) + (v45 + v67)) / S);
    }
    __syncthreads();

    // pack t row into fragment order: 64 lanes x 8 consecutive dims
    if (tid < 64) {
        const int cc = tid >> 2, kgg = tid & 3;
        const float* src = ts + cc * 32 + kgg * 8;   // = ts + tid*8 (contiguous)
        float4 v0 = *(const float4*)src;
        float4 v1 = *(const float4*)(src + 4);
        size_t base = (size_t)(b >> 4) * 8192 + (size_t)cc * 512
                    + (size_t)(kgg * 16 + (b & 15)) * 8;
        split_store8(v0, v1, t_hi + base, t_lo + base);
    }
}

extern "C" void kernel_launch(void* const* d_in, const int* in_sizes, int n_in,
                              void* d_out, int out_size, void* d_ws, size_t ws_size,
                              hipStream_t stream)
{
    const int*   method_code = (const int*)d_in[0];
    const float* code_emb    = (const float*)d_in[1];
    const float* sum_emb     = (const float*)d_in[2];
    const float* w_ih        = (const float*)d_in[3];
    const float* w_hh        = (const float*)d_in[4];
    const float* b_ih        = (const float*)d_in[5];
    const float* b_hh        = (const float*)d_in[6];
    const float* t_w         = (const float*)d_in[7];
    const float* t_b         = (const float*)d_in[8];
    const float* h_w         = (const float*)d_in[9];
    const float* h_b         = (const float*)d_in[10];
    const float* p_w         = (const float*)d_in[11];
    const float* p_b         = (const float*)d_in[12];
    float* out = (float*)d_out;

    float* h     = (float*)d_ws;                                   // 256*512 f32
    float* c     = h + BB * DD;                                    // 256*512 f32
    unsigned long long* keys = (unsigned long long*)(c + BB * DD); // 256
    unsigned short* a_hi   = (unsigned short*)(keys + BB);         // 256*512 (logits A)
    unsigned short* a_lo   = a_hi   + BB * DD;
    unsigned short* t_hi   = a_lo   + BB * DD;                     // t half of pre-A
    unsigned short* t_lo   = t_hi   + BB * DD;
    unsigned short* hp0_hi = t_lo   + BB * DD;                     // packed h, buffer 0
    unsigned short* hp0_lo = hp0_hi + BB * DD;
    unsigned short* hp1_hi = hp0_lo + BB * DD;                     // packed h, buffer 1
    unsigned short* hp1_lo = hp1_hi + BB * DD;
    unsigned short* w1_hi  = hp1_lo + BB * DD;                     // [w_ih|w_hh] perm 2048x1024
    unsigned short* w1_lo  = w1_hi  + (size_t)2048 * 1024;
    unsigned short* w2_hi  = w1_lo  + (size_t)2048 * 1024;         // [t_w|h_w] 512x1024
    unsigned short* w2_lo  = w2_hi  + (size_t)512 * 1024;
    unsigned short* p_hi   = w2_lo  + (size_t)512 * 1024;          // 20224*512
    unsigned short* p_lo   = p_hi   + (size_t)VS_PAD * DD;

    // zero h, c (contiguous) and hp0 pair (step-0 gates reads it)
    hipMemsetAsync(h, 0, (size_t)2 * BB * DD * sizeof(float), stream);
    hipMemsetAsync(hp0_hi, 0, (size_t)2 * BB * DD * sizeof(unsigned short), stream);
    init_keys_kernel<<<1, 256, 0, stream>>>(keys);
    split_pw_kernel<<<(VS_PAD * 64) / 256, 256, 0, stream>>>(p_w, p_hi, p_lo);
    split_wcat_kernel<1><<<1024, 256, 0, stream>>>(w_ih, w_hh, w1_hi, w1_lo);  // gate-interleaved
    split_wcat_kernel<0><<<256, 256, 0, stream>>>(t_w, h_w, w2_hi, w2_lo);     // R=512

    for (int s = 0; s < STEPS; s++) {
        const unsigned short* hin_hi  = (s & 1) ? hp1_hi : hp0_hi;
        const unsigned short* hin_lo  = (s & 1) ? hp1_lo : hp0_lo;
        unsigned short*       hout_hi = (s & 1) ? hp0_hi : hp1_hi;
        unsigned short*       hout_lo = (s & 1) ? hp0_lo : hp1_lo;

        // fused gather + gates GEMM + LSTM + h pack (M=256, N=2048, K=1024)
        gates_lstm_kernel<<<dim3(32, 8), 128, 0, stream>>>(
            sum_emb, keys, hin_hi, hin_lo, w1_hi, w1_lo, b_ih, b_hh,
            c, h, hout_hi, hout_lo);
        attn_kernel<<<256, 512, 0, stream>>>(method_code, code_emb, h, t_hi, t_lo, keys);
        // pre = tanh([t|h] @ [t_w|h_w]^T + t_b + h_b) -> packed logits-A (K split 4)
        pre_kernel<<<dim3(16, 16), 256, 0, stream>>>(
            t_hi, t_lo, hout_hi, hout_lo, w2_hi, w2_lo, t_b, h_b, a_hi, a_lo);
        // logits + greedy argmax (M=256, N=20224, K=512), 4 waves/block share B panels
        mfma_gemm<16, 2, 4><<<dim3(316, 2), 256, 0, stream>>>(
            a_hi, a_lo, nullptr, nullptr, p_hi, p_lo, p_b, nullptr,
            out, nullptr, nullptr, keys, s);
    }
}

// Round 11
// 1860.660 us; speedup vs baseline: 1.1305x; 1.0108x over previous
//
#include <hip/hip_runtime.h>
#include <math.h>

#define BB 256
#define LL 200
#define DD 512
#define VS 20000
#define VS_PAD 20224   // 316 * 64
#define STEPS 15

typedef __attribute__((ext_vector_type(8))) short bf16x8;
typedef __attribute__((ext_vector_type(4))) float f32x4;

// monotone mapping float -> uint32 preserving order
__device__ __forceinline__ unsigned int mono_key(float f) {
    unsigned int u = __float_as_uint(f);
    return (u & 0x80000000u) ? ~u : (u | 0x80000000u);
}

// bf16 round-to-nearest-even split helpers (bit ops, header-independent)
__device__ __forceinline__ unsigned short f2bf_rn(float x) {
    unsigned int u = __float_as_uint(x);
    unsigned int r = (u + 0x7FFFu + ((u >> 16) & 1u)) >> 16;
    return (unsigned short)r;
}
__device__ __forceinline__ float bf2f(unsigned short b) {
    return __uint_as_float((unsigned int)b << 16);
}

// split 8 consecutive floats into bf16 hi + lo residual, store 16B each
__device__ __forceinline__ void split_store8(float4 v0, float4 v1,
    unsigned short* __restrict__ hi, unsigned short* __restrict__ lo)
{
    ushort4 h0, h1, l0, l1;
    h0.x = f2bf_rn(v0.x); l0.x = f2bf_rn(v0.x - bf2f(h0.x));
    h0.y = f2bf_rn(v0.y); l0.y = f2bf_rn(v0.y - bf2f(h0.y));
    h0.z = f2bf_rn(v0.z); l0.z = f2bf_rn(v0.z - bf2f(h0.z));
    h0.w = f2bf_rn(v0.w); l0.w = f2bf_rn(v0.w - bf2f(h0.w));
    h1.x = f2bf_rn(v1.x); l1.x = f2bf_rn(v1.x - bf2f(h1.x));
    h1.y = f2bf_rn(v1.y); l1.y = f2bf_rn(v1.y - bf2f(h1.y));
    h1.z = f2bf_rn(v1.z); l1.z = f2bf_rn(v1.z - bf2f(h1.z));
    h1.w = f2bf_rn(v1.w); l1.w = f2bf_rn(v1.w - bf2f(h1.w));
    *(ushort4*)hi = h0; *(ushort4*)(hi + 4) = h1;
    *(ushort4*)lo = l0; *(ushort4*)(lo + 4) = l1;
}

// same split but into register fragments (for inline gather in the gates GEMM)
__device__ __forceinline__ void split_frag(float4 v0, float4 v1, bf16x8& hi, bf16x8& lo)
{
    float vv[8] = {v0.x, v0.y, v0.z, v0.w, v1.x, v1.y, v1.z, v1.w};
    #pragma unroll
    for (int j = 0; j < 8; j++) {
        unsigned short hb = f2bf_rn(vv[j]);
        hi[j] = (short)hb;
        lo[j] = (short)f2bf_rn(vv[j] - bf2f(hb));
    }
}

__global__ __launch_bounds__(256) void init_keys_kernel(unsigned long long* keys) {
    // low 32 bits = ~token ; decode token = ~(uint32)key. SOS token = 1.
    keys[threadIdx.x] = (unsigned long long)(unsigned int)(~1u);
}

// -------------------- fragment-order packing convention (16x16x32 bf16 MFMA):
// elem idx = panel*(NCH*512) + chunk*512 + lane*8 + j  where
// panel = row/16, chunk = k/32, lane = ((k%32)/8)*16 + row%16, j = k%8.
// A-side buffers are per-512-K halves: panel stride 8192 (16 chunks).

// one-time split of p_w [VS][512] -> hi/lo fragment order (K=512, panel stride 8192)
__global__ __launch_bounds__(256) void split_pw_kernel(
    const float* __restrict__ p_w, unsigned short* __restrict__ p_hi,
    unsigned short* __restrict__ p_lo)
{
    size_t q = (size_t)blockIdx.x * 256 + threadIdx.x;   // chunk id, VS_PAD*64 total
    int P   = (int)(q >> 10);
    int rem = (int)(q & 1023);
    int c   = rem >> 6;
    int l   = rem & 63;
    int row = P * 16 + (l & 15);
    int ks  = c * 32 + (l >> 4) * 8;
    float4 v0 = {0.f, 0.f, 0.f, 0.f}, v1 = {0.f, 0.f, 0.f, 0.f};
    if (row < VS) {
        const float* src = p_w + (size_t)row * DD + ks;
        v0 = *(const float4*)src;
        v1 = *(const float4*)(src + 4);
    }
    split_store8(v0, v1, p_hi + q * 8, p_lo + q * 8);
}

// one-time split of concat weights [R][1024] = [s0 | s1] (each [R][512]) -> hi/lo
// fragment order with panel stride 16384 (32 chunks). R must be multiple of 16.
// PERM=1 (gates W): packed panel P holds orig rows (P&3)*512 + (P>>2)*16 + col
// (gate-interleaved so one wave's 4 fragment columns = the 4 gates of one feature).
template <int PERM>
__global__ __launch_bounds__(256) void split_wcat_kernel(
    const float* __restrict__ s0, const float* __restrict__ s1,
    unsigned short* __restrict__ wh, unsigned short* __restrict__ wl)
{
    size_t q = (size_t)blockIdx.x * 256 + threadIdx.x;   // R*128 groups
    int P   = (int)(q >> 11);
    int rem = (int)(q & 2047);
    int c   = rem >> 6;
    int l   = rem & 63;
    int row;
    if (PERM) row = (P & 3) * 512 + (P >> 2) * 16 + (l & 15);
    else      row = P * 16 + (l & 15);
    int k   = c * 32 + (l >> 4) * 8;
    const float* src = (k < 512) ? (s0 + (size_t)row * DD + k)
                                 : (s1 + (size_t)row * DD + (k - 512));
    float4 v0 = *(const float4*)src;
    float4 v1 = *(const float4*)(src + 4);
    split_store8(v0, v1, wh + q * 8, wl + q * 8);
}

// -------------------- fused: token gather + gates GEMM + LSTM pointwise + h pack.
// R9-PROVEN VERSION (split-K gates failed twice — R3, R10 — lane closed).
// 2-wave blocks; wave w owns m-tile (blockIdx.y*2+w)*16; 256 blocks cover all CUs.
// 16(m) x 64(n = 16 feats x 4 gates) tile, full K=32 chunks per wave.
// Epilogue = fp64 LSTM pointwise (4 cells/lane; RECURRENT state stays fp64).
// grid (32 nt, 8) x 128 threads = 256 blocks, 512 waves.
__global__ __launch_bounds__(128) void gates_lstm_kernel(
    const float* __restrict__ sum_emb, const unsigned long long* __restrict__ keys,
    const unsigned short* __restrict__ hin_hi, const unsigned short* __restrict__ hin_lo,
    const unsigned short* __restrict__ w1h, const unsigned short* __restrict__ w1l,
    const float* __restrict__ bi, const float* __restrict__ bh,
    float* __restrict__ c, float* __restrict__ h,
    unsigned short* __restrict__ hout_hi, unsigned short* __restrict__ hout_lo)
{
    const int tid  = threadIdx.x;
    const int lane = tid & 63;
    const int wav  = tid >> 6;
    const int col = lane & 15;
    const int kg  = lane >> 4;
    const int m0  = (blockIdx.y * 2 + wav) * 16;
    const int nt  = blockIdx.x;               // features nt*16 .. nt*16+15

    unsigned int tok = ~(unsigned int)(keys[m0 + col] & 0xFFFFFFFFull);

    const size_t ahoff = (size_t)(m0 >> 4) * 8192 + (size_t)lane * 8;
    const size_t boff  = (size_t)(nt * 4) * 16384 + (size_t)lane * 8;

    f32x4 acc[4];
    #pragma unroll
    for (int g = 0; g < 4; g++) acc[g] = (f32x4){0.f, 0.f, 0.f, 0.f};

    bf16x8 fa_h[2], fa_l[2], fb_h[2][4], fb_l[2][4];

#define GL_LOAD(C, BUF)                                                            \
    {                                                                              \
        if ((C) < 16) {                                                            \
            const float* s_ = sum_emb + (size_t)tok * DD + (C) * 32 + kg * 8;      \
            float4 v0 = *(const float4*)s_;                                        \
            float4 v1 = *(const float4*)(s_ + 4);                                  \
            split_frag(v0, v1, fa_h[BUF], fa_l[BUF]);                              \
        } else {                                                                   \
            fa_h[BUF] = *(const bf16x8*)(hin_hi + ahoff + ((C) - 16) * 512);       \
            fa_l[BUF] = *(const bf16x8*)(hin_lo + ahoff + ((C) - 16) * 512);       \
        }                                                                          \
        _Pragma("unroll")                                                          \
        for (int g = 0; g < 4; g++) {                                              \
            fb_h[BUF][g] = *(const bf16x8*)(w1h + boff + (size_t)g * 16384 + (C) * 512); \
            fb_l[BUF][g] = *(const bf16x8*)(w1l + boff + (size_t)g * 16384 + (C) * 512); \
        }                                                                          \
    }

    GL_LOAD(0, 0);
    #pragma unroll
    for (int cc = 0; cc < 32; cc++) {
        const int cur = cc & 1, nxt = cur ^ 1;
        if (cc < 31) GL_LOAD(cc + 1, nxt);
        #pragma unroll
        for (int g = 0; g < 4; g++) {
            acc[g] = __builtin_amdgcn_mfma_f32_16x16x32_bf16(fa_h[cur], fb_h[cur][g], acc[g], 0, 0, 0);
            acc[g] = __builtin_amdgcn_mfma_f32_16x16x32_bf16(fa_h[cur], fb_l[cur][g], acc[g], 0, 0, 0);
            acc[g] = __builtin_amdgcn_mfma_f32_16x16x32_bf16(fa_l[cur], fb_h[cur][g], acc[g], 0, 0, 0);
        }
    }
#undef GL_LOAD

    const int feat = nt * 16 + col;
    float bias[4];
    #pragma unroll
    for (int g = 0; g < 4; g++)
        bias[g] = bi[g * 512 + feat] + bh[g * 512 + feat];

    // LSTM pointwise (fp64, identical math), 4 cells/lane
    #pragma unroll
    for (int r = 0; r < 4; r++) {
        const int b = m0 + kg * 4 + r;
        float vi = acc[0][r] + bias[0];
        float vf = acc[1][r] + bias[1];
        float vg = acc[2][r] + bias[2];
        float vo = acc[3][r] + bias[3];
        double ig = 1.0 / (1.0 + exp(-(double)vi));
        double fg = 1.0 / (1.0 + exp(-(double)vf));
        double gv = tanh((double)vg);
        double og = 1.0 / (1.0 + exp(-(double)vo));
        size_t cidx = (size_t)b * DD + feat;
        double cn = fg * (double)c[cidx] + ig * gv;
        double hn = og * tanh(cn);
        c[cidx] = (float)cn;
        float hf = (float)hn;
        h[cidx] = hf;
        size_t hidx = (size_t)(b >> 4) * 8192 + (size_t)(feat >> 5) * 512
                    + (size_t)(((feat >> 3) & 3) * 16 + (b & 15)) * 8 + (feat & 7);
        unsigned short hb2 = f2bf_rn(hf);
        hout_hi[hidx] = hb2;
        hout_lo[hidx] = f2bf_rn(hf - bf2f(hb2));
    }
}

// -------------------- pre GEMM: tanh([t|h] @ [t_w|h_w]^T + t_b + h_b) -> packed A.
// 4-wave blocks, 16(m) x 32(n) tile, 4-way K-split (wave w = chunks 8w..8w+7).
// Partials reduced via LDS; tanhf epilogue (non-recurrent path; fp32 transcendental).
// grid (16 n-tiles, 16 m-tiles) = 1024 waves.
__global__ __launch_bounds__(256) void pre_kernel(
    const unsigned short* __restrict__ t_hi, const unsigned short* __restrict__ t_lo,
    const unsigned short* __restrict__ h_hi, const unsigned short* __restrict__ h_lo,
    const unsigned short* __restrict__ w2h, const unsigned short* __restrict__ w2l,
    const float* __restrict__ tb, const float* __restrict__ hbv,
    unsigned short* __restrict__ o_hi, unsigned short* __restrict__ o_lo)
{
    const int tid  = threadIdx.x;
    const int lane = tid & 63;
    const int wav  = tid >> 6;        // K-split: absolute chunks wav*8 .. wav*8+7
    const int col  = lane & 15;
    const int kg   = lane >> 4;
    const int m0   = blockIdx.y * 16;
    const int n0   = blockIdx.x * 32;

    const unsigned short* ah = (wav < 2) ? t_hi : h_hi;
    const unsigned short* al = (wav < 2) ? t_lo : h_lo;
    const size_t aoff = (size_t)(m0 >> 4) * 8192 + (size_t)lane * 8
                      + (size_t)((wav & 1) * 8) * 512;
    const size_t boff = (size_t)(n0 >> 4) * 16384 + (size_t)lane * 8
                      + (size_t)(wav * 8) * 512;

    f32x4 acc[2];
    acc[0] = (f32x4){0.f, 0.f, 0.f, 0.f};
    acc[1] = (f32x4){0.f, 0.f, 0.f, 0.f};

    bf16x8 fa_h[2], fa_l[2], fb_h[2][2], fb_l[2][2];
    fa_h[0] = *(const bf16x8*)(ah + aoff);
    fa_l[0] = *(const bf16x8*)(al + aoff);
    #pragma unroll
    for (int g = 0; g < 2; g++) {
        fb_h[0][g] = *(const bf16x8*)(w2h + boff + (size_t)g * 16384);
        fb_l[0][g] = *(const bf16x8*)(w2l + boff + (size_t)g * 16384);
    }
    #pragma unroll
    for (int cc = 0; cc < 8; cc++) {
        const int cur = cc & 1, nxt = cur ^ 1;
        if (cc < 7) {
            const int off = (cc + 1) * 512;
            fa_h[nxt] = *(const bf16x8*)(ah + aoff + off);
            fa_l[nxt] = *(const bf16x8*)(al + aoff + off);
            #pragma unroll
            for (int g = 0; g < 2; g++) {
                fb_h[nxt][g] = *(const bf16x8*)(w2h + boff + (size_t)g * 16384 + off);
                fb_l[nxt][g] = *(const bf16x8*)(w2l + boff + (size_t)g * 16384 + off);
            }
        }
        #pragma unroll
        for (int g = 0; g < 2; g++) {
            acc[g] = __builtin_amdgcn_mfma_f32_16x16x32_bf16(fa_h[cur], fb_h[cur][g], acc[g], 0, 0, 0);
            acc[g] = __builtin_amdgcn_mfma_f32_16x16x32_bf16(fa_h[cur], fb_l[cur][g], acc[g], 0, 0, 0);
            acc[g] = __builtin_amdgcn_mfma_f32_16x16x32_bf16(fa_l[cur], fb_h[cur][g], acc[g], 0, 0, 0);
        }
    }

    __shared__ float psum[4][16][32];
    #pragma unroll
    for (int g = 0; g < 2; g++)
        #pragma unroll
        for (int r = 0; r < 4; r++)
            psum[wav][kg * 4 + r][g * 16 + col] = acc[g][r];
    __syncthreads();

    #pragma unroll
    for (int e = 0; e < 2; e++) {
        const int idx  = tid * 2 + e;
        const int row  = idx >> 5, coln = idx & 31;
        const int b    = m0 + row;
        const int n    = n0 + coln;
        float accs = (psum[0][row][coln] + psum[1][row][coln])
                   + (psum[2][row][coln] + psum[3][row][coln]);
        float val = accs + (tb[n] + hbv[n]);
        float v2 = tanhf(val);
        int P = b >> 4, colb = b & 15;
        int cc2 = n >> 5, kgg = (n >> 3) & 3, jj = n & 7;
        size_t oidx = (size_t)P * 8192 + (size_t)cc2 * 512
                    + (size_t)(kgg * 16 + colb) * 8 + jj;
        unsigned short hb = f2bf_rn(v2);
        o_hi[oidx] = hb;
        o_lo[oidx] = f2bf_rn(v2 - bf2f(hb));
    }
}

// -------------------- logits GEMM (bf16x3 MFMA) + bias + store + argmax (R5 proven).
// 32(m) x 64(n) tile per wave, WPB waves per block sharing B panels.
template <int NCH, int EPI, int WPB>
__global__ __launch_bounds__(64 * WPB, 3) void mfma_gemm(
    const unsigned short* __restrict__ a0h, const unsigned short* __restrict__ a0l,
    const unsigned short* __restrict__ a1h, const unsigned short* __restrict__ a1l,
    const unsigned short* __restrict__ bmh, const unsigned short* __restrict__ bml,
    const float* __restrict__ bias0, const float* __restrict__ bias1,
    float* __restrict__ outp,
    unsigned short* __restrict__ o_hi, unsigned short* __restrict__ o_lo,
    unsigned long long* __restrict__ keys, int s)
{
    const int tid  = threadIdx.x;
    const int lane = tid & 63;
    const int wav  = tid >> 6;
    const int col = lane & 15;        // fragment row (A) / column (B)
    const int kg  = lane >> 4;        // k-group 0..3
    const int m0 = (blockIdx.y * WPB + wav) * 32;
    const int n0 = blockIdx.x * 64;

    const size_t aoff = (size_t)(m0 >> 4) * 8192 + (size_t)lane * 8;
    const size_t boff = (size_t)(n0 >> 4) * (NCH * 512) + (size_t)lane * 8;

    f32x4 acc[2][4];
    #pragma unroll
    for (int f = 0; f < 2; f++)
        #pragma unroll
        for (int g = 0; g < 4; g++)
            acc[f][g] = (f32x4){0.f, 0.f, 0.f, 0.f};

    bf16x8 fah[2][2], fal[2][2], fbh[2][4], fbl[2][4];

#define LOAD_CHUNK(C, BUF)                                                         \
    {                                                                              \
        const unsigned short* ah_ = ((NCH == 16) || ((C) < 16)) ? a0h : a1h;       \
        const unsigned short* al_ = ((NCH == 16) || ((C) < 16)) ? a0l : a1l;       \
        const int cc_ = (C) & 15;                                                  \
        _Pragma("unroll")                                                          \
        for (int f = 0; f < 2; f++) {                                              \
            fah[BUF][f] = *(const bf16x8*)(ah_ + aoff + (size_t)f * 8192 + cc_ * 512); \
            fal[BUF][f] = *(const bf16x8*)(al_ + aoff + (size_t)f * 8192 + cc_ * 512); \
        }                                                                          \
        _Pragma("unroll")                                                          \
        for (int g = 0; g < 4; g++) {                                              \
            fbh[BUF][g] = *(const bf16x8*)(bmh + boff + (size_t)g * (NCH * 512) + (C) * 512); \
            fbl[BUF][g] = *(const bf16x8*)(bml + boff + (size_t)g * (NCH * 512) + (C) * 512); \
        }                                                                          \
    }

    LOAD_CHUNK(0, 0);
    #pragma unroll
    for (int c = 0; c < NCH; c++) {
        const int cur = c & 1, nxt = cur ^ 1;
        if (c < NCH - 1) LOAD_CHUNK(c + 1, nxt);
        #pragma unroll
        for (int f = 0; f < 2; f++)
            #pragma unroll
            for (int g = 0; g < 4; g++) {
                acc[f][g] = __builtin_amdgcn_mfma_f32_16x16x32_bf16(fah[cur][f], fbh[cur][g], acc[f][g], 0, 0, 0);
                acc[f][g] = __builtin_amdgcn_mfma_f32_16x16x32_bf16(fah[cur][f], fbl[cur][g], acc[f][g], 0, 0, 0);
                acc[f][g] = __builtin_amdgcn_mfma_f32_16x16x32_bf16(fal[cur][f], fbh[cur][g], acc[f][g], 0, 0, 0);
            }
    }
#undef LOAD_CHUNK

    // bias per n-col of this lane (col fixed per lane)
    float bias[4];
    #pragma unroll
    for (int g = 0; g < 4; g++) {
        int v = n0 + g * 16 + col;
        bias[g] = (v < VS) ? bias0[v] : 0.f;
    }

    // epilogue (C/D: col = lane&15, row = kg*4 + reg)
    #pragma unroll
    for (int f = 0; f < 2; f++) {
        #pragma unroll
        for (int r = 0; r < 4; r++) {
            const int b = m0 + f * 16 + kg * 4 + r;
            float* orow = outp + ((size_t)b * STEPS + s) * VS;
            unsigned long long kmax = 0ull;
            #pragma unroll
            for (int g = 0; g < 4; g++) {
                int v = n0 + g * 16 + col;
                float val = acc[f][g][r] + bias[g];
                if (v < VS) {
                    orow[v] = val;
                    unsigned long long key =
                        ((unsigned long long)mono_key(val) << 32) |
                        (unsigned long long)(unsigned int)(~v);
                    if (key > kmax) kmax = key;
                }
            }
            #pragma unroll
            for (int mk = 1; mk < 16; mk <<= 1) {
                unsigned long long o = __shfl_xor(kmax, mk, 64);
                if (o > kmax) kmax = o;
            }
            if (col == 0) {
                // load-filter: stale reads are only ever lower -> conservative
                if (kmax > *(volatile unsigned long long*)&keys[b])
                    atomicMax(&keys[b], kmax);
            }
        }
    }
}

// -------------------- attention: SINGLE-PASS online softmax (R8 proven structure),
// now with fp32 expf in the serial online loop and the combine phase (non-recurrent
// path; softmax weights are scale-invariant, error ~1e-7 relative — same class as
// R8's reorder which was bit-identical). One block per batch row, 512 threads.
__global__ __launch_bounds__(512) void attn_kernel(
    const int* __restrict__ method_code, const float* __restrict__ code_emb,
    const float* __restrict__ h, unsigned short* __restrict__ t_hi,
    unsigned short* __restrict__ t_lo, unsigned long long* __restrict__ keys)
{
    const int b = blockIdx.x;
    const int tid = threadIdx.x;
    const int lane = tid & 63, wave = tid >> 6;

    __shared__ int    rows[LL];
    __shared__ float  ts[DD];
    __shared__ float  part[8][DD];
    __shared__ float  wmax[8];
    __shared__ double wsum[8];

    if (tid < LL) rows[tid] = method_code[b * LL + tid];
    if (tid == 0) keys[b] = 0ull;   // safe: gates GEMM already consumed last step's keys
    // h fragment in registers: 8 consecutive dims per lane (same for all 8 waves)
    const float* hb = h + (size_t)b * DD;
    float4 h0 = *(const float4*)(hb + lane * 8);
    float4 h1 = *(const float4*)(hb + lane * 8 + 4);
    __syncthreads();

    // single pass: score + online-softmax accumulate (e_l reused from registers)
    float  m = -INFINITY;
    double s = 0.0;
    float pa[8] = {0.f, 0.f, 0.f, 0.f, 0.f, 0.f, 0.f, 0.f};
    for (int l = wave; l < LL; l += 8) {
        const float* e = code_emb + (size_t)rows[l] * DD + lane * 8;
        float4 e0 = *(const float4*)e;
        float4 e1 = *(const float4*)(e + 4);
        float p = h0.x * e0.x + h0.y * e0.y + h0.z * e0.z + h0.w * e0.w
                + h1.x * e1.x + h1.y * e1.y + h1.z * e1.z + h1.w * e1.w;
        #pragma unroll
        for (int mk = 1; mk < 64; mk <<= 1) p += __shfl_xor(p, mk, 64);
        // p is uniform across the wave; online max update (branch is wave-uniform)
        if (p > m) {
            float scale = (m == -INFINITY) ? 0.f : expf(m - p);
            s *= (double)scale;
            #pragma unroll
            for (int j = 0; j < 8; j++) pa[j] *= scale;
            m = p;
        }
        float wf = expf(p - m);   // <= 1 (p==m gives exactly 1)
        s += (double)wf;
        pa[0] = fmaf(wf, e0.x, pa[0]); pa[1] = fmaf(wf, e0.y, pa[1]);
        pa[2] = fmaf(wf, e0.z, pa[2]); pa[3] = fmaf(wf, e0.w, pa[3]);
        pa[4] = fmaf(wf, e1.x, pa[4]); pa[5] = fmaf(wf, e1.y, pa[5]);
        pa[6] = fmaf(wf, e1.z, pa[6]); pa[7] = fmaf(wf, e1.w, pa[7]);
    }
    #pragma unroll
    for (int j = 0; j < 8; j++) part[wave][lane * 8 + j] = pa[j];
    if (lane == 0) { wmax[wave] = m; wsum[wave] = s; }
    __syncthreads();

    // cross-wave combine: each of 512 threads owns one dim (redundant M/S compute)
    {
        float M = wmax[0];
        #pragma unroll
        for (int w2 = 1; w2 < 8; w2++) M = fmaxf(M, wmax[w2]);
        float sc8[8];
        double S = 0.0;
        #pragma unroll
        for (int w2 = 0; w2 < 8; w2++) {
            sc8[w2] = expf(wmax[w2] - M);
            S += wsum[w2] * (double)sc8[w2];
        }
        const int d = tid;
        float v01 = part[0][d] * sc8[0] + part[1][d] * sc8[1];
        float v23 = part[2][d] * sc8[2] + part[3][d] * sc8[3];
        float v45 = part[4][d] * sc8[4] + part[5][d] * sc8[5];
        float v67 = part[6][d] * sc8[6] + part[7][d] * sc8[7];
        ts[d] = (float)((double)((v01 + v23) + (v45 + v67)) / S);
    }
    __syncthreads();

    // pack t row into fragment order: 64 lanes x 8 consecutive dims
    if (tid < 64) {
        const int cc = tid >> 2, kgg = tid & 3;
        const float* src = ts + cc * 32 + kgg * 8;   // = ts + tid*8 (contiguous)
        float4 v0 = *(const float4*)src;
        float4 v1 = *(const float4*)(src + 4);
        size_t base = (size_t)(b >> 4) * 8192 + (size_t)cc * 512
                    + (size_t)(kgg * 16 + (b & 15)) * 8;
        split_store8(v0, v1, t_hi + base, t_lo + base);
    }
}

extern "C" void kernel_launch(void* const* d_in, const int* in_sizes, int n_in,
                              void* d_out, int out_size, void* d_ws, size_t ws_size,
                              hipStream_t stream)
{
    const int*   method_code = (const int*)d_in[0];
    const float* code_emb    = (const float*)d_in[1];
    const float* sum_emb     = (const float*)d_in[2];
    const float* w_ih        = (const float*)d_in[3];
    const float* w_hh        = (const float*)d_in[4];
    const float* b_ih        = (const float*)d_in[5];
    const float* b_hh        = (const float*)d_in[6];
    const float* t_w         = (const float*)d_in[7];
    const float* t_b         = (const float*)d_in[8];
    const float* h_w         = (const float*)d_in[9];
    const float* h_b         = (const float*)d_in[10];
    const float* p_w         = (const float*)d_in[11];
    const float* p_b         = (const float*)d_in[12];
    float* out = (float*)d_out;

    float* h     = (float*)d_ws;                                   // 256*512 f32
    float* c     = h + BB * DD;                                    // 256*512 f32
    unsigned long long* keys = (unsigned long long*)(c + BB * DD); // 256
    unsigned short* a_hi   = (unsigned short*)(keys + BB);         // 256*512 (logits A)
    unsigned short* a_lo   = a_hi   + BB * DD;
    unsigned short* t_hi   = a_lo   + BB * DD;                     // t half of pre-A
    unsigned short* t_lo   = t_hi   + BB * DD;
    unsigned short* hp0_hi = t_lo   + BB * DD;                     // packed h, buffer 0
    unsigned short* hp0_lo = hp0_hi + BB * DD;
    unsigned short* hp1_hi = hp0_lo + BB * DD;                     // packed h, buffer 1
    unsigned short* hp1_lo = hp1_hi + BB * DD;
    unsigned short* w1_hi  = hp1_lo + BB * DD;                     // [w_ih|w_hh] perm 2048x1024
    unsigned short* w1_lo  = w1_hi  + (size_t)2048 * 1024;
    unsigned short* w2_hi  = w1_lo  + (size_t)2048 * 1024;         // [t_w|h_w] 512x1024
    unsigned short* w2_lo  = w2_hi  + (size_t)512 * 1024;
    unsigned short* p_hi   = w2_lo  + (size_t)512 * 1024;          // 20224*512
    unsigned short* p_lo   = p_hi   + (size_t)VS_PAD * DD;

    // zero h, c (contiguous) and hp0 pair (step-0 gates reads it)
    hipMemsetAsync(h, 0, (size_t)2 * BB * DD * sizeof(float), stream);
    hipMemsetAsync(hp0_hi, 0, (size_t)2 * BB * DD * sizeof(unsigned short), stream);
    init_keys_kernel<<<1, 256, 0, stream>>>(keys);
    split_pw_kernel<<<(VS_PAD * 64) / 256, 256, 0, stream>>>(p_w, p_hi, p_lo);
    split_wcat_kernel<1><<<1024, 256, 0, stream>>>(w_ih, w_hh, w1_hi, w1_lo);  // gate-interleaved
    split_wcat_kernel<0><<<256, 256, 0, stream>>>(t_w, h_w, w2_hi, w2_lo);     // R=512

    for (int s = 0; s < STEPS; s++) {
        const unsigned short* hin_hi  = (s & 1) ? hp1_hi : hp0_hi;
        const unsigned short* hin_lo  = (s & 1) ? hp1_lo : hp0_lo;
        unsigned short*       hout_hi = (s & 1) ? hp0_hi : hp1_hi;
        unsigned short*       hout_lo = (s & 1) ? hp0_lo : hp1_lo;

        // fused gather + gates GEMM + LSTM + h pack (M=256, N=2048, K=1024)
        gates_lstm_kernel<<<dim3(32, 8), 128, 0, stream>>>(
            sum_emb, keys, hin_hi, hin_lo, w1_hi, w1_lo, b_ih, b_hh,
            c, h, hout_hi, hout_lo);
        attn_kernel<<<256, 512, 0, stream>>>(method_code, code_emb, h, t_hi, t_lo, keys);
        // pre = tanh([t|h] @ [t_w|h_w]^T + t_b + h_b) -> packed logits-A (K split 4)
        pre_kernel<<<dim3(16, 16), 256, 0, stream>>>(
            t_hi, t_lo, hout_hi, hout_lo, w2_hi, w2_lo, t_b, h_b, a_hi, a_lo);
        // logits + greedy argmax (M=256, N=20224, K=512), 4 waves/block share B panels
        mfma_gemm<16, 2, 4><<<dim3(316, 2), 256, 0, stream>>>(
            a_hi, a_lo, nullptr, nullptr, p_hi, p_lo, p_b, nullptr,
            out, nullptr, nullptr, keys, s);
    }
}

// Round 12
// 1838.013 us; speedup vs baseline: 1.1444x; 1.0123x over previous
//
#include <hip/hip_runtime.h>
#include <math.h>

#define BB 256
#define LL 200
#define DD 512
#define VS 20000
#define VS_PAD 20224   // 316 * 64
#define STEPS 15

typedef __attribute__((ext_vector_type(8))) short bf16x8;
typedef __attribute__((ext_vector_type(4))) float f32x4;

// monotone mapping float -> uint32 preserving order
__device__ __forceinline__ unsigned int mono_key(float f) {
    unsigned int u = __float_as_uint(f);
    return (u & 0x80000000u) ? ~u : (u | 0x80000000u);
}

// bf16 round-to-nearest-even split helpers (bit ops, header-independent)
__device__ __forceinline__ unsigned short f2bf_rn(float x) {
    unsigned int u = __float_as_uint(x);
    unsigned int r = (u + 0x7FFFu + ((u >> 16) & 1u)) >> 16;
    return (unsigned short)r;
}
__device__ __forceinline__ float bf2f(unsigned short b) {
    return __uint_as_float((unsigned int)b << 16);
}

// split 8 consecutive floats into bf16 hi + lo residual, store 16B each
__device__ __forceinline__ void split_store8(float4 v0, float4 v1,
    unsigned short* __restrict__ hi, unsigned short* __restrict__ lo)
{
    ushort4 h0, h1, l0, l1;
    h0.x = f2bf_rn(v0.x); l0.x = f2bf_rn(v0.x - bf2f(h0.x));
    h0.y = f2bf_rn(v0.y); l0.y = f2bf_rn(v0.y - bf2f(h0.y));
    h0.z = f2bf_rn(v0.z); l0.z = f2bf_rn(v0.z - bf2f(h0.z));
    h0.w = f2bf_rn(v0.w); l0.w = f2bf_rn(v0.w - bf2f(h0.w));
    h1.x = f2bf_rn(v1.x); l1.x = f2bf_rn(v1.x - bf2f(h1.x));
    h1.y = f2bf_rn(v1.y); l1.y = f2bf_rn(v1.y - bf2f(h1.y));
    h1.z = f2bf_rn(v1.z); l1.z = f2bf_rn(v1.z - bf2f(h1.z));
    h1.w = f2bf_rn(v1.w); l1.w = f2bf_rn(v1.w - bf2f(h1.w));
    *(ushort4*)hi = h0; *(ushort4*)(hi + 4) = h1;
    *(ushort4*)lo = l0; *(ushort4*)(lo + 4) = l1;
}

// same split but into register fragments (for inline gather in the gates GEMM)
__device__ __forceinline__ void split_frag(float4 v0, float4 v1, bf16x8& hi, bf16x8& lo)
{
    float vv[8] = {v0.x, v0.y, v0.z, v0.w, v1.x, v1.y, v1.z, v1.w};
    #pragma unroll
    for (int j = 0; j < 8; j++) {
        unsigned short hb = f2bf_rn(vv[j]);
        hi[j] = (short)hb;
        lo[j] = (short)f2bf_rn(vv[j] - bf2f(hb));
    }
}

__global__ __launch_bounds__(256) void init_keys_kernel(unsigned long long* keys) {
    // low 32 bits = ~token ; decode token = ~(uint32)key. SOS token = 1.
    keys[threadIdx.x] = (unsigned long long)(unsigned int)(~1u);
}

// -------------------- fragment-order packing convention (16x16x32 bf16 MFMA):
// elem idx = panel*(NCH*512) + chunk*512 + lane*8 + j  where
// panel = row/16, chunk = k/32, lane = ((k%32)/8)*16 + row%16, j = k%8.
// A-side buffers are per-512-K halves: panel stride 8192 (16 chunks).

// one-time split of p_w [VS][512] -> hi/lo fragment order (K=512, panel stride 8192)
__global__ __launch_bounds__(256) void split_pw_kernel(
    const float* __restrict__ p_w, unsigned short* __restrict__ p_hi,
    unsigned short* __restrict__ p_lo)
{
    size_t q = (size_t)blockIdx.x * 256 + threadIdx.x;   // chunk id, VS_PAD*64 total
    int P   = (int)(q >> 10);
    int rem = (int)(q & 1023);
    int c   = rem >> 6;
    int l   = rem & 63;
    int row = P * 16 + (l & 15);
    int ks  = c * 32 + (l >> 4) * 8;
    float4 v0 = {0.f, 0.f, 0.f, 0.f}, v1 = {0.f, 0.f, 0.f, 0.f};
    if (row < VS) {
        const float* src = p_w + (size_t)row * DD + ks;
        v0 = *(const float4*)src;
        v1 = *(const float4*)(src + 4);
    }
    split_store8(v0, v1, p_hi + q * 8, p_lo + q * 8);
}

// one-time split of concat weights [R][1024] = [s0 | s1] (each [R][512]) -> hi/lo
// fragment order with panel stride 16384 (32 chunks). R must be multiple of 16.
// PERM=1 (gates W): packed panel P holds orig rows (P&3)*512 + (P>>2)*16 + col
// (gate-interleaved so one wave's 4 fragment columns = the 4 gates of one feature).
template <int PERM>
__global__ __launch_bounds__(256) void split_wcat_kernel(
    const float* __restrict__ s0, const float* __restrict__ s1,
    unsigned short* __restrict__ wh, unsigned short* __restrict__ wl)
{
    size_t q = (size_t)blockIdx.x * 256 + threadIdx.x;   // R*128 groups
    int P   = (int)(q >> 11);
    int rem = (int)(q & 2047);
    int c   = rem >> 6;
    int l   = rem & 63;
    int row;
    if (PERM) row = (P & 3) * 512 + (P >> 2) * 16 + (l & 15);
    else      row = P * 16 + (l & 15);
    int k   = c * 32 + (l >> 4) * 8;
    const float* src = (k < 512) ? (s0 + (size_t)row * DD + k)
                                 : (s1 + (size_t)row * DD + (k - 512));
    float4 v0 = *(const float4*)src;
    float4 v1 = *(const float4*)(src + 4);
    split_store8(v0, v1, wh + q * 8, wl + q * 8);
}

// -------------------- fused: token gather + gates GEMM + LSTM pointwise + h pack.
// R9-PROVEN VERSION (split-K gates failed twice — R3, R10 — lane closed).
// 2-wave blocks; wave w owns m-tile (blockIdx.y*2+w)*16; 256 blocks cover all CUs.
// 16(m) x 64(n = 16 feats x 4 gates) tile, full K=32 chunks per wave.
// Epilogue = fp64 LSTM pointwise (4 cells/lane; RECURRENT state stays fp64).
// grid (32 nt, 8) x 128 threads = 256 blocks, 512 waves.
__global__ __launch_bounds__(128) void gates_lstm_kernel(
    const float* __restrict__ sum_emb, const unsigned long long* __restrict__ keys,
    const unsigned short* __restrict__ hin_hi, const unsigned short* __restrict__ hin_lo,
    const unsigned short* __restrict__ w1h, const unsigned short* __restrict__ w1l,
    const float* __restrict__ bi, const float* __restrict__ bh,
    float* __restrict__ c, float* __restrict__ h,
    unsigned short* __restrict__ hout_hi, unsigned short* __restrict__ hout_lo)
{
    const int tid  = threadIdx.x;
    const int lane = tid & 63;
    const int wav  = tid >> 6;
    const int col = lane & 15;
    const int kg  = lane >> 4;
    const int m0  = (blockIdx.y * 2 + wav) * 16;
    const int nt  = blockIdx.x;               // features nt*16 .. nt*16+15

    unsigned int tok = ~(unsigned int)(keys[m0 + col] & 0xFFFFFFFFull);

    const size_t ahoff = (size_t)(m0 >> 4) * 8192 + (size_t)lane * 8;
    const size_t boff  = (size_t)(nt * 4) * 16384 + (size_t)lane * 8;

    f32x4 acc[4];
    #pragma unroll
    for (int g = 0; g < 4; g++) acc[g] = (f32x4){0.f, 0.f, 0.f, 0.f};

    bf16x8 fa_h[2], fa_l[2], fb_h[2][4], fb_l[2][4];

#define GL_LOAD(C, BUF)                                                            \
    {                                                                              \
        if ((C) < 16) {                                                            \
            const float* s_ = sum_emb + (size_t)tok * DD + (C) * 32 + kg * 8;      \
            float4 v0 = *(const float4*)s_;                                        \
            float4 v1 = *(const float4*)(s_ + 4);                                  \
            split_frag(v0, v1, fa_h[BUF], fa_l[BUF]);                              \
        } else {                                                                   \
            fa_h[BUF] = *(const bf16x8*)(hin_hi + ahoff + ((C) - 16) * 512);       \
            fa_l[BUF] = *(const bf16x8*)(hin_lo + ahoff + ((C) - 16) * 512);       \
        }                                                                          \
        _Pragma("unroll")                                                          \
        for (int g = 0; g < 4; g++) {                                              \
            fb_h[BUF][g] = *(const bf16x8*)(w1h + boff + (size_t)g * 16384 + (C) * 512); \
            fb_l[BUF][g] = *(const bf16x8*)(w1l + boff + (size_t)g * 16384 + (C) * 512); \
        }                                                                          \
    }

    GL_LOAD(0, 0);
    #pragma unroll
    for (int cc = 0; cc < 32; cc++) {
        const int cur = cc & 1, nxt = cur ^ 1;
        if (cc < 31) GL_LOAD(cc + 1, nxt);
        #pragma unroll
        for (int g = 0; g < 4; g++) {
            acc[g] = __builtin_amdgcn_mfma_f32_16x16x32_bf16(fa_h[cur], fb_h[cur][g], acc[g], 0, 0, 0);
            acc[g] = __builtin_amdgcn_mfma_f32_16x16x32_bf16(fa_h[cur], fb_l[cur][g], acc[g], 0, 0, 0);
            acc[g] = __builtin_amdgcn_mfma_f32_16x16x32_bf16(fa_l[cur], fb_h[cur][g], acc[g], 0, 0, 0);
        }
    }
#undef GL_LOAD

    const int feat = nt * 16 + col;
    float bias[4];
    #pragma unroll
    for (int g = 0; g < 4; g++)
        bias[g] = bi[g * 512 + feat] + bh[g * 512 + feat];

    // LSTM pointwise (fp64, identical math), 4 cells/lane
    #pragma unroll
    for (int r = 0; r < 4; r++) {
        const int b = m0 + kg * 4 + r;
        float vi = acc[0][r] + bias[0];
        float vf = acc[1][r] + bias[1];
        float vg = acc[2][r] + bias[2];
        float vo = acc[3][r] + bias[3];
        double ig = 1.0 / (1.0 + exp(-(double)vi));
        double fg = 1.0 / (1.0 + exp(-(double)vf));
        double gv = tanh((double)vg);
        double og = 1.0 / (1.0 + exp(-(double)vo));
        size_t cidx = (size_t)b * DD + feat;
        double cn = fg * (double)c[cidx] + ig * gv;
        double hn = og * tanh(cn);
        c[cidx] = (float)cn;
        float hf = (float)hn;
        h[cidx] = hf;
        size_t hidx = (size_t)(b >> 4) * 8192 + (size_t)(feat >> 5) * 512
                    + (size_t)(((feat >> 3) & 3) * 16 + (b & 15)) * 8 + (feat & 7);
        unsigned short hb2 = f2bf_rn(hf);
        hout_hi[hidx] = hb2;
        hout_lo[hidx] = f2bf_rn(hf - bf2f(hb2));
    }
}

// -------------------- pre GEMM: tanh([t|h] @ [t_w|h_w]^T + t_b + h_b) -> packed A.
// 4-wave blocks, 16(m) x 32(n) tile, 4-way K-split (wave w = chunks 8w..8w+7).
// Partials reduced via LDS; tanhf epilogue (non-recurrent path; fp32 transcendental).
// grid (16 n-tiles, 16 m-tiles) = 1024 waves.
__global__ __launch_bounds__(256) void pre_kernel(
    const unsigned short* __restrict__ t_hi, const unsigned short* __restrict__ t_lo,
    const unsigned short* __restrict__ h_hi, const unsigned short* __restrict__ h_lo,
    const unsigned short* __restrict__ w2h, const unsigned short* __restrict__ w2l,
    const float* __restrict__ tb, const float* __restrict__ hbv,
    unsigned short* __restrict__ o_hi, unsigned short* __restrict__ o_lo)
{
    const int tid  = threadIdx.x;
    const int lane = tid & 63;
    const int wav  = tid >> 6;        // K-split: absolute chunks wav*8 .. wav*8+7
    const int col  = lane & 15;
    const int kg   = lane >> 4;
    const int m0   = blockIdx.y * 16;
    const int n0   = blockIdx.x * 32;

    const unsigned short* ah = (wav < 2) ? t_hi : h_hi;
    const unsigned short* al = (wav < 2) ? t_lo : h_lo;
    const size_t aoff = (size_t)(m0 >> 4) * 8192 + (size_t)lane * 8
                      + (size_t)((wav & 1) * 8) * 512;
    const size_t boff = (size_t)(n0 >> 4) * 16384 + (size_t)lane * 8
                      + (size_t)(wav * 8) * 512;

    f32x4 acc[2];
    acc[0] = (f32x4){0.f, 0.f, 0.f, 0.f};
    acc[1] = (f32x4){0.f, 0.f, 0.f, 0.f};

    bf16x8 fa_h[2], fa_l[2], fb_h[2][2], fb_l[2][2];
    fa_h[0] = *(const bf16x8*)(ah + aoff);
    fa_l[0] = *(const bf16x8*)(al + aoff);
    #pragma unroll
    for (int g = 0; g < 2; g++) {
        fb_h[0][g] = *(const bf16x8*)(w2h + boff + (size_t)g * 16384);
        fb_l[0][g] = *(const bf16x8*)(w2l + boff + (size_t)g * 16384);
    }
    #pragma unroll
    for (int cc = 0; cc < 8; cc++) {
        const int cur = cc & 1, nxt = cur ^ 1;
        if (cc < 7) {
            const int off = (cc + 1) * 512;
            fa_h[nxt] = *(const bf16x8*)(ah + aoff + off);
            fa_l[nxt] = *(const bf16x8*)(al + aoff + off);
            #pragma unroll
            for (int g = 0; g < 2; g++) {
                fb_h[nxt][g] = *(const bf16x8*)(w2h + boff + (size_t)g * 16384 + off);
                fb_l[nxt][g] = *(const bf16x8*)(w2l + boff + (size_t)g * 16384 + off);
            }
        }
        #pragma unroll
        for (int g = 0; g < 2; g++) {
            acc[g] = __builtin_amdgcn_mfma_f32_16x16x32_bf16(fa_h[cur], fb_h[cur][g], acc[g], 0, 0, 0);
            acc[g] = __builtin_amdgcn_mfma_f32_16x16x32_bf16(fa_h[cur], fb_l[cur][g], acc[g], 0, 0, 0);
            acc[g] = __builtin_amdgcn_mfma_f32_16x16x32_bf16(fa_l[cur], fb_h[cur][g], acc[g], 0, 0, 0);
        }
    }

    __shared__ float psum[4][16][32];
    #pragma unroll
    for (int g = 0; g < 2; g++)
        #pragma unroll
        for (int r = 0; r < 4; r++)
            psum[wav][kg * 4 + r][g * 16 + col] = acc[g][r];
    __syncthreads();

    #pragma unroll
    for (int e = 0; e < 2; e++) {
        const int idx  = tid * 2 + e;
        const int row  = idx >> 5, coln = idx & 31;
        const int b    = m0 + row;
        const int n    = n0 + coln;
        float accs = (psum[0][row][coln] + psum[1][row][coln])
                   + (psum[2][row][coln] + psum[3][row][coln]);
        float val = accs + (tb[n] + hbv[n]);
        float v2 = tanhf(val);
        int P = b >> 4, colb = b & 15;
        int cc2 = n >> 5, kgg = (n >> 3) & 3, jj = n & 7;
        size_t oidx = (size_t)P * 8192 + (size_t)cc2 * 512
                    + (size_t)(kgg * 16 + colb) * 8 + jj;
        unsigned short hb = f2bf_rn(v2);
        o_hi[oidx] = hb;
        o_lo[oidx] = f2bf_rn(v2 - bf2f(hb));
    }
}

// -------------------- logits GEMM (bf16x3 MFMA) + bias + store + argmax (R5 proven).
// 32(m) x 64(n) tile per wave, WPB waves per block sharing B panels.
template <int NCH, int EPI, int WPB>
__global__ __launch_bounds__(64 * WPB, 3) void mfma_gemm(
    const unsigned short* __restrict__ a0h, const unsigned short* __restrict__ a0l,
    const unsigned short* __restrict__ a1h, const unsigned short* __restrict__ a1l,
    const unsigned short* __restrict__ bmh, const unsigned short* __restrict__ bml,
    const float* __restrict__ bias0, const float* __restrict__ bias1,
    float* __restrict__ outp,
    unsigned short* __restrict__ o_hi, unsigned short* __restrict__ o_lo,
    unsigned long long* __restrict__ keys, int s)
{
    const int tid  = threadIdx.x;
    const int lane = tid & 63;
    const int wav  = tid >> 6;
    const int col = lane & 15;        // fragment row (A) / column (B)
    const int kg  = lane >> 4;        // k-group 0..3
    const int m0 = (blockIdx.y * WPB + wav) * 32;
    const int n0 = blockIdx.x * 64;

    const size_t aoff = (size_t)(m0 >> 4) * 8192 + (size_t)lane * 8;
    const size_t boff = (size_t)(n0 >> 4) * (NCH * 512) + (size_t)lane * 8;

    f32x4 acc[2][4];
    #pragma unroll
    for (int f = 0; f < 2; f++)
        #pragma unroll
        for (int g = 0; g < 4; g++)
            acc[f][g] = (f32x4){0.f, 0.f, 0.f, 0.f};

    bf16x8 fah[2][2], fal[2][2], fbh[2][4], fbl[2][4];

#define LOAD_CHUNK(C, BUF)                                                         \
    {                                                                              \
        const unsigned short* ah_ = ((NCH == 16) || ((C) < 16)) ? a0h : a1h;       \
        const unsigned short* al_ = ((NCH == 16) || ((C) < 16)) ? a0l : a1l;       \
        const int cc_ = (C) & 15;                                                  \
        _Pragma("unroll")                                                          \
        for (int f = 0; f < 2; f++) {                                              \
            fah[BUF][f] = *(const bf16x8*)(ah_ + aoff + (size_t)f * 8192 + cc_ * 512); \
            fal[BUF][f] = *(const bf16x8*)(al_ + aoff + (size_t)f * 8192 + cc_ * 512); \
        }                                                                          \
        _Pragma("unroll")                                                          \
        for (int g = 0; g < 4; g++) {                                              \
            fbh[BUF][g] = *(const bf16x8*)(bmh + boff + (size_t)g * (NCH * 512) + (C) * 512); \
            fbl[BUF][g] = *(const bf16x8*)(bml + boff + (size_t)g * (NCH * 512) + (C) * 512); \
        }                                                                          \
    }

    LOAD_CHUNK(0, 0);
    #pragma unroll
    for (int c = 0; c < NCH; c++) {
        const int cur = c & 1, nxt = cur ^ 1;
        if (c < NCH - 1) LOAD_CHUNK(c + 1, nxt);
        #pragma unroll
        for (int f = 0; f < 2; f++)
            #pragma unroll
            for (int g = 0; g < 4; g++) {
                acc[f][g] = __builtin_amdgcn_mfma_f32_16x16x32_bf16(fah[cur][f], fbh[cur][g], acc[f][g], 0, 0, 0);
                acc[f][g] = __builtin_amdgcn_mfma_f32_16x16x32_bf16(fah[cur][f], fbl[cur][g], acc[f][g], 0, 0, 0);
                acc[f][g] = __builtin_amdgcn_mfma_f32_16x16x32_bf16(fal[cur][f], fbh[cur][g], acc[f][g], 0, 0, 0);
            }
    }
#undef LOAD_CHUNK

    // bias per n-col of this lane (col fixed per lane)
    float bias[4];
    #pragma unroll
    for (int g = 0; g < 4; g++) {
        int v = n0 + g * 16 + col;
        bias[g] = (v < VS) ? bias0[v] : 0.f;
    }

    // epilogue (C/D: col = lane&15, row = kg*4 + reg)
    #pragma unroll
    for (int f = 0; f < 2; f++) {
        #pragma unroll
        for (int r = 0; r < 4; r++) {
            const int b = m0 + f * 16 + kg * 4 + r;
            float* orow = outp + ((size_t)b * STEPS + s) * VS;
            unsigned long long kmax = 0ull;
            #pragma unroll
            for (int g = 0; g < 4; g++) {
                int v = n0 + g * 16 + col;
                float val = acc[f][g][r] + bias[g];
                if (v < VS) {
                    orow[v] = val;
                    unsigned long long key =
                        ((unsigned long long)mono_key(val) << 32) |
                        (unsigned long long)(unsigned int)(~v);
                    if (key > kmax) kmax = key;
                }
            }
            #pragma unroll
            for (int mk = 1; mk < 16; mk <<= 1) {
                unsigned long long o = __shfl_xor(kmax, mk, 64);
                if (o > kmax) kmax = o;
            }
            if (col == 0) {
                // load-filter: stale reads are only ever lower -> conservative
                if (kmax > *(volatile unsigned long long*)&keys[b])
                    atomicMax(&keys[b], kmax);
            }
        }
    }
}

// -------------------- attention: SINGLE-PASS online softmax, 16 waves (1024 thr).
// attn was grid-limited at 1 block/CU = 8 waves/CU; 16 waves/block doubles the
// per-CU latency hiding for the L3 gather loop. Wave w handles l = w, w+16, ...
// (12-13 iters). Same online-softmax algorithm; combine over 16 partials.
__global__ __launch_bounds__(1024) void attn_kernel(
    const int* __restrict__ method_code, const float* __restrict__ code_emb,
    const float* __restrict__ h, unsigned short* __restrict__ t_hi,
    unsigned short* __restrict__ t_lo, unsigned long long* __restrict__ keys)
{
    const int b = blockIdx.x;
    const int tid = threadIdx.x;
    const int lane = tid & 63, wave = tid >> 6;   // wave 0..15

    __shared__ int    rows[LL];
    __shared__ float  ts[DD];
    __shared__ float  part[16][DD];
    __shared__ float  wmax[16];
    __shared__ double wsum[16];

    if (tid < LL) rows[tid] = method_code[b * LL + tid];
    if (tid == 0) keys[b] = 0ull;   // safe: gates GEMM already consumed last step's keys
    // h fragment in registers: 8 consecutive dims per lane (same for all waves)
    const float* hb = h + (size_t)b * DD;
    float4 h0 = *(const float4*)(hb + lane * 8);
    float4 h1 = *(const float4*)(hb + lane * 8 + 4);
    __syncthreads();

    // single pass: score + online-softmax accumulate (e_l reused from registers)
    float  m = -INFINITY;
    double s = 0.0;
    float pa[8] = {0.f, 0.f, 0.f, 0.f, 0.f, 0.f, 0.f, 0.f};
    for (int l = wave; l < LL; l += 16) {
        const float* e = code_emb + (size_t)rows[l] * DD + lane * 8;
        float4 e0 = *(const float4*)e;
        float4 e1 = *(const float4*)(e + 4);
        float p = h0.x * e0.x + h0.y * e0.y + h0.z * e0.z + h0.w * e0.w
                + h1.x * e1.x + h1.y * e1.y + h1.z * e1.z + h1.w * e1.w;
        #pragma unroll
        for (int mk = 1; mk < 64; mk <<= 1) p += __shfl_xor(p, mk, 64);
        // p is uniform across the wave; online max update (branch is wave-uniform)
        if (p > m) {
            float scale = (m == -INFINITY) ? 0.f : expf(m - p);
            s *= (double)scale;
            #pragma unroll
            for (int j = 0; j < 8; j++) pa[j] *= scale;
            m = p;
        }
        float wf = expf(p - m);   // <= 1 (p==m gives exactly 1)
        s += (double)wf;
        pa[0] = fmaf(wf, e0.x, pa[0]); pa[1] = fmaf(wf, e0.y, pa[1]);
        pa[2] = fmaf(wf, e0.z, pa[2]); pa[3] = fmaf(wf, e0.w, pa[3]);
        pa[4] = fmaf(wf, e1.x, pa[4]); pa[5] = fmaf(wf, e1.y, pa[5]);
        pa[6] = fmaf(wf, e1.z, pa[6]); pa[7] = fmaf(wf, e1.w, pa[7]);
    }
    #pragma unroll
    for (int j = 0; j < 8; j++) part[wave][lane * 8 + j] = pa[j];
    if (lane == 0) { wmax[wave] = m; wsum[wave] = s; }
    __syncthreads();

    // cross-wave combine: threads 0..511 each own one dim (redundant M/S compute)
    if (tid < DD) {
        float M = wmax[0];
        #pragma unroll
        for (int w2 = 1; w2 < 16; w2++) M = fmaxf(M, wmax[w2]);
        float sc16[16];
        double S = 0.0;
        #pragma unroll
        for (int w2 = 0; w2 < 16; w2++) {
            sc16[w2] = expf(wmax[w2] - M);
            S += wsum[w2] * (double)sc16[w2];
        }
        const int d = tid;
        float q0 = (part[0][d] * sc16[0]  + part[1][d] * sc16[1])
                 + (part[2][d] * sc16[2]  + part[3][d] * sc16[3]);
        float q1 = (part[4][d] * sc16[4]  + part[5][d] * sc16[5])
                 + (part[6][d] * sc16[6]  + part[7][d] * sc16[7]);
        float q2 = (part[8][d] * sc16[8]  + part[9][d] * sc16[9])
                 + (part[10][d] * sc16[10] + part[11][d] * sc16[11]);
        float q3 = (part[12][d] * sc16[12] + part[13][d] * sc16[13])
                 + (part[14][d] * sc16[14] + part[15][d] * sc16[15]);
        ts[d] = (float)((double)((q0 + q1) + (q2 + q3)) / S);
    }
    __syncthreads();

    // pack t row into fragment order: 64 lanes x 8 consecutive dims
    if (tid < 64) {
        const int cc = tid >> 2, kgg = tid & 3;
        const float* src = ts + cc * 32 + kgg * 8;   // = ts + tid*8 (contiguous)
        float4 v0 = *(const float4*)src;
        float4 v1 = *(const float4*)(src + 4);
        size_t base = (size_t)(b >> 4) * 8192 + (size_t)cc * 512
                    + (size_t)(kgg * 16 + (b & 15)) * 8;
        split_store8(v0, v1, t_hi + base, t_lo + base);
    }
}

extern "C" void kernel_launch(void* const* d_in, const int* in_sizes, int n_in,
                              void* d_out, int out_size, void* d_ws, size_t ws_size,
                              hipStream_t stream)
{
    const int*   method_code = (const int*)d_in[0];
    const float* code_emb    = (const float*)d_in[1];
    const float* sum_emb     = (const float*)d_in[2];
    const float* w_ih        = (const float*)d_in[3];
    const float* w_hh        = (const float*)d_in[4];
    const float* b_ih        = (const float*)d_in[5];
    const float* b_hh        = (const float*)d_in[6];
    const float* t_w         = (const float*)d_in[7];
    const float* t_b         = (const float*)d_in[8];
    const float* h_w         = (const float*)d_in[9];
    const float* h_b         = (const float*)d_in[10];
    const float* p_w         = (const float*)d_in[11];
    const float* p_b         = (const float*)d_in[12];
    float* out = (float*)d_out;

    float* h     = (float*)d_ws;                                   // 256*512 f32
    float* c     = h + BB * DD;                                    // 256*512 f32
    unsigned long long* keys = (unsigned long long*)(c + BB * DD); // 256
    unsigned short* a_hi   = (unsigned short*)(keys + BB);         // 256*512 (logits A)
    unsigned short* a_lo   = a_hi   + BB * DD;
    unsigned short* t_hi   = a_lo   + BB * DD;                     // t half of pre-A
    unsigned short* t_lo   = t_hi   + BB * DD;
    unsigned short* hp0_hi = t_lo   + BB * DD;                     // packed h, buffer 0
    unsigned short* hp0_lo = hp0_hi + BB * DD;
    unsigned short* hp1_hi = hp0_lo + BB * DD;                     // packed h, buffer 1
    unsigned short* hp1_lo = hp1_hi + BB * DD;
    unsigned short* w1_hi  = hp1_lo + BB * DD;                     // [w_ih|w_hh] perm 2048x1024
    unsigned short* w1_lo  = w1_hi  + (size_t)2048 * 1024;
    unsigned short* w2_hi  = w1_lo  + (size_t)2048 * 1024;         // [t_w|h_w] 512x1024
    unsigned short* w2_lo  = w2_hi  + (size_t)512 * 1024;
    unsigned short* p_hi   = w2_lo  + (size_t)512 * 1024;          // 20224*512
    unsigned short* p_lo   = p_hi   + (size_t)VS_PAD * DD;

    // zero h, c (contiguous) and hp0 pair (step-0 gates reads it)
    hipMemsetAsync(h, 0, (size_t)2 * BB * DD * sizeof(float), stream);
    hipMemsetAsync(hp0_hi, 0, (size_t)2 * BB * DD * sizeof(unsigned short), stream);
    init_keys_kernel<<<1, 256, 0, stream>>>(keys);
    split_pw_kernel<<<(VS_PAD * 64) / 256, 256, 0, stream>>>(p_w, p_hi, p_lo);
    split_wcat_kernel<1><<<1024, 256, 0, stream>>>(w_ih, w_hh, w1_hi, w1_lo);  // gate-interleaved
    split_wcat_kernel<0><<<256, 256, 0, stream>>>(t_w, h_w, w2_hi, w2_lo);     // R=512

    for (int s = 0; s < STEPS; s++) {
        const unsigned short* hin_hi  = (s & 1) ? hp1_hi : hp0_hi;
        const unsigned short* hin_lo  = (s & 1) ? hp1_lo : hp0_lo;
        unsigned short*       hout_hi = (s & 1) ? hp0_hi : hp1_hi;
        unsigned short*       hout_lo = (s & 1) ? hp0_lo : hp1_lo;

        // fused gather + gates GEMM + LSTM + h pack (M=256, N=2048, K=1024)
        gates_lstm_kernel<<<dim3(32, 8), 128, 0, stream>>>(
            sum_emb, keys, hin_hi, hin_lo, w1_hi, w1_lo, b_ih, b_hh,
            c, h, hout_hi, hout_lo);
        attn_kernel<<<256, 1024, 0, stream>>>(method_code, code_emb, h, t_hi, t_lo, keys);
        // pre = tanh([t|h] @ [t_w|h_w]^T + t_b + h_b) -> packed logits-A (K split 4)
        pre_kernel<<<dim3(16, 16), 256, 0, stream>>>(
            t_hi, t_lo, hout_hi, hout_lo, w2_hi, w2_lo, t_b, h_b, a_hi, a_lo);
        // logits + greedy argmax (M=256, N=20224, K=512), 4 waves/block share B panels
        mfma_gemm<16, 2, 4><<<dim3(316, 2), 256, 0, stream>>>(
            a_hi, a_lo, nullptr, nullptr, p_hi, p_lo, p_b, nullptr,
            out, nullptr, nullptr, keys, s);
    }
}

// Round 13
// 1815.853 us; speedup vs baseline: 1.1584x; 1.0122x over previous
//
#include <hip/hip_runtime.h>
#include <math.h>

#define BB 256
#define LL 200
#define DD 512
#define VS 20000
#define VS_PAD 20224   // 316 * 64
#define STEPS 15

typedef __attribute__((ext_vector_type(8))) short bf16x8;
typedef __attribute__((ext_vector_type(4))) float f32x4;

// monotone mapping float -> uint32 preserving order
__device__ __forceinline__ unsigned int mono_key(float f) {
    unsigned int u = __float_as_uint(f);
    return (u & 0x80000000u) ? ~u : (u | 0x80000000u);
}

// bf16 round-to-nearest-even split helpers (bit ops, header-independent)
__device__ __forceinline__ unsigned short f2bf_rn(float x) {
    unsigned int u = __float_as_uint(x);
    unsigned int r = (u + 0x7FFFu + ((u >> 16) & 1u)) >> 16;
    return (unsigned short)r;
}
__device__ __forceinline__ float bf2f(unsigned short b) {
    return __uint_as_float((unsigned int)b << 16);
}

// split 8 consecutive floats into bf16 hi + lo residual, store 16B each
__device__ __forceinline__ void split_store8(float4 v0, float4 v1,
    unsigned short* __restrict__ hi, unsigned short* __restrict__ lo)
{
    ushort4 h0, h1, l0, l1;
    h0.x = f2bf_rn(v0.x); l0.x = f2bf_rn(v0.x - bf2f(h0.x));
    h0.y = f2bf_rn(v0.y); l0.y = f2bf_rn(v0.y - bf2f(h0.y));
    h0.z = f2bf_rn(v0.z); l0.z = f2bf_rn(v0.z - bf2f(h0.z));
    h0.w = f2bf_rn(v0.w); l0.w = f2bf_rn(v0.w - bf2f(h0.w));
    h1.x = f2bf_rn(v1.x); l1.x = f2bf_rn(v1.x - bf2f(h1.x));
    h1.y = f2bf_rn(v1.y); l1.y = f2bf_rn(v1.y - bf2f(h1.y));
    h1.z = f2bf_rn(v1.z); l1.z = f2bf_rn(v1.z - bf2f(h1.z));
    h1.w = f2bf_rn(v1.w); l1.w = f2bf_rn(v1.w - bf2f(h1.w));
    *(ushort4*)hi = h0; *(ushort4*)(hi + 4) = h1;
    *(ushort4*)lo = l0; *(ushort4*)(lo + 4) = l1;
}

// same split but into register fragments (for inline gather in the gates GEMM)
__device__ __forceinline__ void split_frag(float4 v0, float4 v1, bf16x8& hi, bf16x8& lo)
{
    float vv[8] = {v0.x, v0.y, v0.z, v0.w, v1.x, v1.y, v1.z, v1.w};
    #pragma unroll
    for (int j = 0; j < 8; j++) {
        unsigned short hb = f2bf_rn(vv[j]);
        hi[j] = (short)hb;
        lo[j] = (short)f2bf_rn(vv[j] - bf2f(hb));
    }
}

__global__ __launch_bounds__(256) void init_keys_kernel(unsigned long long* keys) {
    // low 32 bits = ~token ; decode token = ~(uint32)key. SOS token = 1.
    keys[threadIdx.x] = (unsigned long long)(unsigned int)(~1u);
}

// -------------------- fragment-order packing convention (16x16x32 bf16 MFMA):
// elem idx = panel*(NCH*512) + chunk*512 + lane*8 + j  where
// panel = row/16, chunk = k/32, lane = ((k%32)/8)*16 + row%16, j = k%8.
// A-side buffers are per-512-K halves: panel stride 8192 (16 chunks).

// one-time split of p_w [VS][512] -> hi/lo fragment order (K=512, panel stride 8192)
__global__ __launch_bounds__(256) void split_pw_kernel(
    const float* __restrict__ p_w, unsigned short* __restrict__ p_hi,
    unsigned short* __restrict__ p_lo)
{
    size_t q = (size_t)blockIdx.x * 256 + threadIdx.x;   // chunk id, VS_PAD*64 total
    int P   = (int)(q >> 10);
    int rem = (int)(q & 1023);
    int c   = rem >> 6;
    int l   = rem & 63;
    int row = P * 16 + (l & 15);
    int ks  = c * 32 + (l >> 4) * 8;
    float4 v0 = {0.f, 0.f, 0.f, 0.f}, v1 = {0.f, 0.f, 0.f, 0.f};
    if (row < VS) {
        const float* src = p_w + (size_t)row * DD + ks;
        v0 = *(const float4*)src;
        v1 = *(const float4*)(src + 4);
    }
    split_store8(v0, v1, p_hi + q * 8, p_lo + q * 8);
}

// one-time split of concat weights [R][1024] = [s0 | s1] (each [R][512]) -> hi/lo
// fragment order with panel stride 16384 (32 chunks). R must be multiple of 16.
// PERM=1 (gates W): packed panel P holds orig rows (P&3)*512 + (P>>2)*16 + col
// (gate-interleaved so one wave's 4 fragment columns = the 4 gates of one feature).
template <int PERM>
__global__ __launch_bounds__(256) void split_wcat_kernel(
    const float* __restrict__ s0, const float* __restrict__ s1,
    unsigned short* __restrict__ wh, unsigned short* __restrict__ wl)
{
    size_t q = (size_t)blockIdx.x * 256 + threadIdx.x;   // R*128 groups
    int P   = (int)(q >> 11);
    int rem = (int)(q & 2047);
    int c   = rem >> 6;
    int l   = rem & 63;
    int row;
    if (PERM) row = (P & 3) * 512 + (P >> 2) * 16 + (l & 15);
    else      row = P * 16 + (l & 15);
    int k   = c * 32 + (l >> 4) * 8;
    const float* src = (k < 512) ? (s0 + (size_t)row * DD + k)
                                 : (s1 + (size_t)row * DD + (k - 512));
    float4 v0 = *(const float4*)src;
    float4 v1 = *(const float4*)(src + 4);
    split_store8(v0, v1, wh + q * 8, wl + q * 8);
}

// -------------------- fused: token gather + gates GEMM + LSTM pointwise + h pack.
// R9-PROVEN STRUCTURE (split-K gates closed after R3/R10 failures).
// 2-wave blocks; wave w owns m-tile (blockIdx.y*2+w)*16; 256 blocks cover all CUs.
// 16(m) x 64(n = 16 feats x 4 gates) tile, full K=32 chunks per wave.
// Epilogue = f32 LSTM pointwise (matches the JAX f32 reference arithmetic;
// fp64 was extra precision bought with ~32 software-fp64 libm calls/lane).
// grid (32 nt, 8) x 128 threads = 256 blocks, 512 waves.
__global__ __launch_bounds__(128) void gates_lstm_kernel(
    const float* __restrict__ sum_emb, const unsigned long long* __restrict__ keys,
    const unsigned short* __restrict__ hin_hi, const unsigned short* __restrict__ hin_lo,
    const unsigned short* __restrict__ w1h, const unsigned short* __restrict__ w1l,
    const float* __restrict__ bi, const float* __restrict__ bh,
    float* __restrict__ c, float* __restrict__ h,
    unsigned short* __restrict__ hout_hi, unsigned short* __restrict__ hout_lo)
{
    const int tid  = threadIdx.x;
    const int lane = tid & 63;
    const int wav  = tid >> 6;
    const int col = lane & 15;
    const int kg  = lane >> 4;
    const int m0  = (blockIdx.y * 2 + wav) * 16;
    const int nt  = blockIdx.x;               // features nt*16 .. nt*16+15

    unsigned int tok = ~(unsigned int)(keys[m0 + col] & 0xFFFFFFFFull);

    const size_t ahoff = (size_t)(m0 >> 4) * 8192 + (size_t)lane * 8;
    const size_t boff  = (size_t)(nt * 4) * 16384 + (size_t)lane * 8;

    f32x4 acc[4];
    #pragma unroll
    for (int g = 0; g < 4; g++) acc[g] = (f32x4){0.f, 0.f, 0.f, 0.f};

    bf16x8 fa_h[2], fa_l[2], fb_h[2][4], fb_l[2][4];

#define GL_LOAD(C, BUF)                                                            \
    {                                                                              \
        if ((C) < 16) {                                                            \
            const float* s_ = sum_emb + (size_t)tok * DD + (C) * 32 + kg * 8;      \
            float4 v0 = *(const float4*)s_;                                        \
            float4 v1 = *(const float4*)(s_ + 4);                                  \
            split_frag(v0, v1, fa_h[BUF], fa_l[BUF]);                              \
        } else {                                                                   \
            fa_h[BUF] = *(const bf16x8*)(hin_hi + ahoff + ((C) - 16) * 512);       \
            fa_l[BUF] = *(const bf16x8*)(hin_lo + ahoff + ((C) - 16) * 512);       \
        }                                                                          \
        _Pragma("unroll")                                                          \
        for (int g = 0; g < 4; g++) {                                              \
            fb_h[BUF][g] = *(const bf16x8*)(w1h + boff + (size_t)g * 16384 + (C) * 512); \
            fb_l[BUF][g] = *(const bf16x8*)(w1l + boff + (size_t)g * 16384 + (C) * 512); \
        }                                                                          \
    }

    GL_LOAD(0, 0);
    #pragma unroll
    for (int cc = 0; cc < 32; cc++) {
        const int cur = cc & 1, nxt = cur ^ 1;
        if (cc < 31) GL_LOAD(cc + 1, nxt);
        #pragma unroll
        for (int g = 0; g < 4; g++) {
            acc[g] = __builtin_amdgcn_mfma_f32_16x16x32_bf16(fa_h[cur], fb_h[cur][g], acc[g], 0, 0, 0);
            acc[g] = __builtin_amdgcn_mfma_f32_16x16x32_bf16(fa_h[cur], fb_l[cur][g], acc[g], 0, 0, 0);
            acc[g] = __builtin_amdgcn_mfma_f32_16x16x32_bf16(fa_l[cur], fb_h[cur][g], acc[g], 0, 0, 0);
        }
    }
#undef GL_LOAD

    const int feat = nt * 16 + col;
    float bias[4];
    #pragma unroll
    for (int g = 0; g < 4; g++)
        bias[g] = bi[g * 512 + feat] + bh[g * 512 + feat];

    // LSTM pointwise in f32 (reference is JAX f32), 4 cells/lane
    #pragma unroll
    for (int r = 0; r < 4; r++) {
        const int b = m0 + kg * 4 + r;
        float vi = acc[0][r] + bias[0];
        float vf = acc[1][r] + bias[1];
        float vg = acc[2][r] + bias[2];
        float vo = acc[3][r] + bias[3];
        float ig = 1.f / (1.f + expf(-vi));
        float fg = 1.f / (1.f + expf(-vf));
        float gv = tanhf(vg);
        float og = 1.f / (1.f + expf(-vo));
        size_t cidx = (size_t)b * DD + feat;
        float cn = fg * c[cidx] + ig * gv;
        float hf = og * tanhf(cn);
        c[cidx] = cn;
        h[cidx] = hf;
        size_t hidx = (size_t)(b >> 4) * 8192 + (size_t)(feat >> 5) * 512
                    + (size_t)(((feat >> 3) & 3) * 16 + (b & 15)) * 8 + (feat & 7);
        unsigned short hb2 = f2bf_rn(hf);
        hout_hi[hidx] = hb2;
        hout_lo[hidx] = f2bf_rn(hf - bf2f(hb2));
    }
}

// -------------------- pre GEMM: tanh([t|h] @ [t_w|h_w]^T + t_b + h_b) -> packed A.
// 4-wave blocks, 16(m) x 32(n) tile, 4-way K-split (wave w = chunks 8w..8w+7).
// Partials reduced via LDS; tanhf epilogue (non-recurrent path; fp32 transcendental).
// grid (16 n-tiles, 16 m-tiles) = 1024 waves.
__global__ __launch_bounds__(256) void pre_kernel(
    const unsigned short* __restrict__ t_hi, const unsigned short* __restrict__ t_lo,
    const unsigned short* __restrict__ h_hi, const unsigned short* __restrict__ h_lo,
    const unsigned short* __restrict__ w2h, const unsigned short* __restrict__ w2l,
    const float* __restrict__ tb, const float* __restrict__ hbv,
    unsigned short* __restrict__ o_hi, unsigned short* __restrict__ o_lo)
{
    const int tid  = threadIdx.x;
    const int lane = tid & 63;
    const int wav  = tid >> 6;        // K-split: absolute chunks wav*8 .. wav*8+7
    const int col  = lane & 15;
    const int kg   = lane >> 4;
    const int m0   = blockIdx.y * 16;
    const int n0   = blockIdx.x * 32;

    const unsigned short* ah = (wav < 2) ? t_hi : h_hi;
    const unsigned short* al = (wav < 2) ? t_lo : h_lo;
    const size_t aoff = (size_t)(m0 >> 4) * 8192 + (size_t)lane * 8
                      + (size_t)((wav & 1) * 8) * 512;
    const size_t boff = (size_t)(n0 >> 4) * 16384 + (size_t)lane * 8
                      + (size_t)(wav * 8) * 512;

    f32x4 acc[2];
    acc[0] = (f32x4){0.f, 0.f, 0.f, 0.f};
    acc[1] = (f32x4){0.f, 0.f, 0.f, 0.f};

    bf16x8 fa_h[2], fa_l[2], fb_h[2][2], fb_l[2][2];
    fa_h[0] = *(const bf16x8*)(ah + aoff);
    fa_l[0] = *(const bf16x8*)(al + aoff);
    #pragma unroll
    for (int g = 0; g < 2; g++) {
        fb_h[0][g] = *(const bf16x8*)(w2h + boff + (size_t)g * 16384);
        fb_l[0][g] = *(const bf16x8*)(w2l + boff + (size_t)g * 16384);
    }
    #pragma unroll
    for (int cc = 0; cc < 8; cc++) {
        const int cur = cc & 1, nxt = cur ^ 1;
        if (cc < 7) {
            const int off = (cc + 1) * 512;
            fa_h[nxt] = *(const bf16x8*)(ah + aoff + off);
            fa_l[nxt] = *(const bf16x8*)(al + aoff + off);
            #pragma unroll
            for (int g = 0; g < 2; g++) {
                fb_h[nxt][g] = *(const bf16x8*)(w2h + boff + (size_t)g * 16384 + off);
                fb_l[nxt][g] = *(const bf16x8*)(w2l + boff + (size_t)g * 16384 + off);
            }
        }
        #pragma unroll
        for (int g = 0; g < 2; g++) {
            acc[g] = __builtin_amdgcn_mfma_f32_16x16x32_bf16(fa_h[cur], fb_h[cur][g], acc[g], 0, 0, 0);
            acc[g] = __builtin_amdgcn_mfma_f32_16x16x32_bf16(fa_h[cur], fb_l[cur][g], acc[g], 0, 0, 0);
            acc[g] = __builtin_amdgcn_mfma_f32_16x16x32_bf16(fa_l[cur], fb_h[cur][g], acc[g], 0, 0, 0);
        }
    }

    __shared__ float psum[4][16][32];
    #pragma unroll
    for (int g = 0; g < 2; g++)
        #pragma unroll
        for (int r = 0; r < 4; r++)
            psum[wav][kg * 4 + r][g * 16 + col] = acc[g][r];
    __syncthreads();

    #pragma unroll
    for (int e = 0; e < 2; e++) {
        const int idx  = tid * 2 + e;
        const int row  = idx >> 5, coln = idx & 31;
        const int b    = m0 + row;
        const int n    = n0 + coln;
        float accs = (psum[0][row][coln] + psum[1][row][coln])
                   + (psum[2][row][coln] + psum[3][row][coln]);
        float val = accs + (tb[n] + hbv[n]);
        float v2 = tanhf(val);
        int P = b >> 4, colb = b & 15;
        int cc2 = n >> 5, kgg = (n >> 3) & 3, jj = n & 7;
        size_t oidx = (size_t)P * 8192 + (size_t)cc2 * 512
                    + (size_t)(kgg * 16 + colb) * 8 + jj;
        unsigned short hb = f2bf_rn(v2);
        o_hi[oidx] = hb;
        o_lo[oidx] = f2bf_rn(v2 - bf2f(hb));
    }
}

// -------------------- logits GEMM (bf16x3 MFMA) + bias + store + argmax (R5 proven).
// 32(m) x 64(n) tile per wave, WPB waves per block sharing B panels.
template <int NCH, int EPI, int WPB>
__global__ __launch_bounds__(64 * WPB, 3) void mfma_gemm(
    const unsigned short* __restrict__ a0h, const unsigned short* __restrict__ a0l,
    const unsigned short* __restrict__ a1h, const unsigned short* __restrict__ a1l,
    const unsigned short* __restrict__ bmh, const unsigned short* __restrict__ bml,
    const float* __restrict__ bias0, const float* __restrict__ bias1,
    float* __restrict__ outp,
    unsigned short* __restrict__ o_hi, unsigned short* __restrict__ o_lo,
    unsigned long long* __restrict__ keys, int s)
{
    const int tid  = threadIdx.x;
    const int lane = tid & 63;
    const int wav  = tid >> 6;
    const int col = lane & 15;        // fragment row (A) / column (B)
    const int kg  = lane >> 4;        // k-group 0..3
    const int m0 = (blockIdx.y * WPB + wav) * 32;
    const int n0 = blockIdx.x * 64;

    const size_t aoff = (size_t)(m0 >> 4) * 8192 + (size_t)lane * 8;
    const size_t boff = (size_t)(n0 >> 4) * (NCH * 512) + (size_t)lane * 8;

    f32x4 acc[2][4];
    #pragma unroll
    for (int f = 0; f < 2; f++)
        #pragma unroll
        for (int g = 0; g < 4; g++)
            acc[f][g] = (f32x4){0.f, 0.f, 0.f, 0.f};

    bf16x8 fah[2][2], fal[2][2], fbh[2][4], fbl[2][4];

#define LOAD_CHUNK(C, BUF)                                                         \
    {                                                                              \
        const unsigned short* ah_ = ((NCH == 16) || ((C) < 16)) ? a0h : a1h;       \
        const unsigned short* al_ = ((NCH == 16) || ((C) < 16)) ? a0l : a1l;       \
        const int cc_ = (C) & 15;                                                  \
        _Pragma("unroll")                                                          \
        for (int f = 0; f < 2; f++) {                                              \
            fah[BUF][f] = *(const bf16x8*)(ah_ + aoff + (size_t)f * 8192 + cc_ * 512); \
            fal[BUF][f] = *(const bf16x8*)(al_ + aoff + (size_t)f * 8192 + cc_ * 512); \
        }                                                                          \
        _Pragma("unroll")                                                          \
        for (int g = 0; g < 4; g++) {                                              \
            fbh[BUF][g] = *(const bf16x8*)(bmh + boff + (size_t)g * (NCH * 512) + (C) * 512); \
            fbl[BUF][g] = *(const bf16x8*)(bml + boff + (size_t)g * (NCH * 512) + (C) * 512); \
        }                                                                          \
    }

    LOAD_CHUNK(0, 0);
    #pragma unroll
    for (int c = 0; c < NCH; c++) {
        const int cur = c & 1, nxt = cur ^ 1;
        if (c < NCH - 1) LOAD_CHUNK(c + 1, nxt);
        #pragma unroll
        for (int f = 0; f < 2; f++)
            #pragma unroll
            for (int g = 0; g < 4; g++) {
                acc[f][g] = __builtin_amdgcn_mfma_f32_16x16x32_bf16(fah[cur][f], fbh[cur][g], acc[f][g], 0, 0, 0);
                acc[f][g] = __builtin_amdgcn_mfma_f32_16x16x32_bf16(fah[cur][f], fbl[cur][g], acc[f][g], 0, 0, 0);
                acc[f][g] = __builtin_amdgcn_mfma_f32_16x16x32_bf16(fal[cur][f], fbh[cur][g], acc[f][g], 0, 0, 0);
            }
    }
#undef LOAD_CHUNK

    // bias per n-col of this lane (col fixed per lane)
    float bias[4];
    #pragma unroll
    for (int g = 0; g < 4; g++) {
        int v = n0 + g * 16 + col;
        bias[g] = (v < VS) ? bias0[v] : 0.f;
    }

    // epilogue (C/D: col = lane&15, row = kg*4 + reg)
    #pragma unroll
    for (int f = 0; f < 2; f++) {
        #pragma unroll
        for (int r = 0; r < 4; r++) {
            const int b = m0 + f * 16 + kg * 4 + r;
            float* orow = outp + ((size_t)b * STEPS + s) * VS;
            unsigned long long kmax = 0ull;
            #pragma unroll
            for (int g = 0; g < 4; g++) {
                int v = n0 + g * 16 + col;
                float val = acc[f][g][r] + bias[g];
                if (v < VS) {
                    orow[v] = val;
                    unsigned long long key =
                        ((unsigned long long)mono_key(val) << 32) |
                        (unsigned long long)(unsigned int)(~v);
                    if (key > kmax) kmax = key;
                }
            }
            #pragma unroll
            for (int mk = 1; mk < 16; mk <<= 1) {
                unsigned long long o = __shfl_xor(kmax, mk, 64);
                if (o > kmax) kmax = o;
            }
            if (col == 0) {
                // load-filter: stale reads are only ever lower -> conservative
                if (kmax > *(volatile unsigned long long*)&keys[b])
                    atomicMax(&keys[b], kmax);
            }
        }
    }
}

// -------------------- attention: SINGLE-PASS online softmax, 16 waves (1024 thr).
// Wave w handles l = w, w+16, ... (12-13 iters). fp32 expf throughout (R11/R12
// proven). Cross-wave combine over 16 partials; epilogue packs t, resets keys[b].
__global__ __launch_bounds__(1024) void attn_kernel(
    const int* __restrict__ method_code, const float* __restrict__ code_emb,
    const float* __restrict__ h, unsigned short* __restrict__ t_hi,
    unsigned short* __restrict__ t_lo, unsigned long long* __restrict__ keys)
{
    const int b = blockIdx.x;
    const int tid = threadIdx.x;
    const int lane = tid & 63, wave = tid >> 6;   // wave 0..15

    __shared__ int    rows[LL];
    __shared__ float  ts[DD];
    __shared__ float  part[16][DD];
    __shared__ float  wmax[16];
    __shared__ double wsum[16];

    if (tid < LL) rows[tid] = method_code[b * LL + tid];
    if (tid == 0) keys[b] = 0ull;   // safe: gates GEMM already consumed last step's keys
    // h fragment in registers: 8 consecutive dims per lane (same for all waves)
    const float* hb = h + (size_t)b * DD;
    float4 h0 = *(const float4*)(hb + lane * 8);
    float4 h1 = *(const float4*)(hb + lane * 8 + 4);
    __syncthreads();

    // single pass: score + online-softmax accumulate (e_l reused from registers)
    float  m = -INFINITY;
    double s = 0.0;
    float pa[8] = {0.f, 0.f, 0.f, 0.f, 0.f, 0.f, 0.f, 0.f};
    for (int l = wave; l < LL; l += 16) {
        const float* e = code_emb + (size_t)rows[l] * DD + lane * 8;
        float4 e0 = *(const float4*)e;
        float4 e1 = *(const float4*)(e + 4);
        float p = h0.x * e0.x + h0.y * e0.y + h0.z * e0.z + h0.w * e0.w
                + h1.x * e1.x + h1.y * e1.y + h1.z * e1.z + h1.w * e1.w;
        #pragma unroll
        for (int mk = 1; mk < 64; mk <<= 1) p += __shfl_xor(p, mk, 64);
        // p is uniform across the wave; online max update (branch is wave-uniform)
        if (p > m) {
            float scale = (m == -INFINITY) ? 0.f : expf(m - p);
            s *= (double)scale;
            #pragma unroll
            for (int j = 0; j < 8; j++) pa[j] *= scale;
            m = p;
        }
        float wf = expf(p - m);   // <= 1 (p==m gives exactly 1)
        s += (double)wf;
        pa[0] = fmaf(wf, e0.x, pa[0]); pa[1] = fmaf(wf, e0.y, pa[1]);
        pa[2] = fmaf(wf, e0.z, pa[2]); pa[3] = fmaf(wf, e0.w, pa[3]);
        pa[4] = fmaf(wf, e1.x, pa[4]); pa[5] = fmaf(wf, e1.y, pa[5]);
        pa[6] = fmaf(wf, e1.z, pa[6]); pa[7] = fmaf(wf, e1.w, pa[7]);
    }
    #pragma unroll
    for (int j = 0; j < 8; j++) part[wave][lane * 8 + j] = pa[j];
    if (lane == 0) { wmax[wave] = m; wsum[wave] = s; }
    __syncthreads();

    // cross-wave combine: threads 0..511 each own one dim (redundant M/S compute)
    if (tid < DD) {
        float M = wmax[0];
        #pragma unroll
        for (int w2 = 1; w2 < 16; w2++) M = fmaxf(M, wmax[w2]);
        float sc16[16];
        double S = 0.0;
        #pragma unroll
        for (int w2 = 0; w2 < 16; w2++) {
            sc16[w2] = expf(wmax[w2] - M);
            S += wsum[w2] * (double)sc16[w2];
        }
        const int d = tid;
        float q0 = (part[0][d] * sc16[0]  + part[1][d] * sc16[1])
                 + (part[2][d] * sc16[2]  + part[3][d] * sc16[3]);
        float q1 = (part[4][d] * sc16[4]  + part[5][d] * sc16[5])
                 + (part[6][d] * sc16[6]  + part[7][d] * sc16[7]);
        float q2 = (part[8][d] * sc16[8]  + part[9][d] * sc16[9])
                 + (part[10][d] * sc16[10] + part[11][d] * sc16[11]);
        float q3 = (part[12][d] * sc16[12] + part[13][d] * sc16[13])
                 + (part[14][d] * sc16[14] + part[15][d] * sc16[15]);
        ts[d] = (float)((double)((q0 + q1) + (q2 + q3)) / S);
    }
    __syncthreads();

    // pack t row into fragment order: 64 lanes x 8 consecutive dims
    if (tid < 64) {
        const int cc = tid >> 2, kgg = tid & 3;
        const float* src = ts + cc * 32 + kgg * 8;   // = ts + tid*8 (contiguous)
        float4 v0 = *(const float4*)src;
        float4 v1 = *(const float4*)(src + 4);
        size_t base = (size_t)(b >> 4) * 8192 + (size_t)cc * 512
                    + (size_t)(kgg * 16 + (b & 15)) * 8;
        split_store8(v0, v1, t_hi + base, t_lo + base);
    }
}

extern "C" void kernel_launch(void* const* d_in, const int* in_sizes, int n_in,
                              void* d_out, int out_size, void* d_ws, size_t ws_size,
                              hipStream_t stream)
{
    const int*   method_code = (const int*)d_in[0];
    const float* code_emb    = (const float*)d_in[1];
    const float* sum_emb     = (const float*)d_in[2];
    const float* w_ih        = (const float*)d_in[3];
    const float* w_hh        = (const float*)d_in[4];
    const float* b_ih        = (const float*)d_in[5];
    const float* b_hh        = (const float*)d_in[6];
    const float* t_w         = (const float*)d_in[7];
    const float* t_b         = (const float*)d_in[8];
    const float* h_w         = (const float*)d_in[9];
    const float* h_b         = (const float*)d_in[10];
    const float* p_w         = (const float*)d_in[11];
    const float* p_b         = (const float*)d_in[12];
    float* out = (float*)d_out;

    float* h     = (float*)d_ws;                                   // 256*512 f32
    float* c     = h + BB * DD;                                    // 256*512 f32
    unsigned long long* keys = (unsigned long long*)(c + BB * DD); // 256
    unsigned short* a_hi   = (unsigned short*)(keys + BB);         // 256*512 (logits A)
    unsigned short* a_lo   = a_hi   + BB * DD;
    unsigned short* t_hi   = a_lo   + BB * DD;                     // t half of pre-A
    unsigned short* t_lo   = t_hi   + BB * DD;
    unsigned short* hp0_hi = t_lo   + BB * DD;                     // packed h, buffer 0
    unsigned short* hp0_lo = hp0_hi + BB * DD;
    unsigned short* hp1_hi = hp0_lo + BB * DD;                     // packed h, buffer 1
    unsigned short* hp1_lo = hp1_hi + BB * DD;
    unsigned short* w1_hi  = hp1_lo + BB * DD;                     // [w_ih|w_hh] perm 2048x1024
    unsigned short* w1_lo  = w1_hi  + (size_t)2048 * 1024;
    unsigned short* w2_hi  = w1_lo  + (size_t)2048 * 1024;         // [t_w|h_w] 512x1024
    unsigned short* w2_lo  = w2_hi  + (size_t)512 * 1024;
    unsigned short* p_hi   = w2_lo  + (size_t)512 * 1024;          // 20224*512
    unsigned short* p_lo   = p_hi   + (size_t)VS_PAD * DD;

    // zero h, c (contiguous) and hp0 pair (step-0 gates reads it)
    hipMemsetAsync(h, 0, (size_t)2 * BB * DD * sizeof(float), stream);
    hipMemsetAsync(hp0_hi, 0, (size_t)2 * BB * DD * sizeof(unsigned short), stream);
    init_keys_kernel<<<1, 256, 0, stream>>>(keys);
    split_pw_kernel<<<(VS_PAD * 64) / 256, 256, 0, stream>>>(p_w, p_hi, p_lo);
    split_wcat_kernel<1><<<1024, 256, 0, stream>>>(w_ih, w_hh, w1_hi, w1_lo);  // gate-interleaved
    split_wcat_kernel<0><<<256, 256, 0, stream>>>(t_w, h_w, w2_hi, w2_lo);     // R=512

    for (int s = 0; s < STEPS; s++) {
        const unsigned short* hin_hi  = (s & 1) ? hp1_hi : hp0_hi;
        const unsigned short* hin_lo  = (s & 1) ? hp1_lo : hp0_lo;
        unsigned short*       hout_hi = (s & 1) ? hp0_hi : hp1_hi;
        unsigned short*       hout_lo = (s & 1) ? hp0_lo : hp1_lo;

        // fused gather + gates GEMM + LSTM + h pack (M=256, N=2048, K=1024)
        gates_lstm_kernel<<<dim3(32, 8), 128, 0, stream>>>(
            sum_emb, keys, hin_hi, hin_lo, w1_hi, w1_lo, b_ih, b_hh,
            c, h, hout_hi, hout_lo);
        attn_kernel<<<256, 1024, 0, stream>>>(method_code, code_emb, h, t_hi, t_lo, keys);
        // pre = tanh([t|h] @ [t_w|h_w]^T + t_b + h_b) -> packed logits-A (K split 4)
        pre_kernel<<<dim3(16, 16), 256, 0, stream>>>(
            t_hi, t_lo, hout_hi, hout_lo, w2_hi, w2_lo, t_b, h_b, a_hi, a_lo);
        // logits + greedy argmax (M=256, N=20224, K=512), 4 waves/block share B panels
        mfma_gemm<16, 2, 4><<<dim3(316, 2), 256, 0, stream>>>(
            a_hi, a_lo, nullptr, nullptr, p_hi, p_lo, p_b, nullptr,
            out, nullptr, nullptr, keys, s);
    }
}